// Round 12
// baseline (265.336 us; speedup 1.0000x reference)
//
#include <hip/hip_runtime.h>
#include <hip/hip_bf16.h>
#include <math.h>
#include <type_traits>

namespace {
constexpr int Bb = 256, Jj = 21, Cc = 256, Hh = 8, Dd = 256;
constexpr int Mrows = Bb * Jj;      // 5376
constexpr int HD    = Hh * Dd;      // 2048
constexpr int QKVN  = 3 * HD;       // 6144
constexpr int KNN   = 8;
constexpr int KFUSE = HD + Cc + Cc; // 2560

// ---- workspace byte offsets (no T tensor anymore; S = 5376x64 f32 scores) --
constexpr size_t OFF_QKV   = 0;                                   // bf16 5376x6144
constexpr size_t OFF_ATT   = OFF_QKV   + (size_t)Mrows*QKVN*2;    // bf16 5376x2048
constexpr size_t OFF_S     = OFF_ATT   + (size_t)Mrows*HD*2;      // f32  5376x64
constexpr size_t OFF_GT    = OFF_S     + (size_t)Mrows*64*4;      // f16  2048x768
constexpr size_t OFF_JFB   = OFF_GT    + (size_t)HD*768*2;        // bf16 5376x256
constexpr size_t OFF_JFH   = OFF_JFB   + (size_t)Mrows*Cc*2;      // f16  5376x256
constexpr size_t OFF_JFL   = OFF_JFH   + (size_t)Mrows*Cc*2;      // f16  5376x256
constexpr size_t OFF_JFD   = OFF_JFL   + (size_t)Mrows*Cc*2;      // f16  5376x256
constexpr size_t OFF_H1B   = OFF_JFD   + (size_t)Mrows*Cc*2;      // bf16 5376x256
constexpr size_t OFF_H2F   = OFF_H1B   + (size_t)Mrows*Cc*2;      // f32  5376x256
constexpr size_t OFF_WQKVT = OFF_H2F   + (size_t)Mrows*Cc*4;      // bf16 2x6144x256
constexpr size_t OFF_FBT   = OFF_WQKVT + (size_t)2*QKVN*Cc*2;     // bf16 2x256x2560
constexpr size_t OFF_WVP   = OFF_FBT   + (size_t)2*Cc*KFUSE*2;    // f32  256x24
constexpr size_t OFF_VPROJ = OFF_WVP   + (size_t)Cc*24*4;         // f32  5376x24
constexpr size_t OFF_WSUM  = OFF_VPROJ + (size_t)Mrows*24*4;      // f32  256x4
constexpr size_t OFF_CRD   = OFF_WSUM  + (size_t)Cc*4*4;          // f32  5376x4
constexpr size_t OFF_NBR0  = OFF_CRD   + (size_t)Mrows*4*4;       // int  5376x8
constexpr size_t OFF_NBR1  = OFF_NBR0  + (size_t)Mrows*KNN*4;
constexpr size_t OFF_STAT  = OFF_NBR1  + (size_t)Mrows*KNN*4;     // 2 f32
} // namespace

typedef short short8 __attribute__((ext_vector_type(8)));
typedef _Float16 half8 __attribute__((ext_vector_type(8)));
typedef _Float16 half4v __attribute__((ext_vector_type(4)));
typedef unsigned short u16x8 __attribute__((ext_vector_type(8)));
typedef float f32x4 __attribute__((ext_vector_type(4)));

__device__ __forceinline__ unsigned short f2bf(float x) {
    unsigned int u = __float_as_uint(x);
    u = u + 0x7fffu + ((u >> 16) & 1u);            // round-to-nearest-even
    return (unsigned short)(u >> 16);
}
__device__ __forceinline__ float bf2f(unsigned short b) {
    return __uint_as_float(((unsigned int)b) << 16);
}

// ---------------------------------------------------------------------------
// kNN body: exact stable-argsort ranks 1..8 by (d2, index).
__device__ __forceinline__ void knn_body(int b, const float* __restrict__ src,
                                         int ld, int* __restrict__ nbr,
                                         float (*cs)[3]) {
    int t = threadIdx.x;
    if (t < Jj) {
        const float* p = src + (size_t)(b * Jj + t) * ld;
        cs[t][0] = p[0]; cs[t][1] = p[1]; cs[t][2] = p[2];
    }
    __syncthreads();
    if (t < Jj) {
        float x = cs[t][0], y = cs[t][1], z = cs[t][2];
        float d2[Jj];
        #pragma unroll
        for (int jj = 0; jj < Jj; ++jj) {
            float dx = x - cs[jj][0], dy = y - cs[jj][1], dz = z - cs[jj][2];
            d2[jj] = dx*dx + dy*dy + dz*dz;
        }
        unsigned int used = 0u;
        int out_base = (b * Jj + t) * KNN;
        #pragma unroll
        for (int r = 0; r <= KNN; ++r) {
            int best = -1; float bd = INFINITY;
            #pragma unroll
            for (int jj = 0; jj < Jj; ++jj)
                if (!((used >> jj) & 1u) && d2[jj] < bd) { bd = d2[jj]; best = jj; }
            used |= (1u << best);
            if (r > 0) nbr[out_base + r - 1] = best;
        }
    }
}

// ---------------------------------------------------------------------------
// MEGA-PREP: one launch for all input-only work (+ zeroing S).
// [0,4352) transposes; 4352 wsum/stats; [4353,5697) cvt_split;
// [5697,5825) g_gemm; [5825,5833) wvp; [5833,6089) knn0; [6089,6425) zero S.
__global__ __launch_bounds__(256)
void mega_prep_kernel(const float* __restrict__ jf,
                      const float* __restrict__ wq, const float* __restrict__ wk,
                      const float* __restrict__ wv, const float* __restrict__ wp,
                      const float* __restrict__ wsw, const float* __restrict__ wsk,
                      unsigned short* __restrict__ wqkvT,
                      unsigned short* __restrict__ fbt, float* __restrict__ stats,
                      float* __restrict__ wsum,
                      unsigned short* __restrict__ jfb, _Float16* __restrict__ jfh,
                      _Float16* __restrict__ jfl, _Float16* __restrict__ jfd,
                      _Float16* __restrict__ GT, float* __restrict__ Wvp2,
                      int* __restrict__ nbr0, float* __restrict__ S) {
    __shared__ __align__(16) char sm[17408];
    int bid = blockIdx.x;
    int tidx = threadIdx.x;

    if (bid < 4352) {                      // ---- weight transposes ----
        const float* src; unsigned short* dst;
        int ldin, ldout, tilesX, tile;
        constexpr size_t CH = (size_t)Cc * HD;
        if (bid < 3072) {
            int op = bid >> 9; tile = bid & 511; tilesX = 64;
            ldin = HD; ldout = Cc;
            const float* s3[3] = {wq, wk, wv};
            src = s3[op % 3] + (size_t)(op / 3) * CH;
            dst = wqkvT + (size_t)(op % 3) * HD * Cc + (size_t)(op / 3) * QKVN * Cc;
        } else if (bid < 4096) {
            int op = (bid - 3072) >> 9; tile = (bid - 3072) & 511; tilesX = 8;
            ldin = Cc; ldout = KFUSE;
            src = wp + (size_t)op * HD * Cc;
            dst = fbt + (size_t)op * Cc * KFUSE;
        } else {
            int q = bid - 4096; int op = q >> 6; tile = q & 63; tilesX = 8;
            ldin = Cc; ldout = KFUSE;
            const float* s4[4] = {wsw, wsw + (size_t)Cc * Cc, wsk, wsk};
            src = s4[op];
            dst = fbt + (size_t)(op & 1) * Cc * KFUSE + HD + (size_t)(op >> 1) * Cc;
        }
        int bx = tile % tilesX, by = tile / tilesX;
        int n0 = bx * 32, k0 = by * 32;
        float (*t)[33] = (float(*)[33])sm;
        int r = tidx >> 3, c4 = (tidx & 7) * 4;
        float4 v = *(const float4*)&src[(size_t)(k0 + r) * ldin + n0 + c4];
        t[r][c4+0] = v.x; t[r][c4+1] = v.y; t[r][c4+2] = v.z; t[r][c4+3] = v.w;
        __syncthreads();
        ushort4 o;
        o.x = f2bf(t[c4+0][r]); o.y = f2bf(t[c4+1][r]);
        o.z = f2bf(t[c4+2][r]); o.w = f2bf(t[c4+3][r]);
        *(ushort4*)&dst[(size_t)(n0 + r) * ldout + k0 + c4] = o;
    } else if (bid == 4352) {              // ---- wsum + stats zero ----
        int e = tidx;
        float4 o;
        o.x = wsw[(size_t)e*Dd + 0] + wsk[(size_t)e*Dd + 0];
        o.y = wsw[(size_t)e*Dd + 1] + wsk[(size_t)e*Dd + 1];
        o.z = wsw[(size_t)e*Dd + 2] + wsk[(size_t)e*Dd + 2];
        o.w = 0.0f;
        *(float4*)&wsum[e*4] = o;
        if (e < 2) stats[e] = 0.0f;
    } else if (bid < 5697) {               // ---- cvt_split ----
        int i = (bid - 4353) * 256 + tidx;
        float4 v = ((const float4*)jf)[i];
        float x[4] = {v.x, v.y, v.z, v.w};
        ushort4 ob; half4v oh, ol, od;
        #pragma unroll
        for (int u = 0; u < 4; ++u) {
            ((unsigned short*)&ob)[u] = f2bf(x[u]);
            _Float16 h = (_Float16)x[u];
            oh[u] = h;
            ol[u] = (_Float16)((x[u] - (float)h) * 16.0f);
            od[u] = (_Float16)(x[u] * 0.0078125f);   // /128
        }
        ((ushort4*)jfb)[i] = ob;
        ((half4v*)jfh)[i] = oh;
        ((half4v*)jfl)[i] = ol;
        ((half4v*)jfd)[i] = od;
    } else if (bid < 5825) {               // ---- g_gemm -> GT (fp16-split) ----
        int q = bid - 5697;
        int h = q >> 4, rem = q & 15;
        int m0 = (rem >> 2) * 64, n0 = (rem & 3) * 64;
        float (*As)[68] = (float(*)[68])sm;
        float (*Ws)[68] = (float(*)[68])(sm + 8704);
        int ty = tidx >> 4, tx = tidx & 15;
        float acc[4][4] = {};
        for (int kb = 0; kb < 256; kb += 32) {
            #pragma unroll
            for (int it = 0; it < 2; ++it) {
                int c = tidx + it * 256;
                int row = c >> 3, col = (c & 7) * 4;
                float4 v = *(const float4*)&wq[(size_t)(m0 + row)*HD + h*256 + kb + col];
                float4 u = *(const float4*)&wk[(size_t)(n0 + row)*HD + h*256 + kb + col];
                As[col+0][row] = v.x; As[col+1][row] = v.y;
                As[col+2][row] = v.z; As[col+3][row] = v.w;
                Ws[col+0][row] = u.x; Ws[col+1][row] = u.y;
                Ws[col+2][row] = u.z; Ws[col+3][row] = u.w;
            }
            __syncthreads();
            #pragma unroll
            for (int kk = 0; kk < 32; ++kk) {
                float4 a = *(const float4*)&As[kk][ty*4];
                float4 b = *(const float4*)&Ws[kk][tx*4];
                float av[4] = {a.x, a.y, a.z, a.w};
                float bv[4] = {b.x, b.y, b.z, b.w};
                #pragma unroll
                for (int i = 0; i < 4; ++i)
                    #pragma unroll
                    for (int j = 0; j < 4; ++j)
                        acc[i][j] += av[i] * bv[j];
            }
            __syncthreads();
        }
        #pragma unroll
        for (int j = 0; j < 4; ++j) {
            int n = h*256 + n0 + tx*4 + j;
            half4v hi, hs, lo;
            #pragma unroll
            for (int i = 0; i < 4; ++i) {
                float g = acc[i][j];
                _Float16 gh = (_Float16)g;
                hi[i] = gh;
                hs[i] = (_Float16)(g * 0.0625f);
                lo[i] = (_Float16)((g - (float)gh) * 128.0f);
            }
            _Float16* base = &GT[(size_t)n*768 + m0 + ty*4];
            *(half4v*)(base)       = hi;
            *(half4v*)(base + 256) = hs;
            *(half4v*)(base + 512) = lo;
        }
    } else if (bid < 5833) {               // ---- wvp ----
        int h = bid - 5825;
        float (*wpc)[3] = (float(*)[3])sm;
        int t = tidx;
        const float* p = &wp[(size_t)(h*256 + t) * Cc];
        wpc[t][0] = p[0]; wpc[t][1] = p[1]; wpc[t][2] = p[2];
        __syncthreads();
        const float* vr = &wv[(size_t)t*HD + h*256];
        float a0=0, a1=0, a2=0;
        for (int d = 0; d < 256; ++d) {
            float v = vr[d];
            a0 += v*wpc[d][0]; a1 += v*wpc[d][1]; a2 += v*wpc[d][2];
        }
        float* o = &Wvp2[(size_t)t*24 + h*3];
        o[0]=a0; o[1]=a1; o[2]=a2;
    } else if (bid < 6089) {               // ---- knn layer 0 ----
        knn_body(bid - 5833, jf, Cc, nbr0, (float(*)[3])sm);
    } else {                               // ---- zero S (5376*64 f32) ----
        int idx = (bid - 6089) * 256 + tidx;
        ((f32x4*)S)[idx] = (f32x4){0.f, 0.f, 0.f, 0.f};
    }
}

// ---------------------------------------------------------------------------
// 16-bit MFMA GEMM core, XOR-swizzled LDS.
template<int BM, int BN, int BK, int NSEG, bool RELU_STATS, bool OUT_BF16, bool F16>
__device__ __forceinline__
void gemm_core(unsigned short* As, unsigned short* Bs, float* red,
               int bm, int bn,
               const unsigned short* __restrict__ A0, int lda0, int klen0,
               const unsigned short* __restrict__ A1, int lda1, int klen1,
               const unsigned short* __restrict__ A2, int lda2, int klen2,
               const unsigned short* __restrict__ Bt, int ldb,
               void* __restrict__ Cv, int ldc, float* __restrict__ stat) {
    constexpr int WM = BM/2, WN = BN/2;
    constexpr int MW = WM/16, NW = WN/16, KW = BK/32;
    constexpr int CHUNKA = BM*BK/8;
    constexpr int CHUNKB = BN*BK/8;
    constexpr int KB8 = BK/8;
    constexpr int SWZ = KB8 - 1;
    using frag = std::conditional_t<F16, half8, short8>;

    int tid = threadIdx.x;
    int wid = tid >> 6, lane = tid & 63;
    int wr = wid >> 1, wc = wid & 1;

    f32x4 acc[MW][NW];
    #pragma unroll
    for (int m = 0; m < MW; ++m)
        #pragma unroll
        for (int n = 0; n < NW; ++n)
            acc[m][n] = (f32x4){0.f, 0.f, 0.f, 0.f};

    const unsigned short* Aseg[3] = {A0, A1, A2};
    const int ldas[3] = {lda0, lda1, lda2};
    const int klens[3] = {klen0, klen1, klen2};

    int kglob = 0;
    for (int seg = 0; seg < NSEG; ++seg) {
        const unsigned short* A = Aseg[seg];
        const int lda = ldas[seg];
        const int klen = klens[seg];
        for (int k0 = 0; k0 < klen; k0 += BK) {
            #pragma unroll
            for (int it = 0; it < CHUNKA/256; ++it) {
                int c = tid + it*256;
                int row = c / KB8;
                int kp = (c % KB8) ^ (row & SWZ);
                __builtin_amdgcn_global_load_lds(
                    (const __attribute__((address_space(1))) unsigned int*)
                        (A + (size_t)(bm + row)*lda + k0 + kp*8),
                    (__attribute__((address_space(3))) unsigned int*)(As + c*8),
                    16, 0, 0);
            }
            #pragma unroll
            for (int it = 0; it < CHUNKB/256; ++it) {
                int c = tid + it*256;
                int row = c / KB8;
                int kp = (c % KB8) ^ (row & SWZ);
                __builtin_amdgcn_global_load_lds(
                    (const __attribute__((address_space(1))) unsigned int*)
                        (Bt + (size_t)(bn + row)*ldb + kglob + k0 + kp*8),
                    (__attribute__((address_space(3))) unsigned int*)(Bs + c*8),
                    16, 0, 0);
            }
            __syncthreads();
            #pragma unroll
            for (int kp = 0; kp < KW; ++kp) {
                frag af[MW], bf[NW];
                int cbase = kp*4 + (lane >> 4);
                #pragma unroll
                for (int m = 0; m < MW; ++m) {
                    int r = wr*WM + m*16 + (lane & 15);
                    af[m] = *(const frag*)&As[r*BK + ((cbase ^ (r & SWZ))*8)];
                }
                #pragma unroll
                for (int n = 0; n < NW; ++n) {
                    int r = wc*WN + n*16 + (lane & 15);
                    bf[n] = *(const frag*)&Bs[r*BK + ((cbase ^ (r & SWZ))*8)];
                }
                #pragma unroll
                for (int m = 0; m < MW; ++m)
                    #pragma unroll
                    for (int n = 0; n < NW; ++n) {
                        if constexpr (F16)
                            acc[m][n] = __builtin_amdgcn_mfma_f32_16x16x32_f16(
                                af[m], bf[n], acc[m][n], 0, 0, 0);
                        else
                            acc[m][n] = __builtin_amdgcn_mfma_f32_16x16x32_bf16(
                                af[m], bf[n], acc[m][n], 0, 0, 0);
                    }
            }
            __syncthreads();
        }
        kglob += klen;
    }

    int cr = (lane >> 4)*4, cc = lane & 15;
    float bsum = 0.0f;
    #pragma unroll
    for (int m = 0; m < MW; ++m)
        #pragma unroll
        for (int n = 0; n < NW; ++n)
            #pragma unroll
            for (int j = 0; j < 4; ++j) {
                float v = acc[m][n][j];
                if (RELU_STATS) { v = fmaxf(v, 0.0f); bsum += v; }
                size_t row = bm + wr*WM + m*16 + cr + j;
                size_t col = bn + wc*WN + n*16 + cc;
                if (OUT_BF16) ((unsigned short*)Cv)[row*ldc + col] = f2bf(v);
                else          ((float*)Cv)[row*ldc + col] = v;
            }
    if (RELU_STATS) {
        #pragma unroll
        for (int sft = 1; sft < 64; sft <<= 1) bsum += __shfl_xor(bsum, sft);
        if (lane == 0) red[wid] = bsum;
        __syncthreads();
        if (tid == 0) atomicAdd(stat, red[0] + red[1] + red[2] + red[3]);
    }
}

// ---------------------------------------------------------------------------
// T-gemm with fused SCORE epilogue: computes a 128x128 fp32 T tile in acc
// (fp16-split MFMA), spills it to LDS (2x 64-row passes), computes per-tile
// partial scores vs neighbor h0 rows, atomicAdd into S[gi][h*8+k].
// Exactly 2 partials per S entry (2 col-tiles per head) -> deterministic.
__device__ __forceinline__
void tscore_core(char* smem, int bm, int bn,
                 const unsigned short* __restrict__ A0,
                 const unsigned short* __restrict__ A1,
                 const unsigned short* __restrict__ A2,
                 const unsigned short* __restrict__ Bt,
                 const float* __restrict__ jf, const int* __restrict__ nbr,
                 float* __restrict__ S) {
    constexpr int BK = 64, KB8 = 8, SWZ = 7;
    unsigned short* As = (unsigned short*)smem;
    unsigned short* Bs = (unsigned short*)(smem + 16384);
    int tid = threadIdx.x;
    int wid = tid >> 6, lane = tid & 63;
    int wr = wid >> 1, wc = wid & 1;

    f32x4 acc[4][4];
    #pragma unroll
    for (int m = 0; m < 4; ++m)
        #pragma unroll
        for (int n = 0; n < 4; ++n)
            acc[m][n] = (f32x4){0.f, 0.f, 0.f, 0.f};

    const unsigned short* Aseg[3] = {A0, A1, A2};
    int kglob = 0;
    for (int seg = 0; seg < 3; ++seg) {
        const unsigned short* A = Aseg[seg];
        for (int k0 = 0; k0 < Cc; k0 += BK) {
            #pragma unroll
            for (int it = 0; it < 4; ++it) {
                int c = tid + it*256;
                int row = c / KB8;
                int kp = (c % KB8) ^ (row & SWZ);
                __builtin_amdgcn_global_load_lds(
                    (const __attribute__((address_space(1))) unsigned int*)
                        (A + (size_t)(bm + row)*Cc + k0 + kp*8),
                    (__attribute__((address_space(3))) unsigned int*)(As + c*8),
                    16, 0, 0);
                __builtin_amdgcn_global_load_lds(
                    (const __attribute__((address_space(1))) unsigned int*)
                        (Bt + (size_t)(bn + row)*768 + kglob + k0 + kp*8),
                    (__attribute__((address_space(3))) unsigned int*)(Bs + c*8),
                    16, 0, 0);
            }
            __syncthreads();
            #pragma unroll
            for (int kp = 0; kp < 2; ++kp) {
                half8 af[4], bf[4];
                int cbase = kp*4 + (lane >> 4);
                #pragma unroll
                for (int m = 0; m < 4; ++m) {
                    int r = wr*64 + m*16 + (lane & 15);
                    af[m] = *(const half8*)&As[r*BK + ((cbase ^ (r & SWZ))*8)];
                }
                #pragma unroll
                for (int n = 0; n < 4; ++n) {
                    int r = wc*64 + n*16 + (lane & 15);
                    bf[n] = *(const half8*)&Bs[r*BK + ((cbase ^ (r & SWZ))*8)];
                }
                #pragma unroll
                for (int m = 0; m < 4; ++m)
                    #pragma unroll
                    for (int n = 0; n < 4; ++n)
                        acc[m][n] = __builtin_amdgcn_mfma_f32_16x16x32_f16(
                            af[m], bf[n], acc[m][n], 0, 0, 0);
            }
            __syncthreads();
        }
        kglob += Cc;
    }

    // ---- score epilogue ----
    float* Tl = (float*)smem;          // 64 rows x 128 cols fp32 = 32 KB
    int hh = bn >> 8;                  // head
    int cpb = bn & 255;                // c' base (0 or 128)
    for (int half = 0; half < 2; ++half) {
        if (wr == half) {
            #pragma unroll
            for (int m = 0; m < 4; ++m)
                #pragma unroll
                for (int n = 0; n < 4; ++n)
                    #pragma unroll
                    for (int j = 0; j < 4; ++j) {
                        int r = m*16 + (lane >> 4)*4 + j;
                        int ccol = wc*64 + n*16 + (lane & 15);
                        Tl[r*128 + ccol] = acc[m][n][j];
                    }
        }
        __syncthreads();
        #pragma unroll
        for (int p0 = 0; p0 < 2; ++p0) {
            int p = tid + p0*256;
            int il = p >> 3, k = p & 7;
            int gi = bm + half*64 + il;
            int b = gi / Jj;
            int n = nbr[gi*KNN + k];
            const float* hrow = jf + (size_t)(b*Jj + n)*Cc + cpb;
            const float* trow = Tl + il*128;
            float s = 0.0f;
            #pragma unroll 8
            for (int c = 0; c < 128; c += 4) {
                f32x4 tv = *(const f32x4*)&trow[c];
                f32x4 hv = *(const f32x4*)&hrow[c];
                s += tv[0]*hv[0] + tv[1]*hv[1] + tv[2]*hv[2] + tv[3]*hv[3];
            }
            atomicAdd(&S[(size_t)gi*64 + hh*8 + k], s);
        }
        __syncthreads();
    }
}

// ---------------------------------------------------------------------------
// COMBO: y<48 -> layer-0 QKV gemm; y in [48,64) -> T-gemm + score epilogue;
// y in [64,80) -> vproj.
__global__ __launch_bounds__(256)
void combo_kernel(const unsigned short* __restrict__ jfb,
                  const unsigned short* __restrict__ wqkvT,
                  unsigned short* __restrict__ QKVb,
                  const _Float16* __restrict__ jfh, const _Float16* __restrict__ jfl,
                  const _Float16* __restrict__ jfd, const _Float16* __restrict__ GT,
                  const float* __restrict__ jf, const float* __restrict__ Wvp2,
                  float* __restrict__ vproj,
                  const int* __restrict__ nbr0, float* __restrict__ S) {
    __shared__ __align__(16) char smem[32784];
    int x = blockIdx.x, y = blockIdx.y;
    if (y < 48) {
        unsigned short* As = (unsigned short*)smem;
        unsigned short* Bs = (unsigned short*)(smem + 16384);
        float* red = (float*)(smem + 32768);
        gemm_core<128,128,64,1,false,true,false>(As, Bs, red, x*128, y*128,
            jfb, Cc, Cc, jfb, Cc, 0, jfb, Cc, 0, wqkvT, Cc, QKVb, QKVN, nullptr);
    } else if (y < 64) {
        tscore_core(smem, x*128, (y-48)*128,
                    (const unsigned short*)jfh, (const unsigned short*)jfl,
                    (const unsigned short*)jfd, (const unsigned short*)GT,
                    jf, nbr0, S);
    } else {
        int q = (y - 64) * 42 + x;
        float (*hr)[256] = (float(*)[256])smem;
        float* wl = (float*)(smem + 8192);
        int t = threadIdx.x;
        int j0 = q * 8;
        #pragma unroll
        for (int i = 0; i < 6; ++i)
            *(float4*)&wl[t*4 + i*1024] = *(const float4*)&Wvp2[t*4 + i*1024];
        {
            int r = t >> 5, c = (t & 31) * 8;
            const float* src = &jf[(size_t)(j0 + r)*Cc + c];
            *(float4*)&hr[r][c]   = *(const float4*)src;
            *(float4*)&hr[r][c+4] = *(const float4*)(src + 4);
        }
        __syncthreads();
        int r = t >> 5, o = t & 31;
        if (o < 24) {
            float a = 0.0f;
            for (int e = 0; e < 256; ++e) a += hr[r][e] * wl[e*24 + o];
            vproj[(size_t)(j0 + r)*24 + o] = a;
        }
    }
}

// ---------------------------------------------------------------------------
// standalone MFMA gemm (for layer-1 QKV)
template<int BM, int BN, int BK, int NSEG, bool RELU_STATS, bool OUT_BF16, bool F16 = false>
__global__ __launch_bounds__(256)
void gemm_bt_kernel(const unsigned short* __restrict__ A0, int lda0, int klen0,
                    const unsigned short* __restrict__ A1, int lda1, int klen1,
                    const unsigned short* __restrict__ A2, int lda2, int klen2,
                    const unsigned short* __restrict__ Bt, int ldb,
                    void* __restrict__ Cv, int ldc, float* __restrict__ stat) {
    __shared__ __align__(16) unsigned short As[BM*BK];
    __shared__ __align__(16) unsigned short Bs[BN*BK];
    __shared__ float red[4];
    gemm_core<BM,BN,BK,NSEG,RELU_STATS,OUT_BF16,F16>(
        As, Bs, red, blockIdx.x*BM, blockIdx.y*BN,
        A0, lda0, klen0, A1, lda1, klen1, A2, lda2, klen2,
        Bt, ldb, Cv, ldc, stat);
}

// ---------------------------------------------------------------------------
// fused epilogue gemm (BK=64, round-9 config) + optional layer-1 kNN blocks.
template<bool OUT_BF16, bool DO_KNN>
__global__ __launch_bounds__(256)
void fused_kernel(const unsigned short* __restrict__ att,
                  const unsigned short* __restrict__ hseg,
                  const unsigned short* __restrict__ h0seg,
                  const unsigned short* __restrict__ fbtL,
                  void* __restrict__ Cv, float* __restrict__ stat,
                  const float* __restrict__ crd, int* __restrict__ nbr1) {
    __shared__ __align__(16) char smem[16400];
    if (DO_KNN && blockIdx.y >= 4) {
        int b = (blockIdx.y - 4) * 84 + blockIdx.x;
        if (b < Bb) knn_body(b, crd, 4, nbr1, (float(*)[3])smem);
        return;
    }
    unsigned short* As = (unsigned short*)smem;
    unsigned short* Bs = (unsigned short*)(smem + 8192);
    float* red = (float*)(smem + 16384);
    gemm_core<64,64,64,3,true,OUT_BF16,false>(
        As, Bs, red, blockIdx.x*64, blockIdx.y*64,
        att, HD, HD, hseg, Cc, Cc, h0seg, Cc, Cc,
        fbtL, KFUSE, Cv, Cc, stat);
}

// ---------------------------------------------------------------------------
// attention (round-9 per-wave form) + optional finalize tail blocks
// (leaky+softmax over S, vproj combine, skip term, relu -> crd).
template<bool FIN>
__global__ __launch_bounds__(64)
void attn_kernel(const unsigned short* __restrict__ QKV,
                 const int* __restrict__ nbr, unsigned short* __restrict__ att,
                 const float* __restrict__ S, const float* __restrict__ vproj,
                 const float* __restrict__ jf, const float* __restrict__ wsum,
                 float* __restrict__ crd) {
    int gid = blockIdx.x;
    if (FIN && gid >= Mrows*4) {
        int gi = gid - Mrows*4;
        int b = gi / Jj;
        int l = threadIdx.x;
        int h = l >> 3, k = l & 7;
        float s = S[(size_t)gi*64 + l] * 0.0625f;
        s = (s >= 0.0f) ? s : 0.2f * s;
        float m = s;
        m = fmaxf(m, __shfl_xor(m, 1));
        m = fmaxf(m, __shfl_xor(m, 2));
        m = fmaxf(m, __shfl_xor(m, 4));
        float e = expf(s - m);
        float den = e;
        den += __shfl_xor(den, 1); den += __shfl_xor(den, 2); den += __shfl_xor(den, 4);
        float w = e / den;
        int n = nbr[gi*KNN + k];
        const float* vp = &vproj[(size_t)(b*Jj + n)*24 + h*3];
        float t0 = w*vp[0], t1 = w*vp[1], t2 = w*vp[2];
        float4 hv = *(const float4*)&jf[(size_t)gi*Cc + l*4];
        const float hx[4] = {hv.x, hv.y, hv.z, hv.w};
        #pragma unroll
        for (int u = 0; u < 4; ++u) {
            float4 wv = *(const float4*)&wsum[(l*4 + u)*4];
            t0 += hx[u]*wv.x; t1 += hx[u]*wv.y; t2 += hx[u]*wv.z;
        }
        #pragma unroll
        for (int sft = 1; sft < 64; sft <<= 1) {
            t0 += __shfl_xor(t0, sft); t1 += __shfl_xor(t1, sft); t2 += __shfl_xor(t2, sft);
        }
        if (l == 0) {
            crd[gi*4+0] = fmaxf(t0, 0.0f);
            crd[gi*4+1] = fmaxf(t1, 0.0f);
            crd[gi*4+2] = fmaxf(t2, 0.0f);
            crd[gi*4+3] = 0.0f;
        }
        return;
    }
    int hp = gid & 3, row = gid >> 2, b = row / Jj;
    int lane = threadIdx.x;
    int h = hp*2 + (lane >> 5);
    int d0 = (lane & 31) * 8;

    u16x8 qu = *(const u16x8*)&QKV[(size_t)row*QKVN + h*Dd + d0];
    float qf[8];
    #pragma unroll
    for (int i = 0; i < 8; ++i) qf[i] = bf2f(qu[i]);
    const int* np_ = nbr + row * KNN;

    float sc[KNN]; int nb[KNN];
    #pragma unroll
    for (int k = 0; k < KNN; ++k) {
        int n = np_[k]; nb[k] = n;
        u16x8 ku = *(const u16x8*)&QKV[(size_t)(b*Jj + n)*QKVN + HD + h*Dd + d0];
        float p = 0;
        #pragma unroll
        for (int i = 0; i < 8; ++i) p += qf[i] * bf2f(ku[i]);
        #pragma unroll
        for (int s = 1; s < 32; s <<= 1) p += __shfl_xor(p, s);
        sc[k] = p;
    }
    float mx = -INFINITY;
    #pragma unroll
    for (int k = 0; k < KNN; ++k) {
        float s = sc[k] * 0.0625f;
        s = (s >= 0.0f) ? s : 0.2f * s;
        sc[k] = s; mx = fmaxf(mx, s);
    }
    float den = 0.0f;
    #pragma unroll
    for (int k = 0; k < KNN; ++k) { sc[k] = expf(sc[k] - mx); den += sc[k]; }
    float inv = 1.0f / den;
    float o[8] = {};
    #pragma unroll
    for (int k = 0; k < KNN; ++k) {
        u16x8 vu = *(const u16x8*)&QKV[(size_t)(b*Jj + nb[k])*QKVN + 2*HD + h*Dd + d0];
        float w = sc[k] * inv;
        #pragma unroll
        for (int i = 0; i < 8; ++i) o[i] += w * bf2f(vu[i]);
    }
    u16x8 ou;
    #pragma unroll
    for (int i = 0; i < 8; ++i) ou[i] = f2bf(o[i]);
    *(u16x8*)&att[(size_t)row*HD + h*Dd + d0] = ou;
}

// ---------------------------------------------------------------------------
__global__ __launch_bounds__(64)
void final_kernel(const float* __restrict__ h, const float* __restrict__ fcw,
                  const float* __restrict__ fcb, const float* __restrict__ stats,
                  float* __restrict__ out) {
    int row = blockIdx.x, lane = threadIdx.x;
    const float4 hv = *(const float4*)(h + (size_t)row*Cc + lane*4);
    float a0=0, a1=0, a2=0;
    const float hx[4] = {hv.x, hv.y, hv.z, hv.w};
    #pragma unroll
    for (int i = 0; i < 4; ++i) {
        int c = lane*4 + i;
        a0 += hx[i]*fcw[c*3+0]; a1 += hx[i]*fcw[c*3+1]; a2 += hx[i]*fcw[c*3+2];
    }
    #pragma unroll
    for (int s = 32; s > 0; s >>= 1) {
        a0 += __shfl_xor(a0, s); a1 += __shfl_xor(a1, s); a2 += __shfl_xor(a2, s);
    }
    if (lane == 0) {
        out[row*3+0] = a0 + fcb[0];
        out[row*3+1] = a1 + fcb[1];
        out[row*3+2] = a2 + fcb[2];
        if (row == 0)
            out[(size_t)Mrows*3] =
                (stats[0] + stats[1]) * (0.5f / ((float)Mrows * (float)Cc));
    }
}

// ---------------------------------------------------------------------------
extern "C" void kernel_launch(void* const* d_in, const int* in_sizes, int n_in,
                              void* d_out, int out_size, void* d_ws, size_t ws_size,
                              hipStream_t stream) {
    (void)in_sizes; (void)n_in; (void)out_size; (void)ws_size;
    const float* jf     = (const float*)d_in[0];
    const float* wq     = (const float*)d_in[1];
    const float* wk     = (const float*)d_in[2];
    const float* wv     = (const float*)d_in[3];
    const float* wp     = (const float*)d_in[4];
    const float* wsw    = (const float*)d_in[5];
    const float* wskip0 = (const float*)d_in[6];
    const float* fcw    = (const float*)d_in[7];
    const float* fcb    = (const float*)d_in[8];
    float* out = (float*)d_out;

    char* wsb = (char*)d_ws;
    unsigned short* QKVb  = (unsigned short*)(wsb + OFF_QKV);
    unsigned short* attb  = (unsigned short*)(wsb + OFF_ATT);
    float*          S     = (float*)(wsb + OFF_S);
    _Float16*       GT    = (_Float16*)(wsb + OFF_GT);
    unsigned short* jfb   = (unsigned short*)(wsb + OFF_JFB);
    _Float16*       jfh   = (_Float16*)(wsb + OFF_JFH);
    _Float16*       jfl   = (_Float16*)(wsb + OFF_JFL);
    _Float16*       jfd   = (_Float16*)(wsb + OFF_JFD);
    unsigned short* h1b   = (unsigned short*)(wsb + OFF_H1B);
    float*          h2f   = (float*)(wsb + OFF_H2F);
    unsigned short* wqkvT = (unsigned short*)(wsb + OFF_WQKVT);
    unsigned short* fbt   = (unsigned short*)(wsb + OFF_FBT);
    float*          Wvp   = (float*)(wsb + OFF_WVP);
    float*          vproj = (float*)(wsb + OFF_VPROJ);
    float*          wsum  = (float*)(wsb + OFF_WSUM);
    float*          crd   = (float*)(wsb + OFF_CRD);
    int*            nbr0  = (int*)(wsb + OFF_NBR0);
    int*            nbr1  = (int*)(wsb + OFF_NBR1);
    float*          stats = (float*)(wsb + OFF_STAT);

    // 1. all input-only prep (+ zero S) in one launch
    mega_prep_kernel<<<6425, 256, 0, stream>>>(jf, wq, wk, wv, wp, wsw, wskip0,
                                               wqkvT, fbt, stats, wsum,
                                               jfb, jfh, jfl, jfd, GT, Wvp, nbr0, S);
    // 2. layer-0 QKV gemm + T-gemm-with-score-epilogue + vproj
    combo_kernel<<<dim3(42, 80), 256, 0, stream>>>(jfb, wqkvT, QKVb,
                                                   jfh, jfl, jfd, GT,
                                                   jf, Wvp, vproj, nbr0, S);
    // 3. layer-0 attention + coords finalize (independent tail blocks)
    attn_kernel<true><<<Mrows*5, 64, 0, stream>>>(QKVb, nbr0, attb,
                                                  S, vproj, jf, wsum, crd);
    // 4. layer-0 fused output gemm + layer-1 kNN
    fused_kernel<true, true><<<dim3(84, 8), 256, 0, stream>>>(
        attb, jfb, jfb, fbt, h1b, &stats[0], crd, nbr1);
    // 5. layer-1 QKV gemm
    gemm_bt_kernel<128,128,64,1,false,true><<<dim3(Mrows/128, QKVN/128), 256, 0, stream>>>(
        h1b, Cc, Cc, h1b, Cc, 0, h1b, Cc, 0, wqkvT + (size_t)QKVN*Cc, Cc, QKVb, QKVN, nullptr);
    // 6. layer-1 attention
    attn_kernel<false><<<Mrows*4, 64, 0, stream>>>(QKVb, nbr1, attb,
                                                   nullptr, nullptr, nullptr,
                                                   nullptr, nullptr);
    // 7. layer-1 fused output gemm
    fused_kernel<false, false><<<dim3(84, 4), 256, 0, stream>>>(
        attb, h1b, jfb, fbt + (size_t)Cc*KFUSE, h2f, &stats[1], nullptr, nullptr);
    // 8. final
    final_kernel<<<Mrows, 64, 0, stream>>>(h2f, fcw, fcb, stats, out);
}

// Round 13
// 232.678 us; speedup vs baseline: 1.1404x; 1.1404x over previous
//
#include <hip/hip_runtime.h>
#include <hip/hip_bf16.h>
#include <math.h>
#include <type_traits>

namespace {
constexpr int Bb = 256, Jj = 21, Cc = 256, Hh = 8, Dd = 256;
constexpr int Mrows = Bb * Jj;      // 5376
constexpr int HD    = Hh * Dd;      // 2048
constexpr int QKVN  = 3 * HD;       // 6144
constexpr int KNN   = 8;
constexpr int KFUSE = HD + Cc + Cc; // 2560

// ---- workspace byte offsets ----
// attb aliases the T region: T dead after precise_kernel, attn runs later.
constexpr size_t OFF_QKV   = 0;                                   // bf16 5376x6144
constexpr size_t OFF_T     = OFF_QKV   + (size_t)Mrows*QKVN*2;    // f32  5376x2048
constexpr size_t OFF_ATT   = OFF_T;                               // bf16 5376x2048 (alias)
constexpr size_t OFF_GT    = OFF_T     + (size_t)Mrows*HD*4;      // f16  2048x768
constexpr size_t OFF_JFB   = OFF_GT    + (size_t)HD*768*2;        // bf16 5376x256
constexpr size_t OFF_JFH   = OFF_JFB   + (size_t)Mrows*Cc*2;      // f16  5376x256
constexpr size_t OFF_JFL   = OFF_JFH   + (size_t)Mrows*Cc*2;      // f16  5376x256
constexpr size_t OFF_JFD   = OFF_JFL   + (size_t)Mrows*Cc*2;      // f16  5376x256
constexpr size_t OFF_H1B   = OFF_JFD   + (size_t)Mrows*Cc*2;      // bf16 5376x256
constexpr size_t OFF_H2F   = OFF_H1B   + (size_t)Mrows*Cc*2;      // f32  5376x256
constexpr size_t OFF_WQKVT = OFF_H2F   + (size_t)Mrows*Cc*4;      // bf16 2x6144x256
constexpr size_t OFF_FBT   = OFF_WQKVT + (size_t)2*QKVN*Cc*2;     // bf16 2x256x2560
constexpr size_t OFF_WVP   = OFF_FBT   + (size_t)2*Cc*KFUSE*2;    // f32  256x24
constexpr size_t OFF_VPROJ = OFF_WVP   + (size_t)Cc*24*4;         // f32  5376x24
constexpr size_t OFF_WSUM  = OFF_VPROJ + (size_t)Mrows*24*4;      // f32  256x4
constexpr size_t OFF_CRD   = OFF_WSUM  + (size_t)Cc*4*4;          // f32  5376x4
constexpr size_t OFF_NBR0  = OFF_CRD   + (size_t)Mrows*4*4;       // int  5376x8
constexpr size_t OFF_NBR1  = OFF_NBR0  + (size_t)Mrows*KNN*4;
constexpr size_t OFF_STAT  = OFF_NBR1  + (size_t)Mrows*KNN*4;     // 2 f32
} // namespace

typedef short short8 __attribute__((ext_vector_type(8)));
typedef _Float16 half8 __attribute__((ext_vector_type(8)));
typedef _Float16 half4v __attribute__((ext_vector_type(4)));
typedef unsigned short u16x8 __attribute__((ext_vector_type(8)));
typedef float f32x4 __attribute__((ext_vector_type(4)));

__device__ __forceinline__ unsigned short f2bf(float x) {
    unsigned int u = __float_as_uint(x);
    u = u + 0x7fffu + ((u >> 16) & 1u);            // round-to-nearest-even
    return (unsigned short)(u >> 16);
}
__device__ __forceinline__ float bf2f(unsigned short b) {
    return __uint_as_float(((unsigned int)b) << 16);
}

// ---------------------------------------------------------------------------
// kNN body: exact stable-argsort ranks 1..8 by (d2, index).
__device__ __forceinline__ void knn_body(int b, const float* __restrict__ src,
                                         int ld, int* __restrict__ nbr,
                                         float (*cs)[3]) {
    int t = threadIdx.x;
    if (t < Jj) {
        const float* p = src + (size_t)(b * Jj + t) * ld;
        cs[t][0] = p[0]; cs[t][1] = p[1]; cs[t][2] = p[2];
    }
    __syncthreads();
    if (t < Jj) {
        float x = cs[t][0], y = cs[t][1], z = cs[t][2];
        float d2[Jj];
        #pragma unroll
        for (int jj = 0; jj < Jj; ++jj) {
            float dx = x - cs[jj][0], dy = y - cs[jj][1], dz = z - cs[jj][2];
            d2[jj] = dx*dx + dy*dy + dz*dz;
        }
        unsigned int used = 0u;
        int out_base = (b * Jj + t) * KNN;
        #pragma unroll
        for (int r = 0; r <= KNN; ++r) {
            int best = -1; float bd = INFINITY;
            #pragma unroll
            for (int jj = 0; jj < Jj; ++jj)
                if (!((used >> jj) & 1u) && d2[jj] < bd) { bd = d2[jj]; best = jj; }
            used |= (1u << best);
            if (r > 0) nbr[out_base + r - 1] = best;
        }
    }
}

// ---------------------------------------------------------------------------
// MEGA-PREP: one launch for all input-only work.
__global__ __launch_bounds__(256)
void mega_prep_kernel(const float* __restrict__ jf,
                      const float* __restrict__ wq, const float* __restrict__ wk,
                      const float* __restrict__ wv, const float* __restrict__ wp,
                      const float* __restrict__ wsw, const float* __restrict__ wsk,
                      unsigned short* __restrict__ wqkvT,
                      unsigned short* __restrict__ fbt, float* __restrict__ stats,
                      float* __restrict__ wsum,
                      unsigned short* __restrict__ jfb, _Float16* __restrict__ jfh,
                      _Float16* __restrict__ jfl, _Float16* __restrict__ jfd,
                      _Float16* __restrict__ GT, float* __restrict__ Wvp2,
                      int* __restrict__ nbr0) {
    __shared__ __align__(16) char sm[17408];
    int bid = blockIdx.x;
    int tidx = threadIdx.x;

    if (bid < 4352) {                      // ---- weight transposes ----
        const float* src; unsigned short* dst;
        int ldin, ldout, tilesX, tile;
        constexpr size_t CH = (size_t)Cc * HD;
        if (bid < 3072) {
            int op = bid >> 9; tile = bid & 511; tilesX = 64;
            ldin = HD; ldout = Cc;
            const float* s3[3] = {wq, wk, wv};
            src = s3[op % 3] + (size_t)(op / 3) * CH;
            dst = wqkvT + (size_t)(op % 3) * HD * Cc + (size_t)(op / 3) * QKVN * Cc;
        } else if (bid < 4096) {
            int op = (bid - 3072) >> 9; tile = (bid - 3072) & 511; tilesX = 8;
            ldin = Cc; ldout = KFUSE;
            src = wp + (size_t)op * HD * Cc;
            dst = fbt + (size_t)op * Cc * KFUSE;
        } else {
            int q = bid - 4096; int op = q >> 6; tile = q & 63; tilesX = 8;
            ldin = Cc; ldout = KFUSE;
            const float* s4[4] = {wsw, wsw + (size_t)Cc * Cc, wsk, wsk};
            src = s4[op];
            dst = fbt + (size_t)(op & 1) * Cc * KFUSE + HD + (size_t)(op >> 1) * Cc;
        }
        int bx = tile % tilesX, by = tile / tilesX;
        int n0 = bx * 32, k0 = by * 32;
        float (*t)[33] = (float(*)[33])sm;
        int r = tidx >> 3, c4 = (tidx & 7) * 4;
        float4 v = *(const float4*)&src[(size_t)(k0 + r) * ldin + n0 + c4];
        t[r][c4+0] = v.x; t[r][c4+1] = v.y; t[r][c4+2] = v.z; t[r][c4+3] = v.w;
        __syncthreads();
        ushort4 o;
        o.x = f2bf(t[c4+0][r]); o.y = f2bf(t[c4+1][r]);
        o.z = f2bf(t[c4+2][r]); o.w = f2bf(t[c4+3][r]);
        *(ushort4*)&dst[(size_t)(n0 + r) * ldout + k0 + c4] = o;
    } else if (bid == 4352) {              // ---- wsum + stats zero ----
        int e = tidx;
        float4 o;
        o.x = wsw[(size_t)e*Dd + 0] + wsk[(size_t)e*Dd + 0];
        o.y = wsw[(size_t)e*Dd + 1] + wsk[(size_t)e*Dd + 1];
        o.z = wsw[(size_t)e*Dd + 2] + wsk[(size_t)e*Dd + 2];
        o.w = 0.0f;
        *(float4*)&wsum[e*4] = o;
        if (e < 2) stats[e] = 0.0f;
    } else if (bid < 5697) {               // ---- cvt_split ----
        int i = (bid - 4353) * 256 + tidx;
        float4 v = ((const float4*)jf)[i];
        float x[4] = {v.x, v.y, v.z, v.w};
        ushort4 ob; half4v oh, ol, od;
        #pragma unroll
        for (int u = 0; u < 4; ++u) {
            ((unsigned short*)&ob)[u] = f2bf(x[u]);
            _Float16 h = (_Float16)x[u];
            oh[u] = h;
            ol[u] = (_Float16)((x[u] - (float)h) * 16.0f);
            od[u] = (_Float16)(x[u] * 0.0078125f);   // /128
        }
        ((ushort4*)jfb)[i] = ob;
        ((half4v*)jfh)[i] = oh;
        ((half4v*)jfl)[i] = ol;
        ((half4v*)jfd)[i] = od;
    } else if (bid < 5825) {               // ---- g_gemm -> GT (fp16-split) ----
        int q = bid - 5697;
        int h = q >> 4, rem = q & 15;
        int m0 = (rem >> 2) * 64, n0 = (rem & 3) * 64;
        float (*As)[68] = (float(*)[68])sm;
        float (*Ws)[68] = (float(*)[68])(sm + 8704);
        int ty = tidx >> 4, tx = tidx & 15;
        float acc[4][4] = {};
        for (int kb = 0; kb < 256; kb += 32) {
            #pragma unroll
            for (int it = 0; it < 2; ++it) {
                int c = tidx + it * 256;
                int row = c >> 3, col = (c & 7) * 4;
                float4 v = *(const float4*)&wq[(size_t)(m0 + row)*HD + h*256 + kb + col];
                float4 u = *(const float4*)&wk[(size_t)(n0 + row)*HD + h*256 + kb + col];
                As[col+0][row] = v.x; As[col+1][row] = v.y;
                As[col+2][row] = v.z; As[col+3][row] = v.w;
                Ws[col+0][row] = u.x; Ws[col+1][row] = u.y;
                Ws[col+2][row] = u.z; Ws[col+3][row] = u.w;
            }
            __syncthreads();
            #pragma unroll
            for (int kk = 0; kk < 32; ++kk) {
                float4 a = *(const float4*)&As[kk][ty*4];
                float4 b = *(const float4*)&Ws[kk][tx*4];
                float av[4] = {a.x, a.y, a.z, a.w};
                float bv[4] = {b.x, b.y, b.z, b.w};
                #pragma unroll
                for (int i = 0; i < 4; ++i)
                    #pragma unroll
                    for (int j = 0; j < 4; ++j)
                        acc[i][j] += av[i] * bv[j];
            }
            __syncthreads();
        }
        #pragma unroll
        for (int j = 0; j < 4; ++j) {
            int n = h*256 + n0 + tx*4 + j;
            half4v hi, hs, lo;
            #pragma unroll
            for (int i = 0; i < 4; ++i) {
                float g = acc[i][j];
                _Float16 gh = (_Float16)g;
                hi[i] = gh;
                hs[i] = (_Float16)(g * 0.0625f);
                lo[i] = (_Float16)((g - (float)gh) * 128.0f);
            }
            _Float16* base = &GT[(size_t)n*768 + m0 + ty*4];
            *(half4v*)(base)       = hi;
            *(half4v*)(base + 256) = hs;
            *(half4v*)(base + 512) = lo;
        }
    } else if (bid < 5833) {               // ---- wvp ----
        int h = bid - 5825;
        float (*wpc)[3] = (float(*)[3])sm;
        int t = tidx;
        const float* p = &wp[(size_t)(h*256 + t) * Cc];
        wpc[t][0] = p[0]; wpc[t][1] = p[1]; wpc[t][2] = p[2];
        __syncthreads();
        const float* vr = &wv[(size_t)t*HD + h*256];
        float a0=0, a1=0, a2=0;
        for (int d = 0; d < 256; ++d) {
            float v = vr[d];
            a0 += v*wpc[d][0]; a1 += v*wpc[d][1]; a2 += v*wpc[d][2];
        }
        float* o = &Wvp2[(size_t)t*24 + h*3];
        o[0]=a0; o[1]=a1; o[2]=a2;
    } else {                               // ---- knn layer 0 ----
        knn_body(bid - 5833, jf, Cc, nbr0, (float(*)[3])sm);
    }
}

// ---------------------------------------------------------------------------
// 16-bit MFMA GEMM core, XOR-swizzled LDS.
template<int BM, int BN, int BK, int NSEG, bool RELU_STATS, bool OUT_BF16, bool F16>
__device__ __forceinline__
void gemm_core(unsigned short* As, unsigned short* Bs, float* red,
               int bm, int bn,
               const unsigned short* __restrict__ A0, int lda0, int klen0,
               const unsigned short* __restrict__ A1, int lda1, int klen1,
               const unsigned short* __restrict__ A2, int lda2, int klen2,
               const unsigned short* __restrict__ Bt, int ldb,
               void* __restrict__ Cv, int ldc, float* __restrict__ stat) {
    constexpr int WM = BM/2, WN = BN/2;
    constexpr int MW = WM/16, NW = WN/16, KW = BK/32;
    constexpr int CHUNKA = BM*BK/8;
    constexpr int CHUNKB = BN*BK/8;
    constexpr int KB8 = BK/8;
    constexpr int SWZ = KB8 - 1;
    using frag = std::conditional_t<F16, half8, short8>;

    int tid = threadIdx.x;
    int wid = tid >> 6, lane = tid & 63;
    int wr = wid >> 1, wc = wid & 1;

    f32x4 acc[MW][NW];
    #pragma unroll
    for (int m = 0; m < MW; ++m)
        #pragma unroll
        for (int n = 0; n < NW; ++n)
            acc[m][n] = (f32x4){0.f, 0.f, 0.f, 0.f};

    const unsigned short* Aseg[3] = {A0, A1, A2};
    const int ldas[3] = {lda0, lda1, lda2};
    const int klens[3] = {klen0, klen1, klen2};

    int kglob = 0;
    for (int seg = 0; seg < NSEG; ++seg) {
        const unsigned short* A = Aseg[seg];
        const int lda = ldas[seg];
        const int klen = klens[seg];
        for (int k0 = 0; k0 < klen; k0 += BK) {
            #pragma unroll
            for (int it = 0; it < CHUNKA/256; ++it) {
                int c = tid + it*256;
                int row = c / KB8;
                int kp = (c % KB8) ^ (row & SWZ);
                __builtin_amdgcn_global_load_lds(
                    (const __attribute__((address_space(1))) unsigned int*)
                        (A + (size_t)(bm + row)*lda + k0 + kp*8),
                    (__attribute__((address_space(3))) unsigned int*)(As + c*8),
                    16, 0, 0);
            }
            #pragma unroll
            for (int it = 0; it < CHUNKB/256; ++it) {
                int c = tid + it*256;
                int row = c / KB8;
                int kp = (c % KB8) ^ (row & SWZ);
                __builtin_amdgcn_global_load_lds(
                    (const __attribute__((address_space(1))) unsigned int*)
                        (Bt + (size_t)(bn + row)*ldb + kglob + k0 + kp*8),
                    (__attribute__((address_space(3))) unsigned int*)(Bs + c*8),
                    16, 0, 0);
            }
            __syncthreads();
            #pragma unroll
            for (int kp = 0; kp < KW; ++kp) {
                frag af[MW], bf[NW];
                int cbase = kp*4 + (lane >> 4);
                #pragma unroll
                for (int m = 0; m < MW; ++m) {
                    int r = wr*WM + m*16 + (lane & 15);
                    af[m] = *(const frag*)&As[r*BK + ((cbase ^ (r & SWZ))*8)];
                }
                #pragma unroll
                for (int n = 0; n < NW; ++n) {
                    int r = wc*WN + n*16 + (lane & 15);
                    bf[n] = *(const frag*)&Bs[r*BK + ((cbase ^ (r & SWZ))*8)];
                }
                #pragma unroll
                for (int m = 0; m < MW; ++m)
                    #pragma unroll
                    for (int n = 0; n < NW; ++n) {
                        if constexpr (F16)
                            acc[m][n] = __builtin_amdgcn_mfma_f32_16x16x32_f16(
                                af[m], bf[n], acc[m][n], 0, 0, 0);
                        else
                            acc[m][n] = __builtin_amdgcn_mfma_f32_16x16x32_bf16(
                                af[m], bf[n], acc[m][n], 0, 0, 0);
                    }
            }
            __syncthreads();
        }
        kglob += klen;
    }

    int cr = (lane >> 4)*4, cc = lane & 15;
    float bsum = 0.0f;
    #pragma unroll
    for (int m = 0; m < MW; ++m)
        #pragma unroll
        for (int n = 0; n < NW; ++n)
            #pragma unroll
            for (int j = 0; j < 4; ++j) {
                float v = acc[m][n][j];
                if (RELU_STATS) { v = fmaxf(v, 0.0f); bsum += v; }
                size_t row = bm + wr*WM + m*16 + cr + j;
                size_t col = bn + wc*WN + n*16 + cc;
                if (OUT_BF16) ((unsigned short*)Cv)[row*ldc + col] = f2bf(v);
                else          ((float*)Cv)[row*ldc + col] = v;
            }
    if (RELU_STATS) {
        #pragma unroll
        for (int sft = 1; sft < 64; sft <<= 1) bsum += __shfl_xor(bsum, sft);
        if (lane == 0) red[wid] = bsum;
        __syncthreads();
        if (tid == 0) atomicAdd(stat, red[0] + red[1] + red[2] + red[3]);
    }
}

// ---------------------------------------------------------------------------
// COMBO: y<48 -> layer-0 QKV gemm (XCD-chunked); y in [48,64) -> fp16-split
// T-gemm (XCD-chunked); y in [64,80) -> vproj. All independent.
__global__ __launch_bounds__(256)
void combo_kernel(const unsigned short* __restrict__ jfb,
                  const unsigned short* __restrict__ wqkvT,
                  unsigned short* __restrict__ QKVb,
                  const _Float16* __restrict__ jfh, const _Float16* __restrict__ jfl,
                  const _Float16* __restrict__ jfd, const _Float16* __restrict__ GT,
                  float* __restrict__ Tm,
                  const float* __restrict__ jf, const float* __restrict__ Wvp2,
                  float* __restrict__ vproj) {
    __shared__ __align__(16) char smem[32784];
    unsigned short* As = (unsigned short*)smem;
    unsigned short* Bs = (unsigned short*)(smem + 16384);
    float* red = (float*)(smem + 32768);
    int x = blockIdx.x, y = blockIdx.y;
    if (y < 48) {
        // XCD-chunked: 2016 blocks, chunk=252 -> each XCD gets ~6 contiguous
        // y-panels (B 6x64KB + A 2.75MB ~ 3.4MB fits 4MB L2/XCD).
        int lb = x + 42*y;
        int nb = (lb & 7) * 252 + (lb >> 3);
        int sx = nb % 42, sy = nb / 42;
        gemm_core<128,128,64,1,false,true,false>(As, Bs, red, sx*128, sy*128,
            jfb, Cc, Cc, jfb, Cc, 0, jfb, Cc, 0, wqkvT, Cc, QKVb, QKVN, nullptr);
    } else if (y < 64) {
        // XCD-chunked by x: 672 blocks, chunk=84 -> each XCD ~5 x-rows x all
        // 16 y (A ~1MB + B 3.1MB fits L2/XCD).
        int lb = x + 42*(y - 48);
        int nb = (lb & 7) * 84 + (lb >> 3);
        int sx = nb / 16, sy = nb % 16;
        gemm_core<128,128,64,3,false,false,true>(As, Bs, red, sx*128, sy*128,
            (const unsigned short*)jfh, Cc, Cc, (const unsigned short*)jfl, Cc, Cc,
            (const unsigned short*)jfd, Cc, Cc, (const unsigned short*)GT, 768,
            Tm, HD, nullptr);
    } else {
        int q = (y - 64) * 42 + x;
        float (*hr)[256] = (float(*)[256])smem;
        float* wl = (float*)(smem + 8192);
        int t = threadIdx.x;
        int j0 = q * 8;
        #pragma unroll
        for (int i = 0; i < 6; ++i)
            *(float4*)&wl[t*4 + i*1024] = *(const float4*)&Wvp2[t*4 + i*1024];
        {
            int r = t >> 5, c = (t & 31) * 8;
            const float* src = &jf[(size_t)(j0 + r)*Cc + c];
            *(float4*)&hr[r][c]   = *(const float4*)src;
            *(float4*)&hr[r][c+4] = *(const float4*)(src + 4);
        }
        __syncthreads();
        int r = t >> 5, o = t & 31;
        if (o < 24) {
            float a = 0.0f;
            for (int e = 0; e < 256; ++e) a += hr[r][e] * wl[e*24 + o];
            vproj[(size_t)(j0 + r)*24 + o] = a;
        }
    }
}

// ---------------------------------------------------------------------------
// layer-1 QKV gemm with XCD-chunked swizzle (grid 42x48, 2016 blocks).
__global__ __launch_bounds__(256)
void qkv1_kernel(const unsigned short* __restrict__ h1b,
                 const unsigned short* __restrict__ wqkvT1,
                 unsigned short* __restrict__ QKVb) {
    __shared__ __align__(16) unsigned short As[128*64];
    __shared__ __align__(16) unsigned short Bs[128*64];
    __shared__ float red[4];
    int lb = blockIdx.x + 42*blockIdx.y;
    int nb = (lb & 7) * 252 + (lb >> 3);
    int sx = nb % 42, sy = nb / 42;
    gemm_core<128,128,64,1,false,true,false>(
        As, Bs, red, sx*128, sy*128,
        h1b, Cc, Cc, h1b, Cc, 0, h1b, Cc, 0, wqkvT1, Cc, QKVb, QKVN, nullptr);
}

// ---------------------------------------------------------------------------
// fused epilogue gemm (+ optional layer-1 kNN in extra y-blocks)
template<bool OUT_BF16, bool DO_KNN>
__global__ __launch_bounds__(256)
void fused_kernel(const unsigned short* __restrict__ att,
                  const unsigned short* __restrict__ hseg,
                  const unsigned short* __restrict__ h0seg,
                  const unsigned short* __restrict__ fbtL,
                  void* __restrict__ Cv, float* __restrict__ stat,
                  const float* __restrict__ crd, int* __restrict__ nbr1) {
    __shared__ __align__(16) char smem[16400];
    if (DO_KNN && blockIdx.y >= 4) {
        int b = (blockIdx.y - 4) * 84 + blockIdx.x;
        if (b < Bb) knn_body(b, crd, 4, nbr1, (float(*)[3])smem);
        return;
    }
    unsigned short* As = (unsigned short*)smem;
    unsigned short* Bs = (unsigned short*)(smem + 8192);
    float* red = (float*)(smem + 16384);
    gemm_core<64,64,64,3,true,OUT_BF16,false>(
        As, Bs, red, blockIdx.x*64, blockIdx.y*64,
        att, HD, HD, hseg, Cc, Cc, h0seg, Cc, Cc,
        fbtL, KFUSE, Cv, Cc, stat);
}

// ---------------------------------------------------------------------------
// precise layer-0 coords
__global__ __launch_bounds__(64)
void precise_kernel(const float* __restrict__ T, const float* __restrict__ h0,
                    const int* __restrict__ nbr, const float* __restrict__ vproj,
                    const float* __restrict__ wsum, float* __restrict__ crd) {
    int i = blockIdx.x;
    int b = i / Jj;
    int l = threadIdx.x;
    __shared__ float Ts[8][260];
    __shared__ float nb[8][260];
    __shared__ float hi[256];
    #pragma unroll
    for (int u = 0; u < 8; ++u) {
        int idx = u*64 + l;
        float4 v = *(const float4*)&T[(size_t)i*HD + idx*4];
        int hh = idx >> 6, dd = (idx & 63) * 4;
        *(float4*)&Ts[hh][dd] = v;
    }
    *(float4*)&hi[l*4] = *(const float4*)&h0[(size_t)i*Cc + l*4];
    int kq = l >> 3, s = l & 7;
    int njs = nbr[i*KNN + kq];
    const float* nrow = &h0[(size_t)(b*Jj + njs)*Cc];
    #pragma unroll
    for (int u = 0; u < 8; ++u)
        *(float4*)&nb[kq][(s*8+u)*4] = *(const float4*)&nrow[(s*8+u)*4];
    __syncthreads();

    int k = l >> 3, h = l & 7;
    float sacc = 0;
    #pragma unroll 8
    for (int d = 0; d < 256; d += 4) {
        float4 tv = *(const float4*)&Ts[h][d];
        float4 nv = *(const float4*)&nb[k][d];
        sacc += tv.x*nv.x + tv.y*nv.y + tv.z*nv.z + tv.w*nv.w;
    }
    float sc = sacc * 0.0625f;
    sc = (sc >= 0.0f) ? sc : 0.2f * sc;
    float m = sc;
    m = fmaxf(m, __shfl_xor(m, 8));
    m = fmaxf(m, __shfl_xor(m, 16));
    m = fmaxf(m, __shfl_xor(m, 32));
    float e = expf(sc - m);
    float den = e;
    den += __shfl_xor(den, 8); den += __shfl_xor(den, 16); den += __shfl_xor(den, 32);
    float w = e / den;

    int njk = nbr[i*KNN + k];
    const float* vp = &vproj[(size_t)(b*Jj + njk)*24 + h*3];
    float t0 = w * vp[0], t1 = w * vp[1], t2 = w * vp[2];
    #pragma unroll
    for (int u = 0; u < 4; ++u) {
        int e4 = l*4 + u;
        float hv = hi[e4];
        float4 wv = *(const float4*)&wsum[e4*4];
        t0 += hv * wv.x; t1 += hv * wv.y; t2 += hv * wv.z;
    }
    #pragma unroll
    for (int sft = 1; sft < 64; sft <<= 1) {
        t0 += __shfl_xor(t0, sft); t1 += __shfl_xor(t1, sft); t2 += __shfl_xor(t2, sft);
    }
    if (l == 0) {
        crd[i*4+0] = fmaxf(t0, 0.0f);
        crd[i*4+1] = fmaxf(t1, 0.0f);
        crd[i*4+2] = fmaxf(t2, 0.0f);
        crd[i*4+3] = 0.0f;
    }
}

// ---------------------------------------------------------------------------
// attention: one wave per (row, head-pair); 32 lanes per head, ushort8 loads.
__global__ __launch_bounds__(64)
void attn_kernel(const unsigned short* __restrict__ QKV,
                 const int* __restrict__ nbr, unsigned short* __restrict__ att) {
    int gid = blockIdx.x;
    int hp = gid & 3, row = gid >> 2, b = row / Jj;
    int lane = threadIdx.x;
    int h = hp*2 + (lane >> 5);
    int d0 = (lane & 31) * 8;

    u16x8 qu = *(const u16x8*)&QKV[(size_t)row*QKVN + h*Dd + d0];
    float qf[8];
    #pragma unroll
    for (int i = 0; i < 8; ++i) qf[i] = bf2f(qu[i]);
    const int* np_ = nbr + row * KNN;

    float sc[KNN]; int nb[KNN];
    #pragma unroll
    for (int k = 0; k < KNN; ++k) {
        int n = np_[k]; nb[k] = n;
        u16x8 ku = *(const u16x8*)&QKV[(size_t)(b*Jj + n)*QKVN + HD + h*Dd + d0];
        float p = 0;
        #pragma unroll
        for (int i = 0; i < 8; ++i) p += qf[i] * bf2f(ku[i]);
        #pragma unroll
        for (int s = 1; s < 32; s <<= 1) p += __shfl_xor(p, s);
        sc[k] = p;
    }
    float mx = -INFINITY;
    #pragma unroll
    for (int k = 0; k < KNN; ++k) {
        float s = sc[k] * 0.0625f;
        s = (s >= 0.0f) ? s : 0.2f * s;
        sc[k] = s; mx = fmaxf(mx, s);
    }
    float den = 0.0f;
    #pragma unroll
    for (int k = 0; k < KNN; ++k) { sc[k] = expf(sc[k] - mx); den += sc[k]; }
    float inv = 1.0f / den;
    float o[8] = {};
    #pragma unroll
    for (int k = 0; k < KNN; ++k) {
        u16x8 vu = *(const u16x8*)&QKV[(size_t)(b*Jj + nb[k])*QKVN + 2*HD + h*Dd + d0];
        float w = sc[k] * inv;
        #pragma unroll
        for (int i = 0; i < 8; ++i) o[i] += w * bf2f(vu[i]);
    }
    u16x8 ou;
    #pragma unroll
    for (int i = 0; i < 8; ++i) ou[i] = f2bf(o[i]);
    *(u16x8*)&att[(size_t)row*HD + h*Dd + d0] = ou;
}

// ---------------------------------------------------------------------------
__global__ __launch_bounds__(64)
void final_kernel(const float* __restrict__ h, const float* __restrict__ fcw,
                  const float* __restrict__ fcb, const float* __restrict__ stats,
                  float* __restrict__ out) {
    int row = blockIdx.x, lane = threadIdx.x;
    const float4 hv = *(const float4*)(h + (size_t)row*Cc + lane*4);
    float a0=0, a1=0, a2=0;
    const float hx[4] = {hv.x, hv.y, hv.z, hv.w};
    #pragma unroll
    for (int i = 0; i < 4; ++i) {
        int c = lane*4 + i;
        a0 += hx[i]*fcw[c*3+0]; a1 += hx[i]*fcw[c*3+1]; a2 += hx[i]*fcw[c*3+2];
    }
    #pragma unroll
    for (int s = 32; s > 0; s >>= 1) {
        a0 += __shfl_xor(a0, s); a1 += __shfl_xor(a1, s); a2 += __shfl_xor(a2, s);
    }
    if (lane == 0) {
        out[row*3+0] = a0 + fcb[0];
        out[row*3+1] = a1 + fcb[1];
        out[row*3+2] = a2 + fcb[2];
        if (row == 0)
            out[(size_t)Mrows*3] =
                (stats[0] + stats[1]) * (0.5f / ((float)Mrows * (float)Cc));
    }
}

// ---------------------------------------------------------------------------
extern "C" void kernel_launch(void* const* d_in, const int* in_sizes, int n_in,
                              void* d_out, int out_size, void* d_ws, size_t ws_size,
                              hipStream_t stream) {
    (void)in_sizes; (void)n_in; (void)out_size; (void)ws_size;
    const float* jf     = (const float*)d_in[0];
    const float* wq     = (const float*)d_in[1];
    const float* wk     = (const float*)d_in[2];
    const float* wv     = (const float*)d_in[3];
    const float* wp     = (const float*)d_in[4];
    const float* wsw    = (const float*)d_in[5];
    const float* wskip0 = (const float*)d_in[6];
    const float* fcw    = (const float*)d_in[7];
    const float* fcb    = (const float*)d_in[8];
    float* out = (float*)d_out;

    char* wsb = (char*)d_ws;
    unsigned short* QKVb  = (unsigned short*)(wsb + OFF_QKV);
    float*          Tm    = (float*)(wsb + OFF_T);
    unsigned short* attb  = (unsigned short*)(wsb + OFF_ATT);   // aliases T
    _Float16*       GT    = (_Float16*)(wsb + OFF_GT);
    unsigned short* jfb   = (unsigned short*)(wsb + OFF_JFB);
    _Float16*       jfh   = (_Float16*)(wsb + OFF_JFH);
    _Float16*       jfl   = (_Float16*)(wsb + OFF_JFL);
    _Float16*       jfd   = (_Float16*)(wsb + OFF_JFD);
    unsigned short* h1b   = (unsigned short*)(wsb + OFF_H1B);
    float*          h2f   = (float*)(wsb + OFF_H2F);
    unsigned short* wqkvT = (unsigned short*)(wsb + OFF_WQKVT);
    unsigned short* fbt   = (unsigned short*)(wsb + OFF_FBT);
    float*          Wvp   = (float*)(wsb + OFF_WVP);
    float*          vproj = (float*)(wsb + OFF_VPROJ);
    float*          wsum  = (float*)(wsb + OFF_WSUM);
    float*          crd   = (float*)(wsb + OFF_CRD);
    int*            nbr0  = (int*)(wsb + OFF_NBR0);
    int*            nbr1  = (int*)(wsb + OFF_NBR1);
    float*          stats = (float*)(wsb + OFF_STAT);

    // 1. all input-only prep in one launch
    mega_prep_kernel<<<6089, 256, 0, stream>>>(jf, wq, wk, wv, wp, wsw, wskip0,
                                               wqkvT, fbt, stats, wsum,
                                               jfb, jfh, jfl, jfd, GT, Wvp, nbr0);
    // 2. layer-0 QKV gemm + fp16-split T-gemm + vproj in one launch
    combo_kernel<<<dim3(42, 80), 256, 0, stream>>>(jfb, wqkvT, QKVb,
                                                   jfh, jfl, jfd, GT, Tm,
                                                   jf, Wvp, vproj);
    // 3. precise layer-0 coords (consumes Tm; attb overwrites it after)
    precise_kernel<<<Mrows, 64, 0, stream>>>(Tm, jf, nbr0, vproj, wsum, crd);
    // 4. layer-0 attention
    attn_kernel<<<Mrows*4, 64, 0, stream>>>(QKVb, nbr0, attb);
    // 5. layer-0 fused output gemm + layer-1 kNN
    fused_kernel<true, true><<<dim3(84, 8), 256, 0, stream>>>(
        attb, jfb, jfb, fbt, h1b, &stats[0], crd, nbr1);
    // 6. layer-1 QKV gemm (XCD-chunked)
    qkv1_kernel<<<dim3(42, 48), 256, 0, stream>>>(h1b, wqkvT + (size_t)QKVN*Cc, QKVb);
    // 7. layer-1 attention
    attn_kernel<<<Mrows*4, 64, 0, stream>>>(QKVb, nbr1, attb);
    // 8. layer-1 fused output gemm
    fused_kernel<false, false><<<dim3(84, 4), 256, 0, stream>>>(
        attb, h1b, jfb, fbt + (size_t)Cc*KFUSE, h2f, &stats[1], nullptr, nullptr);
    // 9. final
    final_kernel<<<Mrows, 64, 0, stream>>>(h2f, fcw, fcb, stats, out);
}

// Round 14
// 231.701 us; speedup vs baseline: 1.1452x; 1.0042x over previous
//
#include <hip/hip_runtime.h>
#include <hip/hip_bf16.h>
#include <math.h>
#include <type_traits>

namespace {
constexpr int Bb = 256, Jj = 21, Cc = 256, Hh = 8, Dd = 256;
constexpr int Mrows = Bb * Jj;      // 5376
constexpr int HD    = Hh * Dd;      // 2048
constexpr int QKVN  = 3 * HD;       // 6144
constexpr int KNN   = 8;
constexpr int KFUSE = HD + Cc + Cc; // 2560

// ---- workspace byte offsets ----
// attb aliases the T region: T dead after precise_kernel, attn runs later.
constexpr size_t OFF_QKV   = 0;                                   // bf16 5376x6144
constexpr size_t OFF_T     = OFF_QKV   + (size_t)Mrows*QKVN*2;    // f32  5376x2048
constexpr size_t OFF_ATT   = OFF_T;                               // bf16 5376x2048 (alias)
constexpr size_t OFF_GT    = OFF_T     + (size_t)Mrows*HD*4;      // f16  2048x768
constexpr size_t OFF_JFB   = OFF_GT    + (size_t)HD*768*2;        // bf16 5376x256
constexpr size_t OFF_JFH   = OFF_JFB   + (size_t)Mrows*Cc*2;      // f16  5376x256
constexpr size_t OFF_JFL   = OFF_JFH   + (size_t)Mrows*Cc*2;      // f16  5376x256
constexpr size_t OFF_JFD   = OFF_JFL   + (size_t)Mrows*Cc*2;      // f16  5376x256
constexpr size_t OFF_H1B   = OFF_JFD   + (size_t)Mrows*Cc*2;      // bf16 5376x256
constexpr size_t OFF_H2F   = OFF_H1B   + (size_t)Mrows*Cc*2;      // f32  5376x256
constexpr size_t OFF_WQKVT = OFF_H2F   + (size_t)Mrows*Cc*4;      // bf16 2x6144x256
constexpr size_t OFF_FBT   = OFF_WQKVT + (size_t)2*QKVN*Cc*2;     // bf16 2x256x2560
constexpr size_t OFF_WVP   = OFF_FBT   + (size_t)2*Cc*KFUSE*2;    // f32  256x24
constexpr size_t OFF_VPROJ = OFF_WVP   + (size_t)Cc*24*4;         // f32  5376x24
constexpr size_t OFF_WSUM  = OFF_VPROJ + (size_t)Mrows*24*4;      // f32  256x4
constexpr size_t OFF_CRD   = OFF_WSUM  + (size_t)Cc*4*4;          // f32  5376x4
constexpr size_t OFF_NBR0  = OFF_CRD   + (size_t)Mrows*4*4;       // int  5376x8
constexpr size_t OFF_NBR1  = OFF_NBR0  + (size_t)Mrows*KNN*4;
constexpr size_t OFF_STAT  = OFF_NBR1  + (size_t)Mrows*KNN*4;     // 2 f32
} // namespace

typedef short short8 __attribute__((ext_vector_type(8)));
typedef _Float16 half8 __attribute__((ext_vector_type(8)));
typedef _Float16 half4v __attribute__((ext_vector_type(4)));
typedef unsigned short u16x8 __attribute__((ext_vector_type(8)));
typedef float f32x4 __attribute__((ext_vector_type(4)));

__device__ __forceinline__ unsigned short f2bf(float x) {
    unsigned int u = __float_as_uint(x);
    u = u + 0x7fffu + ((u >> 16) & 1u);            // round-to-nearest-even
    return (unsigned short)(u >> 16);
}
__device__ __forceinline__ float bf2f(unsigned short b) {
    return __uint_as_float(((unsigned int)b) << 16);
}

// ---------------------------------------------------------------------------
// kNN body: exact stable-argsort ranks 1..8 by (d2, index).
__device__ __forceinline__ void knn_body(int b, const float* __restrict__ src,
                                         int ld, int* __restrict__ nbr,
                                         float (*cs)[3]) {
    int t = threadIdx.x;
    if (t < Jj) {
        const float* p = src + (size_t)(b * Jj + t) * ld;
        cs[t][0] = p[0]; cs[t][1] = p[1]; cs[t][2] = p[2];
    }
    __syncthreads();
    if (t < Jj) {
        float x = cs[t][0], y = cs[t][1], z = cs[t][2];
        float d2[Jj];
        #pragma unroll
        for (int jj = 0; jj < Jj; ++jj) {
            float dx = x - cs[jj][0], dy = y - cs[jj][1], dz = z - cs[jj][2];
            d2[jj] = dx*dx + dy*dy + dz*dz;
        }
        unsigned int used = 0u;
        int out_base = (b * Jj + t) * KNN;
        #pragma unroll
        for (int r = 0; r <= KNN; ++r) {
            int best = -1; float bd = INFINITY;
            #pragma unroll
            for (int jj = 0; jj < Jj; ++jj)
                if (!((used >> jj) & 1u) && d2[jj] < bd) { bd = d2[jj]; best = jj; }
            used |= (1u << best);
            if (r > 0) nbr[out_base + r - 1] = best;
        }
    }
}

// ---------------------------------------------------------------------------
// MEGA-PREP: one launch for all input-only work.
__global__ __launch_bounds__(256)
void mega_prep_kernel(const float* __restrict__ jf,
                      const float* __restrict__ wq, const float* __restrict__ wk,
                      const float* __restrict__ wv, const float* __restrict__ wp,
                      const float* __restrict__ wsw, const float* __restrict__ wsk,
                      unsigned short* __restrict__ wqkvT,
                      unsigned short* __restrict__ fbt, float* __restrict__ stats,
                      float* __restrict__ wsum,
                      unsigned short* __restrict__ jfb, _Float16* __restrict__ jfh,
                      _Float16* __restrict__ jfl, _Float16* __restrict__ jfd,
                      _Float16* __restrict__ GT, float* __restrict__ Wvp2,
                      int* __restrict__ nbr0) {
    __shared__ __align__(16) char sm[17408];
    int bid = blockIdx.x;
    int tidx = threadIdx.x;

    if (bid < 4352) {                      // ---- weight transposes ----
        const float* src; unsigned short* dst;
        int ldin, ldout, tilesX, tile;
        constexpr size_t CH = (size_t)Cc * HD;
        if (bid < 3072) {
            int op = bid >> 9; tile = bid & 511; tilesX = 64;
            ldin = HD; ldout = Cc;
            const float* s3[3] = {wq, wk, wv};
            src = s3[op % 3] + (size_t)(op / 3) * CH;
            dst = wqkvT + (size_t)(op % 3) * HD * Cc + (size_t)(op / 3) * QKVN * Cc;
        } else if (bid < 4096) {
            int op = (bid - 3072) >> 9; tile = (bid - 3072) & 511; tilesX = 8;
            ldin = Cc; ldout = KFUSE;
            src = wp + (size_t)op * HD * Cc;
            dst = fbt + (size_t)op * Cc * KFUSE;
        } else {
            int q = bid - 4096; int op = q >> 6; tile = q & 63; tilesX = 8;
            ldin = Cc; ldout = KFUSE;
            const float* s4[4] = {wsw, wsw + (size_t)Cc * Cc, wsk, wsk};
            src = s4[op];
            dst = fbt + (size_t)(op & 1) * Cc * KFUSE + HD + (size_t)(op >> 1) * Cc;
        }
        int bx = tile % tilesX, by = tile / tilesX;
        int n0 = bx * 32, k0 = by * 32;
        float (*t)[33] = (float(*)[33])sm;
        int r = tidx >> 3, c4 = (tidx & 7) * 4;
        float4 v = *(const float4*)&src[(size_t)(k0 + r) * ldin + n0 + c4];
        t[r][c4+0] = v.x; t[r][c4+1] = v.y; t[r][c4+2] = v.z; t[r][c4+3] = v.w;
        __syncthreads();
        ushort4 o;
        o.x = f2bf(t[c4+0][r]); o.y = f2bf(t[c4+1][r]);
        o.z = f2bf(t[c4+2][r]); o.w = f2bf(t[c4+3][r]);
        *(ushort4*)&dst[(size_t)(n0 + r) * ldout + k0 + c4] = o;
    } else if (bid == 4352) {              // ---- wsum + stats zero ----
        int e = tidx;
        float4 o;
        o.x = wsw[(size_t)e*Dd + 0] + wsk[(size_t)e*Dd + 0];
        o.y = wsw[(size_t)e*Dd + 1] + wsk[(size_t)e*Dd + 1];
        o.z = wsw[(size_t)e*Dd + 2] + wsk[(size_t)e*Dd + 2];
        o.w = 0.0f;
        *(float4*)&wsum[e*4] = o;
        if (e < 2) stats[e] = 0.0f;
    } else if (bid < 5697) {               // ---- cvt_split ----
        int i = (bid - 4353) * 256 + tidx;
        float4 v = ((const float4*)jf)[i];
        float x[4] = {v.x, v.y, v.z, v.w};
        ushort4 ob; half4v oh, ol, od;
        #pragma unroll
        for (int u = 0; u < 4; ++u) {
            ((unsigned short*)&ob)[u] = f2bf(x[u]);
            _Float16 h = (_Float16)x[u];
            oh[u] = h;
            ol[u] = (_Float16)((x[u] - (float)h) * 16.0f);
            od[u] = (_Float16)(x[u] * 0.0078125f);   // /128
        }
        ((ushort4*)jfb)[i] = ob;
        ((half4v*)jfh)[i] = oh;
        ((half4v*)jfl)[i] = ol;
        ((half4v*)jfd)[i] = od;
    } else if (bid < 5825) {               // ---- g_gemm -> GT (fp16-split) ----
        int q = bid - 5697;
        int h = q >> 4, rem = q & 15;
        int m0 = (rem >> 2) * 64, n0 = (rem & 3) * 64;
        float (*As)[68] = (float(*)[68])sm;
        float (*Ws)[68] = (float(*)[68])(sm + 8704);
        int ty = tidx >> 4, tx = tidx & 15;
        float acc[4][4] = {};
        for (int kb = 0; kb < 256; kb += 32) {
            #pragma unroll
            for (int it = 0; it < 2; ++it) {
                int c = tidx + it * 256;
                int row = c >> 3, col = (c & 7) * 4;
                float4 v = *(const float4*)&wq[(size_t)(m0 + row)*HD + h*256 + kb + col];
                float4 u = *(const float4*)&wk[(size_t)(n0 + row)*HD + h*256 + kb + col];
                As[col+0][row] = v.x; As[col+1][row] = v.y;
                As[col+2][row] = v.z; As[col+3][row] = v.w;
                Ws[col+0][row] = u.x; Ws[col+1][row] = u.y;
                Ws[col+2][row] = u.z; Ws[col+3][row] = u.w;
            }
            __syncthreads();
            #pragma unroll
            for (int kk = 0; kk < 32; ++kk) {
                float4 a = *(const float4*)&As[kk][ty*4];
                float4 b = *(const float4*)&Ws[kk][tx*4];
                float av[4] = {a.x, a.y, a.z, a.w};
                float bv[4] = {b.x, b.y, b.z, b.w};
                #pragma unroll
                for (int i = 0; i < 4; ++i)
                    #pragma unroll
                    for (int j = 0; j < 4; ++j)
                        acc[i][j] += av[i] * bv[j];
            }
            __syncthreads();
        }
        #pragma unroll
        for (int j = 0; j < 4; ++j) {
            int n = h*256 + n0 + tx*4 + j;
            half4v hi, hs, lo;
            #pragma unroll
            for (int i = 0; i < 4; ++i) {
                float g = acc[i][j];
                _Float16 gh = (_Float16)g;
                hi[i] = gh;
                hs[i] = (_Float16)(g * 0.0625f);
                lo[i] = (_Float16)((g - (float)gh) * 128.0f);
            }
            _Float16* base = &GT[(size_t)n*768 + m0 + ty*4];
            *(half4v*)(base)       = hi;
            *(half4v*)(base + 256) = hs;
            *(half4v*)(base + 512) = lo;
        }
    } else if (bid < 5833) {               // ---- wvp ----
        int h = bid - 5825;
        float (*wpc)[3] = (float(*)[3])sm;
        int t = tidx;
        const float* p = &wp[(size_t)(h*256 + t) * Cc];
        wpc[t][0] = p[0]; wpc[t][1] = p[1]; wpc[t][2] = p[2];
        __syncthreads();
        const float* vr = &wv[(size_t)t*HD + h*256];
        float a0=0, a1=0, a2=0;
        for (int d = 0; d < 256; ++d) {
            float v = vr[d];
            a0 += v*wpc[d][0]; a1 += v*wpc[d][1]; a2 += v*wpc[d][2];
        }
        float* o = &Wvp2[(size_t)t*24 + h*3];
        o[0]=a0; o[1]=a1; o[2]=a2;
    } else {                               // ---- knn layer 0 ----
        knn_body(bid - 5833, jf, Cc, nbr0, (float(*)[3])sm);
    }
}

// ---------------------------------------------------------------------------
// 16-bit MFMA GEMM core, XOR-swizzled LDS.
template<int BM, int BN, int BK, int NSEG, bool RELU_STATS, bool OUT_BF16, bool F16>
__device__ __forceinline__
void gemm_core(unsigned short* As, unsigned short* Bs, float* red,
               int bm, int bn,
               const unsigned short* __restrict__ A0, int lda0, int klen0,
               const unsigned short* __restrict__ A1, int lda1, int klen1,
               const unsigned short* __restrict__ A2, int lda2, int klen2,
               const unsigned short* __restrict__ Bt, int ldb,
               void* __restrict__ Cv, int ldc, float* __restrict__ stat) {
    constexpr int WM = BM/2, WN = BN/2;
    constexpr int MW = WM/16, NW = WN/16, KW = BK/32;
    constexpr int CHUNKA = BM*BK/8;
    constexpr int CHUNKB = BN*BK/8;
    constexpr int KB8 = BK/8;
    constexpr int SWZ = KB8 - 1;
    using frag = std::conditional_t<F16, half8, short8>;

    int tid = threadIdx.x;
    int wid = tid >> 6, lane = tid & 63;
    int wr = wid >> 1, wc = wid & 1;

    f32x4 acc[MW][NW];
    #pragma unroll
    for (int m = 0; m < MW; ++m)
        #pragma unroll
        for (int n = 0; n < NW; ++n)
            acc[m][n] = (f32x4){0.f, 0.f, 0.f, 0.f};

    const unsigned short* Aseg[3] = {A0, A1, A2};
    const int ldas[3] = {lda0, lda1, lda2};
    const int klens[3] = {klen0, klen1, klen2};

    int kglob = 0;
    for (int seg = 0; seg < NSEG; ++seg) {
        const unsigned short* A = Aseg[seg];
        const int lda = ldas[seg];
        const int klen = klens[seg];
        for (int k0 = 0; k0 < klen; k0 += BK) {
            #pragma unroll
            for (int it = 0; it < CHUNKA/256; ++it) {
                int c = tid + it*256;
                int row = c / KB8;
                int kp = (c % KB8) ^ (row & SWZ);
                __builtin_amdgcn_global_load_lds(
                    (const __attribute__((address_space(1))) unsigned int*)
                        (A + (size_t)(bm + row)*lda + k0 + kp*8),
                    (__attribute__((address_space(3))) unsigned int*)(As + c*8),
                    16, 0, 0);
            }
            #pragma unroll
            for (int it = 0; it < CHUNKB/256; ++it) {
                int c = tid + it*256;
                int row = c / KB8;
                int kp = (c % KB8) ^ (row & SWZ);
                __builtin_amdgcn_global_load_lds(
                    (const __attribute__((address_space(1))) unsigned int*)
                        (Bt + (size_t)(bn + row)*ldb + kglob + k0 + kp*8),
                    (__attribute__((address_space(3))) unsigned int*)(Bs + c*8),
                    16, 0, 0);
            }
            __syncthreads();
            #pragma unroll
            for (int kp = 0; kp < KW; ++kp) {
                frag af[MW], bf[NW];
                int cbase = kp*4 + (lane >> 4);
                #pragma unroll
                for (int m = 0; m < MW; ++m) {
                    int r = wr*WM + m*16 + (lane & 15);
                    af[m] = *(const frag*)&As[r*BK + ((cbase ^ (r & SWZ))*8)];
                }
                #pragma unroll
                for (int n = 0; n < NW; ++n) {
                    int r = wc*WN + n*16 + (lane & 15);
                    bf[n] = *(const frag*)&Bs[r*BK + ((cbase ^ (r & SWZ))*8)];
                }
                #pragma unroll
                for (int m = 0; m < MW; ++m)
                    #pragma unroll
                    for (int n = 0; n < NW; ++n) {
                        if constexpr (F16)
                            acc[m][n] = __builtin_amdgcn_mfma_f32_16x16x32_f16(
                                af[m], bf[n], acc[m][n], 0, 0, 0);
                        else
                            acc[m][n] = __builtin_amdgcn_mfma_f32_16x16x32_bf16(
                                af[m], bf[n], acc[m][n], 0, 0, 0);
                    }
            }
            __syncthreads();
        }
        kglob += klen;
    }

    int cr = (lane >> 4)*4, cc = lane & 15;
    float bsum = 0.0f;
    #pragma unroll
    for (int m = 0; m < MW; ++m)
        #pragma unroll
        for (int n = 0; n < NW; ++n)
            #pragma unroll
            for (int j = 0; j < 4; ++j) {
                float v = acc[m][n][j];
                if (RELU_STATS) { v = fmaxf(v, 0.0f); bsum += v; }
                size_t row = bm + wr*WM + m*16 + cr + j;
                size_t col = bn + wc*WN + n*16 + cc;
                if (OUT_BF16) ((unsigned short*)Cv)[row*ldc + col] = f2bf(v);
                else          ((float*)Cv)[row*ldc + col] = v;
            }
    if (RELU_STATS) {
        #pragma unroll
        for (int sft = 1; sft < 64; sft <<= 1) bsum += __shfl_xor(bsum, sft);
        if (lane == 0) red[wid] = bsum;
        __syncthreads();
        if (tid == 0) atomicAdd(stat, red[0] + red[1] + red[2] + red[3]);
    }
}

// ---------------------------------------------------------------------------
// COMBO: y<48 -> layer-0 QKV gemm (XCD-chunked); y in [48,64) -> fp16-split
// T-gemm (XCD-chunked); y in [64,80) -> vproj. All independent.
__global__ __launch_bounds__(256)
void combo_kernel(const unsigned short* __restrict__ jfb,
                  const unsigned short* __restrict__ wqkvT,
                  unsigned short* __restrict__ QKVb,
                  const _Float16* __restrict__ jfh, const _Float16* __restrict__ jfl,
                  const _Float16* __restrict__ jfd, const _Float16* __restrict__ GT,
                  float* __restrict__ Tm,
                  const float* __restrict__ jf, const float* __restrict__ Wvp2,
                  float* __restrict__ vproj) {
    __shared__ __align__(16) char smem[32784];
    unsigned short* As = (unsigned short*)smem;
    unsigned short* Bs = (unsigned short*)(smem + 16384);
    float* red = (float*)(smem + 32768);
    int x = blockIdx.x, y = blockIdx.y;
    if (y < 48) {
        int lb = x + 42*y;
        int nb = (lb & 7) * 252 + (lb >> 3);
        int sx = nb % 42, sy = nb / 42;
        gemm_core<128,128,64,1,false,true,false>(As, Bs, red, sx*128, sy*128,
            jfb, Cc, Cc, jfb, Cc, 0, jfb, Cc, 0, wqkvT, Cc, QKVb, QKVN, nullptr);
    } else if (y < 64) {
        int lb = x + 42*(y - 48);
        int nb = (lb & 7) * 84 + (lb >> 3);
        int sx = nb / 16, sy = nb % 16;
        gemm_core<128,128,64,3,false,false,true>(As, Bs, red, sx*128, sy*128,
            (const unsigned short*)jfh, Cc, Cc, (const unsigned short*)jfl, Cc, Cc,
            (const unsigned short*)jfd, Cc, Cc, (const unsigned short*)GT, 768,
            Tm, HD, nullptr);
    } else {
        int q = (y - 64) * 42 + x;
        float (*hr)[256] = (float(*)[256])smem;
        float* wl = (float*)(smem + 8192);
        int t = threadIdx.x;
        int j0 = q * 8;
        #pragma unroll
        for (int i = 0; i < 6; ++i)
            *(float4*)&wl[t*4 + i*1024] = *(const float4*)&Wvp2[t*4 + i*1024];
        {
            int r = t >> 5, c = (t & 31) * 8;
            const float* src = &jf[(size_t)(j0 + r)*Cc + c];
            *(float4*)&hr[r][c]   = *(const float4*)src;
            *(float4*)&hr[r][c+4] = *(const float4*)(src + 4);
        }
        __syncthreads();
        int r = t >> 5, o = t & 31;
        if (o < 24) {
            float a = 0.0f;
            for (int e = 0; e < 256; ++e) a += hr[r][e] * wl[e*24 + o];
            vproj[(size_t)(j0 + r)*24 + o] = a;
        }
    }
}

// ---------------------------------------------------------------------------
// layer-1 QKV gemm with XCD-chunked swizzle (grid 42x48, 2016 blocks).
__global__ __launch_bounds__(256)
void qkv1_kernel(const unsigned short* __restrict__ h1b,
                 const unsigned short* __restrict__ wqkvT1,
                 unsigned short* __restrict__ QKVb) {
    __shared__ __align__(16) unsigned short As[128*64];
    __shared__ __align__(16) unsigned short Bs[128*64];
    __shared__ float red[4];
    int lb = blockIdx.x + 42*blockIdx.y;
    int nb = (lb & 7) * 252 + (lb >> 3);
    int sx = nb % 42, sy = nb / 42;
    gemm_core<128,128,64,1,false,true,false>(
        As, Bs, red, sx*128, sy*128,
        h1b, Cc, Cc, h1b, Cc, 0, h1b, Cc, 0, wqkvT1, Cc, QKVb, QKVN, nullptr);
}

// ---------------------------------------------------------------------------
// fused epilogue gemm (+ optional layer-1 kNN in extra y-blocks)
template<bool OUT_BF16, bool DO_KNN>
__global__ __launch_bounds__(256)
void fused_kernel(const unsigned short* __restrict__ att,
                  const unsigned short* __restrict__ hseg,
                  const unsigned short* __restrict__ h0seg,
                  const unsigned short* __restrict__ fbtL,
                  void* __restrict__ Cv, float* __restrict__ stat,
                  const float* __restrict__ crd, int* __restrict__ nbr1) {
    __shared__ __align__(16) char smem[16400];
    if (DO_KNN && blockIdx.y >= 4) {
        int b = (blockIdx.y - 4) * 84 + blockIdx.x;
        if (b < Bb) knn_body(b, crd, 4, nbr1, (float(*)[3])smem);
        return;
    }
    unsigned short* As = (unsigned short*)smem;
    unsigned short* Bs = (unsigned short*)(smem + 8192);
    float* red = (float*)(smem + 16384);
    gemm_core<64,64,64,3,true,OUT_BF16,false>(
        As, Bs, red, blockIdx.x*64, blockIdx.y*64,
        att, HD, HD, hseg, Cc, Cc, h0seg, Cc, Cc,
        fbtL, KFUSE, Cv, Cc, stat);
}

// ---------------------------------------------------------------------------
// precise layer-0 coords
__global__ __launch_bounds__(64)
void precise_kernel(const float* __restrict__ T, const float* __restrict__ h0,
                    const int* __restrict__ nbr, const float* __restrict__ vproj,
                    const float* __restrict__ wsum, float* __restrict__ crd) {
    int i = blockIdx.x;
    int b = i / Jj;
    int l = threadIdx.x;
    __shared__ float Ts[8][260];
    __shared__ float nb[8][260];
    __shared__ float hi[256];
    #pragma unroll
    for (int u = 0; u < 8; ++u) {
        int idx = u*64 + l;
        float4 v = *(const float4*)&T[(size_t)i*HD + idx*4];
        int hh = idx >> 6, dd = (idx & 63) * 4;
        *(float4*)&Ts[hh][dd] = v;
    }
    *(float4*)&hi[l*4] = *(const float4*)&h0[(size_t)i*Cc + l*4];
    int kq = l >> 3, s = l & 7;
    int njs = nbr[i*KNN + kq];
    const float* nrow = &h0[(size_t)(b*Jj + njs)*Cc];
    #pragma unroll
    for (int u = 0; u < 8; ++u)
        *(float4*)&nb[kq][(s*8+u)*4] = *(const float4*)&nrow[(s*8+u)*4];
    __syncthreads();

    int k = l >> 3, h = l & 7;
    float sacc = 0;
    #pragma unroll 8
    for (int d = 0; d < 256; d += 4) {
        float4 tv = *(const float4*)&Ts[h][d];
        float4 nv = *(const float4*)&nb[k][d];
        sacc += tv.x*nv.x + tv.y*nv.y + tv.z*nv.z + tv.w*nv.w;
    }
    float sc = sacc * 0.0625f;
    sc = (sc >= 0.0f) ? sc : 0.2f * sc;
    float m = sc;
    m = fmaxf(m, __shfl_xor(m, 8));
    m = fmaxf(m, __shfl_xor(m, 16));
    m = fmaxf(m, __shfl_xor(m, 32));
    float e = expf(sc - m);
    float den = e;
    den += __shfl_xor(den, 8); den += __shfl_xor(den, 16); den += __shfl_xor(den, 32);
    float w = e / den;

    int njk = nbr[i*KNN + k];
    const float* vp = &vproj[(size_t)(b*Jj + njk)*24 + h*3];
    float t0 = w * vp[0], t1 = w * vp[1], t2 = w * vp[2];
    #pragma unroll
    for (int u = 0; u < 4; ++u) {
        int e4 = l*4 + u;
        float hv = hi[e4];
        float4 wv = *(const float4*)&wsum[e4*4];
        t0 += hv * wv.x; t1 += hv * wv.y; t2 += hv * wv.z;
    }
    #pragma unroll
    for (int sft = 1; sft < 64; sft <<= 1) {
        t0 += __shfl_xor(t0, sft); t1 += __shfl_xor(t1, sft); t2 += __shfl_xor(t2, sft);
    }
    if (l == 0) {
        crd[i*4+0] = fmaxf(t0, 0.0f);
        crd[i*4+1] = fmaxf(t1, 0.0f);
        crd[i*4+2] = fmaxf(t2, 0.0f);
        crd[i*4+3] = 0.0f;
    }
}

// ---------------------------------------------------------------------------
// attention: one wave per (row, head-pair); XCD-chunked block remap so each
// XCD owns 672 contiguous rows (32 whole batches, K/V gather set ~2.7MB < L2).
__global__ __launch_bounds__(64)
void attn_kernel(const unsigned short* __restrict__ QKV,
                 const int* __restrict__ nbr, unsigned short* __restrict__ att) {
    int lb = blockIdx.x;
    int gid = (lb & 7) * (Mrows*4/8) + (lb >> 3);   // bijective: 21504 % 8 == 0
    int hp = gid & 3, row = gid >> 2, b = row / Jj;
    int lane = threadIdx.x;
    int h = hp*2 + (lane >> 5);
    int d0 = (lane & 31) * 8;

    u16x8 qu = *(const u16x8*)&QKV[(size_t)row*QKVN + h*Dd + d0];
    float qf[8];
    #pragma unroll
    for (int i = 0; i < 8; ++i) qf[i] = bf2f(qu[i]);
    const int* np_ = nbr + row * KNN;

    float sc[KNN]; int nb[KNN];
    #pragma unroll
    for (int k = 0; k < KNN; ++k) {
        int n = np_[k]; nb[k] = n;
        u16x8 ku = *(const u16x8*)&QKV[(size_t)(b*Jj + n)*QKVN + HD + h*Dd + d0];
        float p = 0;
        #pragma unroll
        for (int i = 0; i < 8; ++i) p += qf[i] * bf2f(ku[i]);
        #pragma unroll
        for (int s = 1; s < 32; s <<= 1) p += __shfl_xor(p, s);
        sc[k] = p;
    }
    float mx = -INFINITY;
    #pragma unroll
    for (int k = 0; k < KNN; ++k) {
        float s = sc[k] * 0.0625f;
        s = (s >= 0.0f) ? s : 0.2f * s;
        sc[k] = s; mx = fmaxf(mx, s);
    }
    float den = 0.0f;
    #pragma unroll
    for (int k = 0; k < KNN; ++k) { sc[k] = expf(sc[k] - mx); den += sc[k]; }
    float inv = 1.0f / den;
    float o[8] = {};
    #pragma unroll
    for (int k = 0; k < KNN; ++k) {
        u16x8 vu = *(const u16x8*)&QKV[(size_t)(b*Jj + nb[k])*QKVN + 2*HD + h*Dd + d0];
        float w = sc[k] * inv;
        #pragma unroll
        for (int i = 0; i < 8; ++i) o[i] += w * bf2f(vu[i]);
    }
    u16x8 ou;
    #pragma unroll
    for (int i = 0; i < 8; ++i) ou[i] = f2bf(o[i]);
    *(u16x8*)&att[(size_t)row*HD + h*Dd + d0] = ou;
}

// ---------------------------------------------------------------------------
__global__ __launch_bounds__(64)
void final_kernel(const float* __restrict__ h, const float* __restrict__ fcw,
                  const float* __restrict__ fcb, const float* __restrict__ stats,
                  float* __restrict__ out) {
    int row = blockIdx.x, lane = threadIdx.x;
    const float4 hv = *(const float4*)(h + (size_t)row*Cc + lane*4);
    float a0=0, a1=0, a2=0;
    const float hx[4] = {hv.x, hv.y, hv.z, hv.w};
    #pragma unroll
    for (int i = 0; i < 4; ++i) {
        int c = lane*4 + i;
        a0 += hx[i]*fcw[c*3+0]; a1 += hx[i]*fcw[c*3+1]; a2 += hx[i]*fcw[c*3+2];
    }
    #pragma unroll
    for (int s = 32; s > 0; s >>= 1) {
        a0 += __shfl_xor(a0, s); a1 += __shfl_xor(a1, s); a2 += __shfl_xor(a2, s);
    }
    if (lane == 0) {
        out[row*3+0] = a0 + fcb[0];
        out[row*3+1] = a1 + fcb[1];
        out[row*3+2] = a2 + fcb[2];
        if (row == 0)
            out[(size_t)Mrows*3] =
                (stats[0] + stats[1]) * (0.5f / ((float)Mrows * (float)Cc));
    }
}

// ---------------------------------------------------------------------------
extern "C" void kernel_launch(void* const* d_in, const int* in_sizes, int n_in,
                              void* d_out, int out_size, void* d_ws, size_t ws_size,
                              hipStream_t stream) {
    (void)in_sizes; (void)n_in; (void)out_size; (void)ws_size;
    const float* jf     = (const float*)d_in[0];
    const float* wq     = (const float*)d_in[1];
    const float* wk     = (const float*)d_in[2];
    const float* wv     = (const float*)d_in[3];
    const float* wp     = (const float*)d_in[4];
    const float* wsw    = (const float*)d_in[5];
    const float* wskip0 = (const float*)d_in[6];
    const float* fcw    = (const float*)d_in[7];
    const float* fcb    = (const float*)d_in[8];
    float* out = (float*)d_out;

    char* wsb = (char*)d_ws;
    unsigned short* QKVb  = (unsigned short*)(wsb + OFF_QKV);
    float*          Tm    = (float*)(wsb + OFF_T);
    unsigned short* attb  = (unsigned short*)(wsb + OFF_ATT);   // aliases T
    _Float16*       GT    = (_Float16*)(wsb + OFF_GT);
    unsigned short* jfb   = (unsigned short*)(wsb + OFF_JFB);
    _Float16*       jfh   = (_Float16*)(wsb + OFF_JFH);
    _Float16*       jfl   = (_Float16*)(wsb + OFF_JFL);
    _Float16*       jfd   = (_Float16*)(wsb + OFF_JFD);
    unsigned short* h1b   = (unsigned short*)(wsb + OFF_H1B);
    float*          h2f   = (float*)(wsb + OFF_H2F);
    unsigned short* wqkvT = (unsigned short*)(wsb + OFF_WQKVT);
    unsigned short* fbt   = (unsigned short*)(wsb + OFF_FBT);
    float*          Wvp   = (float*)(wsb + OFF_WVP);
    float*          vproj = (float*)(wsb + OFF_VPROJ);
    float*          wsum  = (float*)(wsb + OFF_WSUM);
    float*          crd   = (float*)(wsb + OFF_CRD);
    int*            nbr0  = (int*)(wsb + OFF_NBR0);
    int*            nbr1  = (int*)(wsb + OFF_NBR1);
    float*          stats = (float*)(wsb + OFF_STAT);

    // 1. all input-only prep in one launch
    mega_prep_kernel<<<6089, 256, 0, stream>>>(jf, wq, wk, wv, wp, wsw, wskip0,
                                               wqkvT, fbt, stats, wsum,
                                               jfb, jfh, jfl, jfd, GT, Wvp, nbr0);
    // 2. layer-0 QKV gemm + fp16-split T-gemm + vproj in one launch
    combo_kernel<<<dim3(42, 80), 256, 0, stream>>>(jfb, wqkvT, QKVb,
                                                   jfh, jfl, jfd, GT, Tm,
                                                   jf, Wvp, vproj);
    // 3. precise layer-0 coords (consumes Tm; attb overwrites it after)
    precise_kernel<<<Mrows, 64, 0, stream>>>(Tm, jf, nbr0, vproj, wsum, crd);
    // 4. layer-0 attention (XCD-chunked)
    attn_kernel<<<Mrows*4, 64, 0, stream>>>(QKVb, nbr0, attb);
    // 5. layer-0 fused output gemm + layer-1 kNN
    fused_kernel<true, true><<<dim3(84, 8), 256, 0, stream>>>(
        attb, jfb, jfb, fbt, h1b, &stats[0], crd, nbr1);
    // 6. layer-1 QKV gemm (XCD-chunked)
    qkv1_kernel<<<dim3(42, 48), 256, 0, stream>>>(h1b, wqkvT + (size_t)QKVN*Cc, QKVb);
    // 7. layer-1 attention (XCD-chunked)
    attn_kernel<<<Mrows*4, 64, 0, stream>>>(QKVb, nbr1, attb);
    // 8. layer-1 fused output gemm
    fused_kernel<false, false><<<dim3(84, 4), 256, 0, stream>>>(
        attb, h1b, jfb, fbt + (size_t)Cc*KFUSE, h2f, &stats[1], nullptr, nullptr);
    // 9. final
    final_kernel<<<Mrows, 64, 0, stream>>>(h2f, fcw, fcb, stats, out);
}

// Round 15
// 205.058 us; speedup vs baseline: 1.2940x; 1.1299x over previous
//
#include <hip/hip_runtime.h>
#include <hip/hip_bf16.h>
#include <math.h>
#include <type_traits>

namespace {
constexpr int Bb = 256, Jj = 21, Cc = 256, Hh = 8, Dd = 256;
constexpr int Mrows = Bb * Jj;      // 5376
constexpr int HD    = Hh * Dd;      // 2048
constexpr int QKVN  = 3 * HD;       // 6144
constexpr int KNN   = 8;
constexpr int KFUSE = HD + Cc + Cc; // 2560

// ---- workspace byte offsets ----
// attb aliases the T region: T dead after precise_kernel, attn runs later.
constexpr size_t OFF_QKV   = 0;                                   // bf16 5376x6144
constexpr size_t OFF_T     = OFF_QKV   + (size_t)Mrows*QKVN*2;    // f32  5376x2048
constexpr size_t OFF_ATT   = OFF_T;                               // bf16 5376x2048 (alias)
constexpr size_t OFF_GT    = OFF_T     + (size_t)Mrows*HD*4;      // f16  2048x768
constexpr size_t OFF_JFB   = OFF_GT    + (size_t)HD*768*2;        // bf16 5376x256
constexpr size_t OFF_JFH   = OFF_JFB   + (size_t)Mrows*Cc*2;      // f16  5376x256
constexpr size_t OFF_JFL   = OFF_JFH   + (size_t)Mrows*Cc*2;      // f16  5376x256
constexpr size_t OFF_JFD   = OFF_JFL   + (size_t)Mrows*Cc*2;      // f16  5376x256
constexpr size_t OFF_H1B   = OFF_JFD   + (size_t)Mrows*Cc*2;      // bf16 5376x256
constexpr size_t OFF_H2F   = OFF_H1B   + (size_t)Mrows*Cc*2;      // f32  5376x256
constexpr size_t OFF_WQKVT = OFF_H2F   + (size_t)Mrows*Cc*4;      // bf16 2x6144x256
constexpr size_t OFF_FBT   = OFF_WQKVT + (size_t)2*QKVN*Cc*2;     // bf16 2x256x2560
constexpr size_t OFF_WVP   = OFF_FBT   + (size_t)2*Cc*KFUSE*2;    // f32  256x24
constexpr size_t OFF_VPROJ = OFF_WVP   + (size_t)Cc*24*4;         // f32  5376x24
constexpr size_t OFF_WSUM  = OFF_VPROJ + (size_t)Mrows*24*4;      // f32  256x4
constexpr size_t OFF_CRD   = OFF_WSUM  + (size_t)Cc*4*4;          // f32  5376x4
constexpr size_t OFF_NBR0  = OFF_CRD   + (size_t)Mrows*4*4;       // int  5376x8
constexpr size_t OFF_NBR1  = OFF_NBR0  + (size_t)Mrows*KNN*4;
constexpr size_t OFF_W0    = OFF_NBR1  + (size_t)Mrows*KNN*4;     // f32  5376x64
constexpr size_t OFF_STAT  = OFF_W0    + (size_t)Mrows*64*4;      // 2 f32
} // namespace

typedef short short8 __attribute__((ext_vector_type(8)));
typedef _Float16 half8 __attribute__((ext_vector_type(8)));
typedef _Float16 half4v __attribute__((ext_vector_type(4)));
typedef unsigned short u16x8 __attribute__((ext_vector_type(8)));
typedef float f32x4 __attribute__((ext_vector_type(4)));

__device__ __forceinline__ unsigned short f2bf(float x) {
    unsigned int u = __float_as_uint(x);
    u = u + 0x7fffu + ((u >> 16) & 1u);            // round-to-nearest-even
    return (unsigned short)(u >> 16);
}
__device__ __forceinline__ float bf2f(unsigned short b) {
    return __uint_as_float(((unsigned int)b) << 16);
}

// ---------------------------------------------------------------------------
// kNN body: exact stable-argsort ranks 1..8 by (d2, index).
__device__ __forceinline__ void knn_body(int b, const float* __restrict__ src,
                                         int ld, int* __restrict__ nbr,
                                         float (*cs)[3]) {
    int t = threadIdx.x;
    if (t < Jj) {
        const float* p = src + (size_t)(b * Jj + t) * ld;
        cs[t][0] = p[0]; cs[t][1] = p[1]; cs[t][2] = p[2];
    }
    __syncthreads();
    if (t < Jj) {
        float x = cs[t][0], y = cs[t][1], z = cs[t][2];
        float d2[Jj];
        #pragma unroll
        for (int jj = 0; jj < Jj; ++jj) {
            float dx = x - cs[jj][0], dy = y - cs[jj][1], dz = z - cs[jj][2];
            d2[jj] = dx*dx + dy*dy + dz*dz;
        }
        unsigned int used = 0u;
        int out_base = (b * Jj + t) * KNN;
        #pragma unroll
        for (int r = 0; r <= KNN; ++r) {
            int best = -1; float bd = INFINITY;
            #pragma unroll
            for (int jj = 0; jj < Jj; ++jj)
                if (!((used >> jj) & 1u) && d2[jj] < bd) { bd = d2[jj]; best = jj; }
            used |= (1u << best);
            if (r > 0) nbr[out_base + r - 1] = best;
        }
    }
}

// ---------------------------------------------------------------------------
// MEGA-PREP: one launch for all input-only work.
__global__ __launch_bounds__(256)
void mega_prep_kernel(const float* __restrict__ jf,
                      const float* __restrict__ wq, const float* __restrict__ wk,
                      const float* __restrict__ wv, const float* __restrict__ wp,
                      const float* __restrict__ wsw, const float* __restrict__ wsk,
                      unsigned short* __restrict__ wqkvT,
                      unsigned short* __restrict__ fbt, float* __restrict__ stats,
                      float* __restrict__ wsum,
                      unsigned short* __restrict__ jfb, _Float16* __restrict__ jfh,
                      _Float16* __restrict__ jfl, _Float16* __restrict__ jfd,
                      _Float16* __restrict__ GT, float* __restrict__ Wvp2,
                      int* __restrict__ nbr0) {
    __shared__ __align__(16) char sm[17408];
    int bid = blockIdx.x;
    int tidx = threadIdx.x;

    if (bid < 4352) {                      // ---- weight transposes ----
        const float* src; unsigned short* dst;
        int ldin, ldout, tilesX, tile;
        constexpr size_t CH = (size_t)Cc * HD;
        if (bid < 3072) {
            int op = bid >> 9; tile = bid & 511; tilesX = 64;
            ldin = HD; ldout = Cc;
            const float* s3[3] = {wq, wk, wv};
            src = s3[op % 3] + (size_t)(op / 3) * CH;
            dst = wqkvT + (size_t)(op % 3) * HD * Cc + (size_t)(op / 3) * QKVN * Cc;
        } else if (bid < 4096) {
            int op = (bid - 3072) >> 9; tile = (bid - 3072) & 511; tilesX = 8;
            ldin = Cc; ldout = KFUSE;
            src = wp + (size_t)op * HD * Cc;
            dst = fbt + (size_t)op * Cc * KFUSE;
        } else {
            int q = bid - 4096; int op = q >> 6; tile = q & 63; tilesX = 8;
            ldin = Cc; ldout = KFUSE;
            const float* s4[4] = {wsw, wsw + (size_t)Cc * Cc, wsk, wsk};
            src = s4[op];
            dst = fbt + (size_t)(op & 1) * Cc * KFUSE + HD + (size_t)(op >> 1) * Cc;
        }
        int bx = tile % tilesX, by = tile / tilesX;
        int n0 = bx * 32, k0 = by * 32;
        float (*t)[33] = (float(*)[33])sm;
        int r = tidx >> 3, c4 = (tidx & 7) * 4;
        float4 v = *(const float4*)&src[(size_t)(k0 + r) * ldin + n0 + c4];
        t[r][c4+0] = v.x; t[r][c4+1] = v.y; t[r][c4+2] = v.z; t[r][c4+3] = v.w;
        __syncthreads();
        ushort4 o;
        o.x = f2bf(t[c4+0][r]); o.y = f2bf(t[c4+1][r]);
        o.z = f2bf(t[c4+2][r]); o.w = f2bf(t[c4+3][r]);
        *(ushort4*)&dst[(size_t)(n0 + r) * ldout + k0 + c4] = o;
    } else if (bid == 4352) {              // ---- wsum + stats zero ----
        int e = tidx;
        float4 o;
        o.x = wsw[(size_t)e*Dd + 0] + wsk[(size_t)e*Dd + 0];
        o.y = wsw[(size_t)e*Dd + 1] + wsk[(size_t)e*Dd + 1];
        o.z = wsw[(size_t)e*Dd + 2] + wsk[(size_t)e*Dd + 2];
        o.w = 0.0f;
        *(float4*)&wsum[e*4] = o;
        if (e < 2) stats[e] = 0.0f;
    } else if (bid < 5697) {               // ---- cvt_split ----
        int i = (bid - 4353) * 256 + tidx;
        float4 v = ((const float4*)jf)[i];
        float x[4] = {v.x, v.y, v.z, v.w};
        ushort4 ob; half4v oh, ol, od;
        #pragma unroll
        for (int u = 0; u < 4; ++u) {
            ((unsigned short*)&ob)[u] = f2bf(x[u]);
            _Float16 h = (_Float16)x[u];
            oh[u] = h;
            ol[u] = (_Float16)((x[u] - (float)h) * 16.0f);
            od[u] = (_Float16)(x[u] * 0.0078125f);   // /128
        }
        ((ushort4*)jfb)[i] = ob;
        ((half4v*)jfh)[i] = oh;
        ((half4v*)jfl)[i] = ol;
        ((half4v*)jfd)[i] = od;
    } else if (bid < 5825) {               // ---- g_gemm -> GT (fp16-split) ----
        int q = bid - 5697;
        int h = q >> 4, rem = q & 15;
        int m0 = (rem >> 2) * 64, n0 = (rem & 3) * 64;
        float (*As)[68] = (float(*)[68])sm;
        float (*Ws)[68] = (float(*)[68])(sm + 8704);
        int ty = tidx >> 4, tx = tidx & 15;
        float acc[4][4] = {};
        for (int kb = 0; kb < 256; kb += 32) {
            #pragma unroll
            for (int it = 0; it < 2; ++it) {
                int c = tidx + it * 256;
                int row = c >> 3, col = (c & 7) * 4;
                float4 v = *(const float4*)&wq[(size_t)(m0 + row)*HD + h*256 + kb + col];
                float4 u = *(const float4*)&wk[(size_t)(n0 + row)*HD + h*256 + kb + col];
                As[col+0][row] = v.x; As[col+1][row] = v.y;
                As[col+2][row] = v.z; As[col+3][row] = v.w;
                Ws[col+0][row] = u.x; Ws[col+1][row] = u.y;
                Ws[col+2][row] = u.z; Ws[col+3][row] = u.w;
            }
            __syncthreads();
            #pragma unroll
            for (int kk = 0; kk < 32; ++kk) {
                float4 a = *(const float4*)&As[kk][ty*4];
                float4 b = *(const float4*)&Ws[kk][tx*4];
                float av[4] = {a.x, a.y, a.z, a.w};
                float bv[4] = {b.x, b.y, b.z, b.w};
                #pragma unroll
                for (int i = 0; i < 4; ++i)
                    #pragma unroll
                    for (int j = 0; j < 4; ++j)
                        acc[i][j] += av[i] * bv[j];
            }
            __syncthreads();
        }
        #pragma unroll
        for (int j = 0; j < 4; ++j) {
            int n = h*256 + n0 + tx*4 + j;
            half4v hi, hs, lo;
            #pragma unroll
            for (int i = 0; i < 4; ++i) {
                float g = acc[i][j];
                _Float16 gh = (_Float16)g;
                hi[i] = gh;
                hs[i] = (_Float16)(g * 0.0625f);
                lo[i] = (_Float16)((g - (float)gh) * 128.0f);
            }
            _Float16* base = &GT[(size_t)n*768 + m0 + ty*4];
            *(half4v*)(base)       = hi;
            *(half4v*)(base + 256) = hs;
            *(half4v*)(base + 512) = lo;
        }
    } else if (bid < 5833) {               // ---- wvp ----
        int h = bid - 5825;
        float (*wpc)[3] = (float(*)[3])sm;
        int t = tidx;
        const float* p = &wp[(size_t)(h*256 + t) * Cc];
        wpc[t][0] = p[0]; wpc[t][1] = p[1]; wpc[t][2] = p[2];
        __syncthreads();
        const float* vr = &wv[(size_t)t*HD + h*256];
        float a0=0, a1=0, a2=0;
        for (int d = 0; d < 256; ++d) {
            float v = vr[d];
            a0 += v*wpc[d][0]; a1 += v*wpc[d][1]; a2 += v*wpc[d][2];
        }
        float* o = &Wvp2[(size_t)t*24 + h*3];
        o[0]=a0; o[1]=a1; o[2]=a2;
    } else {                               // ---- knn layer 0 ----
        knn_body(bid - 5833, jf, Cc, nbr0, (float(*)[3])sm);
    }
}

// ---------------------------------------------------------------------------
// 16-bit MFMA GEMM core, XOR-swizzled LDS.
template<int BM, int BN, int BK, int NSEG, bool RELU_STATS, bool OUT_BF16, bool F16>
__device__ __forceinline__
void gemm_core(unsigned short* As, unsigned short* Bs, float* red,
               int bm, int bn,
               const unsigned short* __restrict__ A0, int lda0, int klen0,
               const unsigned short* __restrict__ A1, int lda1, int klen1,
               const unsigned short* __restrict__ A2, int lda2, int klen2,
               const unsigned short* __restrict__ Bt, int ldb,
               void* __restrict__ Cv, int ldc, float* __restrict__ stat) {
    constexpr int WM = BM/2, WN = BN/2;
    constexpr int MW = WM/16, NW = WN/16, KW = BK/32;
    constexpr int CHUNKA = BM*BK/8;
    constexpr int CHUNKB = BN*BK/8;
    constexpr int KB8 = BK/8;
    constexpr int SWZ = KB8 - 1;
    using frag = std::conditional_t<F16, half8, short8>;

    int tid = threadIdx.x;
    int wid = tid >> 6, lane = tid & 63;
    int wr = wid >> 1, wc = wid & 1;

    f32x4 acc[MW][NW];
    #pragma unroll
    for (int m = 0; m < MW; ++m)
        #pragma unroll
        for (int n = 0; n < NW; ++n)
            acc[m][n] = (f32x4){0.f, 0.f, 0.f, 0.f};

    const unsigned short* Aseg[3] = {A0, A1, A2};
    const int ldas[3] = {lda0, lda1, lda2};
    const int klens[3] = {klen0, klen1, klen2};

    int kglob = 0;
    for (int seg = 0; seg < NSEG; ++seg) {
        const unsigned short* A = Aseg[seg];
        const int lda = ldas[seg];
        const int klen = klens[seg];
        for (int k0 = 0; k0 < klen; k0 += BK) {
            #pragma unroll
            for (int it = 0; it < CHUNKA/256; ++it) {
                int c = tid + it*256;
                int row = c / KB8;
                int kp = (c % KB8) ^ (row & SWZ);
                __builtin_amdgcn_global_load_lds(
                    (const __attribute__((address_space(1))) unsigned int*)
                        (A + (size_t)(bm + row)*lda + k0 + kp*8),
                    (__attribute__((address_space(3))) unsigned int*)(As + c*8),
                    16, 0, 0);
            }
            #pragma unroll
            for (int it = 0; it < CHUNKB/256; ++it) {
                int c = tid + it*256;
                int row = c / KB8;
                int kp = (c % KB8) ^ (row & SWZ);
                __builtin_amdgcn_global_load_lds(
                    (const __attribute__((address_space(1))) unsigned int*)
                        (Bt + (size_t)(bn + row)*ldb + kglob + k0 + kp*8),
                    (__attribute__((address_space(3))) unsigned int*)(Bs + c*8),
                    16, 0, 0);
            }
            __syncthreads();
            #pragma unroll
            for (int kp = 0; kp < KW; ++kp) {
                frag af[MW], bf[NW];
                int cbase = kp*4 + (lane >> 4);
                #pragma unroll
                for (int m = 0; m < MW; ++m) {
                    int r = wr*WM + m*16 + (lane & 15);
                    af[m] = *(const frag*)&As[r*BK + ((cbase ^ (r & SWZ))*8)];
                }
                #pragma unroll
                for (int n = 0; n < NW; ++n) {
                    int r = wc*WN + n*16 + (lane & 15);
                    bf[n] = *(const frag*)&Bs[r*BK + ((cbase ^ (r & SWZ))*8)];
                }
                #pragma unroll
                for (int m = 0; m < MW; ++m)
                    #pragma unroll
                    for (int n = 0; n < NW; ++n) {
                        if constexpr (F16)
                            acc[m][n] = __builtin_amdgcn_mfma_f32_16x16x32_f16(
                                af[m], bf[n], acc[m][n], 0, 0, 0);
                        else
                            acc[m][n] = __builtin_amdgcn_mfma_f32_16x16x32_bf16(
                                af[m], bf[n], acc[m][n], 0, 0, 0);
                    }
            }
            __syncthreads();
        }
        kglob += klen;
    }

    int cr = (lane >> 4)*4, cc = lane & 15;
    float bsum = 0.0f;
    #pragma unroll
    for (int m = 0; m < MW; ++m)
        #pragma unroll
        for (int n = 0; n < NW; ++n)
            #pragma unroll
            for (int j = 0; j < 4; ++j) {
                float v = acc[m][n][j];
                if (RELU_STATS) { v = fmaxf(v, 0.0f); bsum += v; }
                size_t row = bm + wr*WM + m*16 + cr + j;
                size_t col = bn + wc*WN + n*16 + cc;
                if (OUT_BF16) ((unsigned short*)Cv)[row*ldc + col] = f2bf(v);
                else          ((float*)Cv)[row*ldc + col] = v;
            }
    if (RELU_STATS) {
        #pragma unroll
        for (int sft = 1; sft < 64; sft <<= 1) bsum += __shfl_xor(bsum, sft);
        if (lane == 0) red[wid] = bsum;
        __syncthreads();
        if (tid == 0) atomicAdd(stat, red[0] + red[1] + red[2] + red[3]);
    }
}

// ---------------------------------------------------------------------------
// COMBO: y<16 -> layer-0 V gemm (writes V columns of QKVb, XCD-chunked);
// y in [16,32) -> fp16-split T-gemm (XCD-chunked); y in [32,48) -> vproj.
__global__ __launch_bounds__(256)
void combo_kernel(const unsigned short* __restrict__ jfb,
                  const unsigned short* __restrict__ wqkvT,
                  unsigned short* __restrict__ QKVb,
                  const _Float16* __restrict__ jfh, const _Float16* __restrict__ jfl,
                  const _Float16* __restrict__ jfd, const _Float16* __restrict__ GT,
                  float* __restrict__ Tm,
                  const float* __restrict__ jf, const float* __restrict__ Wvp2,
                  float* __restrict__ vproj) {
    __shared__ __align__(16) char smem[32784];
    unsigned short* As = (unsigned short*)smem;
    unsigned short* Bs = (unsigned short*)(smem + 16384);
    float* red = (float*)(smem + 32768);
    int x = blockIdx.x, y = blockIdx.y;
    if (y < 16) {
        // V-only gemm: B rows/C cols offset by 2*HD (the wv^T panel / V cols).
        int lb = x + 42*y;                 // 672 blocks
        int nb = (lb & 7) * 84 + (lb >> 3);
        int sx = nb % 42, sy = nb / 42;
        gemm_core<128,128,64,1,false,true,false>(As, Bs, red, sx*128,
            2*HD + sy*128,
            jfb, Cc, Cc, jfb, Cc, 0, jfb, Cc, 0, wqkvT, Cc, QKVb, QKVN, nullptr);
    } else if (y < 32) {
        int lb = x + 42*(y - 16);
        int nb = (lb & 7) * 84 + (lb >> 3);
        int sx = nb / 16, sy = nb % 16;
        gemm_core<128,128,64,3,false,false,true>(As, Bs, red, sx*128, sy*128,
            (const unsigned short*)jfh, Cc, Cc, (const unsigned short*)jfl, Cc, Cc,
            (const unsigned short*)jfd, Cc, Cc, (const unsigned short*)GT, 768,
            Tm, HD, nullptr);
    } else {
        int q = (y - 32) * 42 + x;
        float (*hr)[256] = (float(*)[256])smem;
        float* wl = (float*)(smem + 8192);
        int t = threadIdx.x;
        int j0 = q * 8;
        #pragma unroll
        for (int i = 0; i < 6; ++i)
            *(float4*)&wl[t*4 + i*1024] = *(const float4*)&Wvp2[t*4 + i*1024];
        {
            int r = t >> 5, c = (t & 31) * 8;
            const float* src = &jf[(size_t)(j0 + r)*Cc + c];
            *(float4*)&hr[r][c]   = *(const float4*)src;
            *(float4*)&hr[r][c+4] = *(const float4*)(src + 4);
        }
        __syncthreads();
        int r = t >> 5, o = t & 31;
        if (o < 24) {
            float a = 0.0f;
            for (int e = 0; e < 256; ++e) a += hr[r][e] * wl[e*24 + o];
            vproj[(size_t)(j0 + r)*24 + o] = a;
        }
    }
}

// ---------------------------------------------------------------------------
// layer-1 QKV gemm with XCD-chunked swizzle (grid 42x48, 2016 blocks).
__global__ __launch_bounds__(256)
void qkv1_kernel(const unsigned short* __restrict__ h1b,
                 const unsigned short* __restrict__ wqkvT1,
                 unsigned short* __restrict__ QKVb) {
    __shared__ __align__(16) unsigned short As[128*64];
    __shared__ __align__(16) unsigned short Bs[128*64];
    __shared__ float red[4];
    int lb = blockIdx.x + 42*blockIdx.y;
    int nb = (lb & 7) * 252 + (lb >> 3);
    int sx = nb % 42, sy = nb / 42;
    gemm_core<128,128,64,1,false,true,false>(
        As, Bs, red, sx*128, sy*128,
        h1b, Cc, Cc, h1b, Cc, 0, h1b, Cc, 0, wqkvT1, Cc, QKVb, QKVN, nullptr);
}

// ---------------------------------------------------------------------------
// fused epilogue gemm (+ optional layer-1 kNN in extra y-blocks)
template<bool OUT_BF16, bool DO_KNN>
__global__ __launch_bounds__(256)
void fused_kernel(const unsigned short* __restrict__ att,
                  const unsigned short* __restrict__ hseg,
                  const unsigned short* __restrict__ h0seg,
                  const unsigned short* __restrict__ fbtL,
                  void* __restrict__ Cv, float* __restrict__ stat,
                  const float* __restrict__ crd, int* __restrict__ nbr1) {
    __shared__ __align__(16) char smem[16400];
    if (DO_KNN && blockIdx.y >= 4) {
        int b = (blockIdx.y - 4) * 84 + blockIdx.x;
        if (b < Bb) knn_body(b, crd, 4, nbr1, (float(*)[3])smem);
        return;
    }
    unsigned short* As = (unsigned short*)smem;
    unsigned short* Bs = (unsigned short*)(smem + 8192);
    float* red = (float*)(smem + 16384);
    gemm_core<64,64,64,3,true,OUT_BF16,false>(
        As, Bs, red, blockIdx.x*64, blockIdx.y*64,
        att, HD, HD, hseg, Cc, Cc, h0seg, Cc, Cc,
        fbtL, KFUSE, Cv, Cc, stat);
}

// ---------------------------------------------------------------------------
// precise layer-0 coords + SAVES the fp32 softmax weights to W0[i*64 + l]
// (lane l holds (k = l>>3, h = l&7)).
__global__ __launch_bounds__(64)
void precise_kernel(const float* __restrict__ T, const float* __restrict__ h0,
                    const int* __restrict__ nbr, const float* __restrict__ vproj,
                    const float* __restrict__ wsum, float* __restrict__ crd,
                    float* __restrict__ W0) {
    int i = blockIdx.x;
    int b = i / Jj;
    int l = threadIdx.x;
    __shared__ float Ts[8][260];
    __shared__ float nb[8][260];
    __shared__ float hi[256];
    #pragma unroll
    for (int u = 0; u < 8; ++u) {
        int idx = u*64 + l;
        float4 v = *(const float4*)&T[(size_t)i*HD + idx*4];
        int hh = idx >> 6, dd = (idx & 63) * 4;
        *(float4*)&Ts[hh][dd] = v;
    }
    *(float4*)&hi[l*4] = *(const float4*)&h0[(size_t)i*Cc + l*4];
    int kq = l >> 3, s = l & 7;
    int njs = nbr[i*KNN + kq];
    const float* nrow = &h0[(size_t)(b*Jj + njs)*Cc];
    #pragma unroll
    for (int u = 0; u < 8; ++u)
        *(float4*)&nb[kq][(s*8+u)*4] = *(const float4*)&nrow[(s*8+u)*4];
    __syncthreads();

    int k = l >> 3, h = l & 7;
    float sacc = 0;
    #pragma unroll 8
    for (int d = 0; d < 256; d += 4) {
        float4 tv = *(const float4*)&Ts[h][d];
        float4 nv = *(const float4*)&nb[k][d];
        sacc += tv.x*nv.x + tv.y*nv.y + tv.z*nv.z + tv.w*nv.w;
    }
    float sc = sacc * 0.0625f;
    sc = (sc >= 0.0f) ? sc : 0.2f * sc;
    float m = sc;
    m = fmaxf(m, __shfl_xor(m, 8));
    m = fmaxf(m, __shfl_xor(m, 16));
    m = fmaxf(m, __shfl_xor(m, 32));
    float e = expf(sc - m);
    float den = e;
    den += __shfl_xor(den, 8); den += __shfl_xor(den, 16); den += __shfl_xor(den, 32);
    float w = e / den;
    W0[(size_t)i*64 + l] = w;              // save for layer-0 attention

    int njk = nbr[i*KNN + k];
    const float* vp = &vproj[(size_t)(b*Jj + njk)*24 + h*3];
    float t0 = w * vp[0], t1 = w * vp[1], t2 = w * vp[2];
    #pragma unroll
    for (int u = 0; u < 4; ++u) {
        int e4 = l*4 + u;
        float hv = hi[e4];
        float4 wv = *(const float4*)&wsum[e4*4];
        t0 += hv * wv.x; t1 += hv * wv.y; t2 += hv * wv.z;
    }
    #pragma unroll
    for (int sft = 1; sft < 64; sft <<= 1) {
        t0 += __shfl_xor(t0, sft); t1 += __shfl_xor(t1, sft); t2 += __shfl_xor(t2, sft);
    }
    if (l == 0) {
        crd[i*4+0] = fmaxf(t0, 0.0f);
        crd[i*4+1] = fmaxf(t1, 0.0f);
        crd[i*4+2] = fmaxf(t2, 0.0f);
        crd[i*4+3] = 0.0f;
    }
}

// ---------------------------------------------------------------------------
// layer-0 attention from precomputed fp32 weights: V gather + weighted sum.
// One wave per (row, head-pair); XCD-chunked block remap.
__global__ __launch_bounds__(64)
void attnw_kernel(const unsigned short* __restrict__ QKV,
                  const int* __restrict__ nbr, const float* __restrict__ W0,
                  unsigned short* __restrict__ att) {
    int lb = blockIdx.x;
    int gid = (lb & 7) * (Mrows*4/8) + (lb >> 3);
    int hp = gid & 3, row = gid >> 2, b = row / Jj;
    int lane = threadIdx.x;
    int h = hp*2 + (lane >> 5);
    int d0 = (lane & 31) * 8;
    const int* np_ = nbr + row * KNN;
    const float* wr = W0 + (size_t)row*64 + h;

    float o[8] = {};
    #pragma unroll
    for (int k = 0; k < KNN; ++k) {
        float w = wr[k*8];                 // W0[row*64 + k*8 + h]
        int n = np_[k];
        u16x8 vu = *(const u16x8*)&QKV[(size_t)(b*Jj + n)*QKVN + 2*HD + h*Dd + d0];
        #pragma unroll
        for (int i = 0; i < 8; ++i) o[i] += w * bf2f(vu[i]);
    }
    u16x8 ou;
    #pragma unroll
    for (int i = 0; i < 8; ++i) ou[i] = f2bf(o[i]);
    *(u16x8*)&att[(size_t)row*HD + h*Dd + d0] = ou;
}

// ---------------------------------------------------------------------------
// layer-1 attention (score-based): one wave per (row, head-pair), XCD-chunked.
__global__ __launch_bounds__(64)
void attn_kernel(const unsigned short* __restrict__ QKV,
                 const int* __restrict__ nbr, unsigned short* __restrict__ att) {
    int lb = blockIdx.x;
    int gid = (lb & 7) * (Mrows*4/8) + (lb >> 3);
    int hp = gid & 3, row = gid >> 2, b = row / Jj;
    int lane = threadIdx.x;
    int h = hp*2 + (lane >> 5);
    int d0 = (lane & 31) * 8;

    u16x8 qu = *(const u16x8*)&QKV[(size_t)row*QKVN + h*Dd + d0];
    float qf[8];
    #pragma unroll
    for (int i = 0; i < 8; ++i) qf[i] = bf2f(qu[i]);
    const int* np_ = nbr + row * KNN;

    float sc[KNN]; int nb[KNN];
    #pragma unroll
    for (int k = 0; k < KNN; ++k) {
        int n = np_[k]; nb[k] = n;
        u16x8 ku = *(const u16x8*)&QKV[(size_t)(b*Jj + n)*QKVN + HD + h*Dd + d0];
        float p = 0;
        #pragma unroll
        for (int i = 0; i < 8; ++i) p += qf[i] * bf2f(ku[i]);
        #pragma unroll
        for (int s = 1; s < 32; s <<= 1) p += __shfl_xor(p, s);
        sc[k] = p;
    }
    float mx = -INFINITY;
    #pragma unroll
    for (int k = 0; k < KNN; ++k) {
        float s = sc[k] * 0.0625f;
        s = (s >= 0.0f) ? s : 0.2f * s;
        sc[k] = s; mx = fmaxf(mx, s);
    }
    float den = 0.0f;
    #pragma unroll
    for (int k = 0; k < KNN; ++k) { sc[k] = expf(sc[k] - mx); den += sc[k]; }
    float inv = 1.0f / den;
    float o[8] = {};
    #pragma unroll
    for (int k = 0; k < KNN; ++k) {
        u16x8 vu = *(const u16x8*)&QKV[(size_t)(b*Jj + nb[k])*QKVN + 2*HD + h*Dd + d0];
        float w = sc[k] * inv;
        #pragma unroll
        for (int i = 0; i < 8; ++i) o[i] += w * bf2f(vu[i]);
    }
    u16x8 ou;
    #pragma unroll
    for (int i = 0; i < 8; ++i) ou[i] = f2bf(o[i]);
    *(u16x8*)&att[(size_t)row*HD + h*Dd + d0] = ou;
}

// ---------------------------------------------------------------------------
__global__ __launch_bounds__(64)
void final_kernel(const float* __restrict__ h, const float* __restrict__ fcw,
                  const float* __restrict__ fcb, const float* __restrict__ stats,
                  float* __restrict__ out) {
    int row = blockIdx.x, lane = threadIdx.x;
    const float4 hv = *(const float4*)(h + (size_t)row*Cc + lane*4);
    float a0=0, a1=0, a2=0;
    const float hx[4] = {hv.x, hv.y, hv.z, hv.w};
    #pragma unroll
    for (int i = 0; i < 4; ++i) {
        int c = lane*4 + i;
        a0 += hx[i]*fcw[c*3+0]; a1 += hx[i]*fcw[c*3+1]; a2 += hx[i]*fcw[c*3+2];
    }
    #pragma unroll
    for (int s = 32; s > 0; s >>= 1) {
        a0 += __shfl_xor(a0, s); a1 += __shfl_xor(a1, s); a2 += __shfl_xor(a2, s);
    }
    if (lane == 0) {
        out[row*3+0] = a0 + fcb[0];
        out[row*3+1] = a1 + fcb[1];
        out[row*3+2] = a2 + fcb[2];
        if (row == 0)
            out[(size_t)Mrows*3] =
                (stats[0] + stats[1]) * (0.5f / ((float)Mrows * (float)Cc));
    }
}

// ---------------------------------------------------------------------------
extern "C" void kernel_launch(void* const* d_in, const int* in_sizes, int n_in,
                              void* d_out, int out_size, void* d_ws, size_t ws_size,
                              hipStream_t stream) {
    (void)in_sizes; (void)n_in; (void)out_size; (void)ws_size;
    const float* jf     = (const float*)d_in[0];
    const float* wq     = (const float*)d_in[1];
    const float* wk     = (const float*)d_in[2];
    const float* wv     = (const float*)d_in[3];
    const float* wp     = (const float*)d_in[4];
    const float* wsw    = (const float*)d_in[5];
    const float* wskip0 = (const float*)d_in[6];
    const float* fcw    = (const float*)d_in[7];
    const float* fcb    = (const float*)d_in[8];
    float* out = (float*)d_out;

    char* wsb = (char*)d_ws;
    unsigned short* QKVb  = (unsigned short*)(wsb + OFF_QKV);
    float*          Tm    = (float*)(wsb + OFF_T);
    unsigned short* attb  = (unsigned short*)(wsb + OFF_ATT);   // aliases T
    _Float16*       GT    = (_Float16*)(wsb + OFF_GT);
    unsigned short* jfb   = (unsigned short*)(wsb + OFF_JFB);
    _Float16*       jfh   = (_Float16*)(wsb + OFF_JFH);
    _Float16*       jfl   = (_Float16*)(wsb + OFF_JFL);
    _Float16*       jfd   = (_Float16*)(wsb + OFF_JFD);
    unsigned short* h1b   = (unsigned short*)(wsb + OFF_H1B);
    float*          h2f   = (float*)(wsb + OFF_H2F);
    unsigned short* wqkvT = (unsigned short*)(wsb + OFF_WQKVT);
    unsigned short* fbt   = (unsigned short*)(wsb + OFF_FBT);
    float*          Wvp   = (float*)(wsb + OFF_WVP);
    float*          vproj = (float*)(wsb + OFF_VPROJ);
    float*          wsum  = (float*)(wsb + OFF_WSUM);
    float*          crd   = (float*)(wsb + OFF_CRD);
    int*            nbr0  = (int*)(wsb + OFF_NBR0);
    int*            nbr1  = (int*)(wsb + OFF_NBR1);
    float*          W0    = (float*)(wsb + OFF_W0);
    float*          stats = (float*)(wsb + OFF_STAT);

    // 1. all input-only prep in one launch
    mega_prep_kernel<<<6089, 256, 0, stream>>>(jf, wq, wk, wv, wp, wsw, wskip0,
                                               wqkvT, fbt, stats, wsum,
                                               jfb, jfh, jfl, jfd, GT, Wvp, nbr0);
    // 2. layer-0 V gemm + fp16-split T-gemm + vproj in one launch
    combo_kernel<<<dim3(42, 48), 256, 0, stream>>>(jfb, wqkvT, QKVb,
                                                   jfh, jfl, jfd, GT, Tm,
                                                   jf, Wvp, vproj);
    // 3. precise layer-0 coords + fp32 attention weights (consumes Tm)
    precise_kernel<<<Mrows, 64, 0, stream>>>(Tm, jf, nbr0, vproj, wsum, crd, W0);
    // 4. layer-0 attention from saved weights (V-only)
    attnw_kernel<<<Mrows*4, 64, 0, stream>>>(QKVb, nbr0, W0, attb);
    // 5. layer-0 fused output gemm + layer-1 kNN
    fused_kernel<true, true><<<dim3(84, 8), 256, 0, stream>>>(
        attb, jfb, jfb, fbt, h1b, &stats[0], crd, nbr1);
    // 6. layer-1 QKV gemm (XCD-chunked)
    qkv1_kernel<<<dim3(42, 48), 256, 0, stream>>>(h1b, wqkvT + (size_t)QKVN*Cc, QKVb);
    // 7. layer-1 attention (XCD-chunked)
    attn_kernel<<<Mrows*4, 64, 0, stream>>>(QKVb, nbr1, attb);
    // 8. layer-1 fused output gemm
    fused_kernel<false, false><<<dim3(84, 4), 256, 0, stream>>>(
        attb, h1b, jfb, fbt + (size_t)Cc*KFUSE, h2f, &stats[1], nullptr, nullptr);
    // 9. final
    final_kernel<<<Mrows, 64, 0, stream>>>(h2f, fcw, fcb, stats, out);
}

// Round 16
// 202.016 us; speedup vs baseline: 1.3134x; 1.0151x over previous
//
#include <hip/hip_runtime.h>
#include <hip/hip_bf16.h>
#include <math.h>
#include <type_traits>

namespace {
constexpr int Bb = 256, Jj = 21, Cc = 256, Hh = 8, Dd = 256;
constexpr int Mrows = Bb * Jj;      // 5376
constexpr int HD    = Hh * Dd;      // 2048
constexpr int QKVN  = 3 * HD;       // 6144
constexpr int KNN   = 8;
constexpr int KFUSE = HD + Cc + Cc; // 2560

// ---- workspace byte offsets (ATT no longer aliases T) ----
constexpr size_t OFF_QKV   = 0;                                   // bf16 5376x6144
constexpr size_t OFF_T     = OFF_QKV   + (size_t)Mrows*QKVN*2;    // f32  5376x2048
constexpr size_t OFF_ATT   = OFF_T     + (size_t)Mrows*HD*4;      // bf16 5376x2048
constexpr size_t OFF_GT    = OFF_ATT   + (size_t)Mrows*HD*2;      // f16  2048x768
constexpr size_t OFF_JFB   = OFF_GT    + (size_t)HD*768*2;        // bf16 5376x256
constexpr size_t OFF_JFH   = OFF_JFB   + (size_t)Mrows*Cc*2;      // f16  5376x256
constexpr size_t OFF_JFL   = OFF_JFH   + (size_t)Mrows*Cc*2;      // f16  5376x256
constexpr size_t OFF_JFD   = OFF_JFL   + (size_t)Mrows*Cc*2;      // f16  5376x256
constexpr size_t OFF_H1B   = OFF_JFD   + (size_t)Mrows*Cc*2;      // bf16 5376x256
constexpr size_t OFF_H2F   = OFF_H1B   + (size_t)Mrows*Cc*2;      // f32  5376x256
constexpr size_t OFF_WQKVT = OFF_H2F   + (size_t)Mrows*Cc*4;      // bf16 2x6144x256
constexpr size_t OFF_FBT   = OFF_WQKVT + (size_t)2*QKVN*Cc*2;     // bf16 2x256x2560
constexpr size_t OFF_WVP   = OFF_FBT   + (size_t)2*Cc*KFUSE*2;    // f32  256x24
constexpr size_t OFF_VPROJ = OFF_WVP   + (size_t)Cc*24*4;         // f32  5376x24
constexpr size_t OFF_WSUM  = OFF_VPROJ + (size_t)Mrows*24*4;      // f32  256x4
constexpr size_t OFF_CRD   = OFF_WSUM  + (size_t)Cc*4*4;          // f32  5376x4
constexpr size_t OFF_NBR0  = OFF_CRD   + (size_t)Mrows*4*4;       // int  5376x8
constexpr size_t OFF_NBR1  = OFF_NBR0  + (size_t)Mrows*KNN*4;
constexpr size_t OFF_STAT  = OFF_NBR1  + (size_t)Mrows*KNN*4;     // 2 f32
} // namespace

typedef short short8 __attribute__((ext_vector_type(8)));
typedef _Float16 half8 __attribute__((ext_vector_type(8)));
typedef _Float16 half4v __attribute__((ext_vector_type(4)));
typedef unsigned short u16x8 __attribute__((ext_vector_type(8)));
typedef float f32x4 __attribute__((ext_vector_type(4)));

__device__ __forceinline__ unsigned short f2bf(float x) {
    unsigned int u = __float_as_uint(x);
    u = u + 0x7fffu + ((u >> 16) & 1u);            // round-to-nearest-even
    return (unsigned short)(u >> 16);
}
__device__ __forceinline__ float bf2f(unsigned short b) {
    return __uint_as_float(((unsigned int)b) << 16);
}

// ---------------------------------------------------------------------------
// kNN body: exact stable-argsort ranks 1..8 by (d2, index).
__device__ __forceinline__ void knn_body(int b, const float* __restrict__ src,
                                         int ld, int* __restrict__ nbr,
                                         float (*cs)[3]) {
    int t = threadIdx.x;
    if (t < Jj) {
        const float* p = src + (size_t)(b * Jj + t) * ld;
        cs[t][0] = p[0]; cs[t][1] = p[1]; cs[t][2] = p[2];
    }
    __syncthreads();
    if (t < Jj) {
        float x = cs[t][0], y = cs[t][1], z = cs[t][2];
        float d2[Jj];
        #pragma unroll
        for (int jj = 0; jj < Jj; ++jj) {
            float dx = x - cs[jj][0], dy = y - cs[jj][1], dz = z - cs[jj][2];
            d2[jj] = dx*dx + dy*dy + dz*dz;
        }
        unsigned int used = 0u;
        int out_base = (b * Jj + t) * KNN;
        #pragma unroll
        for (int r = 0; r <= KNN; ++r) {
            int best = -1; float bd = INFINITY;
            #pragma unroll
            for (int jj = 0; jj < Jj; ++jj)
                if (!((used >> jj) & 1u) && d2[jj] < bd) { bd = d2[jj]; best = jj; }
            used |= (1u << best);
            if (r > 0) nbr[out_base + r - 1] = best;
        }
    }
}

// ---------------------------------------------------------------------------
// MEGA-PREP: one launch for all input-only work. Long poles dispatched FIRST:
// [0,256) g_gemm 32x64; [256,264) wvp; [264,520) knn0; 520 wsum/stats;
// [521,1865) cvt_split; [1865,6217) weight transposes.
__global__ __launch_bounds__(256)
void mega_prep_kernel(const float* __restrict__ jf,
                      const float* __restrict__ wq, const float* __restrict__ wk,
                      const float* __restrict__ wv, const float* __restrict__ wp,
                      const float* __restrict__ wsw, const float* __restrict__ wsk,
                      unsigned short* __restrict__ wqkvT,
                      unsigned short* __restrict__ fbt, float* __restrict__ stats,
                      float* __restrict__ wsum,
                      unsigned short* __restrict__ jfb, _Float16* __restrict__ jfh,
                      _Float16* __restrict__ jfl, _Float16* __restrict__ jfd,
                      _Float16* __restrict__ GT, float* __restrict__ Wvp2,
                      int* __restrict__ nbr0) {
    __shared__ __align__(16) char sm[17408];
    int bid = blockIdx.x;
    int tidx = threadIdx.x;

    if (bid < 256) {                       // ---- g_gemm 32x64 -> GT ----
        int h = bid >> 5, rem = bid & 31;
        int m0 = (rem >> 2) * 32, n0 = (rem & 3) * 64;
        float (*As)[36] = (float(*)[36])sm;              // 4608 B
        float (*Ws)[68] = (float(*)[68])(sm + 4608);     // 8704 B
        int ty = tidx >> 4, tx = tidx & 15;
        float acc[2][4] = {};
        for (int kb = 0; kb < 256; kb += 32) {
            {
                int row = tidx >> 3, col = (tidx & 7) * 4;
                float4 v = *(const float4*)&wq[(size_t)(m0 + row)*HD + h*256 + kb + col];
                As[col+0][row] = v.x; As[col+1][row] = v.y;
                As[col+2][row] = v.z; As[col+3][row] = v.w;
                int row2 = tidx >> 2, col2 = (tidx & 3) * 8;
                float4 u0 = *(const float4*)&wk[(size_t)(n0 + row2)*HD + h*256 + kb + col2];
                float4 u1 = *(const float4*)&wk[(size_t)(n0 + row2)*HD + h*256 + kb + col2 + 4];
                Ws[col2+0][row2] = u0.x; Ws[col2+1][row2] = u0.y;
                Ws[col2+2][row2] = u0.z; Ws[col2+3][row2] = u0.w;
                Ws[col2+4][row2] = u1.x; Ws[col2+5][row2] = u1.y;
                Ws[col2+6][row2] = u1.z; Ws[col2+7][row2] = u1.w;
            }
            __syncthreads();
            #pragma unroll
            for (int kk = 0; kk < 32; ++kk) {
                float a0 = As[kk][ty*2], a1 = As[kk][ty*2 + 1];
                float4 bv = *(const float4*)&Ws[kk][tx*4];
                float b4[4] = {bv.x, bv.y, bv.z, bv.w};
                #pragma unroll
                for (int j = 0; j < 4; ++j) {
                    acc[0][j] += a0 * b4[j];
                    acc[1][j] += a1 * b4[j];
                }
            }
            __syncthreads();
        }
        #pragma unroll
        for (int j = 0; j < 4; ++j) {
            int n = h*256 + n0 + tx*4 + j;
            float g0 = acc[0][j], g1 = acc[1][j];
            _Float16 h0_ = (_Float16)g0, h1_ = (_Float16)g1;
            _Float16* base = &GT[(size_t)n*768 + m0 + ty*2];
            base[0]   = h0_;                          base[1]   = h1_;
            base[256] = (_Float16)(g0 * 0.0625f);     base[257] = (_Float16)(g1 * 0.0625f);
            base[512] = (_Float16)((g0 - (float)h0_) * 128.0f);
            base[513] = (_Float16)((g1 - (float)h1_) * 128.0f);
        }
    } else if (bid < 264) {                // ---- wvp ----
        int h = bid - 256;
        float (*wpc)[3] = (float(*)[3])sm;
        int t = tidx;
        const float* p = &wp[(size_t)(h*256 + t) * Cc];
        wpc[t][0] = p[0]; wpc[t][1] = p[1]; wpc[t][2] = p[2];
        __syncthreads();
        const float* vr = &wv[(size_t)t*HD + h*256];
        float a0=0, a1=0, a2=0;
        for (int d = 0; d < 256; ++d) {
            float v = vr[d];
            a0 += v*wpc[d][0]; a1 += v*wpc[d][1]; a2 += v*wpc[d][2];
        }
        float* o = &Wvp2[(size_t)t*24 + h*3];
        o[0]=a0; o[1]=a1; o[2]=a2;
    } else if (bid < 520) {                // ---- knn layer 0 ----
        knn_body(bid - 264, jf, Cc, nbr0, (float(*)[3])sm);
    } else if (bid == 520) {               // ---- wsum + stats zero ----
        int e = tidx;
        float4 o;
        o.x = wsw[(size_t)e*Dd + 0] + wsk[(size_t)e*Dd + 0];
        o.y = wsw[(size_t)e*Dd + 1] + wsk[(size_t)e*Dd + 1];
        o.z = wsw[(size_t)e*Dd + 2] + wsk[(size_t)e*Dd + 2];
        o.w = 0.0f;
        *(float4*)&wsum[e*4] = o;
        if (e < 2) stats[e] = 0.0f;
    } else if (bid < 1865) {               // ---- cvt_split ----
        int i = (bid - 521) * 256 + tidx;
        float4 v = ((const float4*)jf)[i];
        float x[4] = {v.x, v.y, v.z, v.w};
        ushort4 ob; half4v oh, ol, od;
        #pragma unroll
        for (int u = 0; u < 4; ++u) {
            ((unsigned short*)&ob)[u] = f2bf(x[u]);
            _Float16 h = (_Float16)x[u];
            oh[u] = h;
            ol[u] = (_Float16)((x[u] - (float)h) * 16.0f);
            od[u] = (_Float16)(x[u] * 0.0078125f);   // /128
        }
        ((ushort4*)jfb)[i] = ob;
        ((half4v*)jfh)[i] = oh;
        ((half4v*)jfl)[i] = ol;
        ((half4v*)jfd)[i] = od;
    } else {                               // ---- weight transposes ----
        int tt = bid - 1865;
        const float* src; unsigned short* dst;
        int ldin, ldout, tilesX, tile;
        constexpr size_t CH = (size_t)Cc * HD;
        if (tt < 3072) {
            int op = tt >> 9; tile = tt & 511; tilesX = 64;
            ldin = HD; ldout = Cc;
            const float* s3[3] = {wq, wk, wv};
            src = s3[op % 3] + (size_t)(op / 3) * CH;
            dst = wqkvT + (size_t)(op % 3) * HD * Cc + (size_t)(op / 3) * QKVN * Cc;
        } else if (tt < 4096) {
            int op = (tt - 3072) >> 9; tile = (tt - 3072) & 511; tilesX = 8;
            ldin = Cc; ldout = KFUSE;
            src = wp + (size_t)op * HD * Cc;
            dst = fbt + (size_t)op * Cc * KFUSE;
        } else {
            int q = tt - 4096; int op = q >> 6; tile = q & 63; tilesX = 8;
            ldin = Cc; ldout = KFUSE;
            const float* s4[4] = {wsw, wsw + (size_t)Cc * Cc, wsk, wsk};
            src = s4[op];
            dst = fbt + (size_t)(op & 1) * Cc * KFUSE + HD + (size_t)(op >> 1) * Cc;
        }
        int bx = tile % tilesX, by = tile / tilesX;
        int n0 = bx * 32, k0 = by * 32;
        float (*t)[33] = (float(*)[33])sm;
        int r = tidx >> 3, c4 = (tidx & 7) * 4;
        float4 v = *(const float4*)&src[(size_t)(k0 + r) * ldin + n0 + c4];
        t[r][c4+0] = v.x; t[r][c4+1] = v.y; t[r][c4+2] = v.z; t[r][c4+3] = v.w;
        __syncthreads();
        ushort4 o;
        o.x = f2bf(t[c4+0][r]); o.y = f2bf(t[c4+1][r]);
        o.z = f2bf(t[c4+2][r]); o.w = f2bf(t[c4+3][r]);
        *(ushort4*)&dst[(size_t)(n0 + r) * ldout + k0 + c4] = o;
    }
}

// ---------------------------------------------------------------------------
// 16-bit MFMA GEMM core, XOR-swizzled LDS.
template<int BM, int BN, int BK, int NSEG, bool RELU_STATS, bool OUT_BF16, bool F16>
__device__ __forceinline__
void gemm_core(unsigned short* As, unsigned short* Bs, float* red,
               int bm, int bn,
               const unsigned short* __restrict__ A0, int lda0, int klen0,
               const unsigned short* __restrict__ A1, int lda1, int klen1,
               const unsigned short* __restrict__ A2, int lda2, int klen2,
               const unsigned short* __restrict__ Bt, int ldb,
               void* __restrict__ Cv, int ldc, float* __restrict__ stat) {
    constexpr int WM = BM/2, WN = BN/2;
    constexpr int MW = WM/16, NW = WN/16, KW = BK/32;
    constexpr int CHUNKA = BM*BK/8;
    constexpr int CHUNKB = BN*BK/8;
    constexpr int KB8 = BK/8;
    constexpr int SWZ = KB8 - 1;
    using frag = std::conditional_t<F16, half8, short8>;

    int tid = threadIdx.x;
    int wid = tid >> 6, lane = tid & 63;
    int wr = wid >> 1, wc = wid & 1;

    f32x4 acc[MW][NW];
    #pragma unroll
    for (int m = 0; m < MW; ++m)
        #pragma unroll
        for (int n = 0; n < NW; ++n)
            acc[m][n] = (f32x4){0.f, 0.f, 0.f, 0.f};

    const unsigned short* Aseg[3] = {A0, A1, A2};
    const int ldas[3] = {lda0, lda1, lda2};
    const int klens[3] = {klen0, klen1, klen2};

    int kglob = 0;
    for (int seg = 0; seg < NSEG; ++seg) {
        const unsigned short* A = Aseg[seg];
        const int lda = ldas[seg];
        const int klen = klens[seg];
        for (int k0 = 0; k0 < klen; k0 += BK) {
            #pragma unroll
            for (int it = 0; it < CHUNKA/256; ++it) {
                int c = tid + it*256;
                int row = c / KB8;
                int kp = (c % KB8) ^ (row & SWZ);
                __builtin_amdgcn_global_load_lds(
                    (const __attribute__((address_space(1))) unsigned int*)
                        (A + (size_t)(bm + row)*lda + k0 + kp*8),
                    (__attribute__((address_space(3))) unsigned int*)(As + c*8),
                    16, 0, 0);
            }
            #pragma unroll
            for (int it = 0; it < CHUNKB/256; ++it) {
                int c = tid + it*256;
                int row = c / KB8;
                int kp = (c % KB8) ^ (row & SWZ);
                __builtin_amdgcn_global_load_lds(
                    (const __attribute__((address_space(1))) unsigned int*)
                        (Bt + (size_t)(bn + row)*ldb + kglob + k0 + kp*8),
                    (__attribute__((address_space(3))) unsigned int*)(Bs + c*8),
                    16, 0, 0);
            }
            __syncthreads();
            #pragma unroll
            for (int kp = 0; kp < KW; ++kp) {
                frag af[MW], bf[NW];
                int cbase = kp*4 + (lane >> 4);
                #pragma unroll
                for (int m = 0; m < MW; ++m) {
                    int r = wr*WM + m*16 + (lane & 15);
                    af[m] = *(const frag*)&As[r*BK + ((cbase ^ (r & SWZ))*8)];
                }
                #pragma unroll
                for (int n = 0; n < NW; ++n) {
                    int r = wc*WN + n*16 + (lane & 15);
                    bf[n] = *(const frag*)&Bs[r*BK + ((cbase ^ (r & SWZ))*8)];
                }
                #pragma unroll
                for (int m = 0; m < MW; ++m)
                    #pragma unroll
                    for (int n = 0; n < NW; ++n) {
                        if constexpr (F16)
                            acc[m][n] = __builtin_amdgcn_mfma_f32_16x16x32_f16(
                                af[m], bf[n], acc[m][n], 0, 0, 0);
                        else
                            acc[m][n] = __builtin_amdgcn_mfma_f32_16x16x32_bf16(
                                af[m], bf[n], acc[m][n], 0, 0, 0);
                    }
            }
            __syncthreads();
        }
        kglob += klen;
    }

    int cr = (lane >> 4)*4, cc = lane & 15;
    float bsum = 0.0f;
    #pragma unroll
    for (int m = 0; m < MW; ++m)
        #pragma unroll
        for (int n = 0; n < NW; ++n)
            #pragma unroll
            for (int j = 0; j < 4; ++j) {
                float v = acc[m][n][j];
                if (RELU_STATS) { v = fmaxf(v, 0.0f); bsum += v; }
                size_t row = bm + wr*WM + m*16 + cr + j;
                size_t col = bn + wc*WN + n*16 + cc;
                if (OUT_BF16) ((unsigned short*)Cv)[row*ldc + col] = f2bf(v);
                else          ((float*)Cv)[row*ldc + col] = v;
            }
    if (RELU_STATS) {
        #pragma unroll
        for (int sft = 1; sft < 64; sft <<= 1) bsum += __shfl_xor(bsum, sft);
        if (lane == 0) red[wid] = bsum;
        __syncthreads();
        if (tid == 0) atomicAdd(stat, red[0] + red[1] + red[2] + red[3]);
    }
}

// ---------------------------------------------------------------------------
// COMBO: y<16 -> layer-0 V gemm (writes V columns of QKVb, XCD-chunked);
// y in [16,32) -> fp16-split T-gemm (XCD-chunked); y in [32,48) -> vproj.
__global__ __launch_bounds__(256)
void combo_kernel(const unsigned short* __restrict__ jfb,
                  const unsigned short* __restrict__ wqkvT,
                  unsigned short* __restrict__ QKVb,
                  const _Float16* __restrict__ jfh, const _Float16* __restrict__ jfl,
                  const _Float16* __restrict__ jfd, const _Float16* __restrict__ GT,
                  float* __restrict__ Tm,
                  const float* __restrict__ jf, const float* __restrict__ Wvp2,
                  float* __restrict__ vproj) {
    __shared__ __align__(16) char smem[32784];
    unsigned short* As = (unsigned short*)smem;
    unsigned short* Bs = (unsigned short*)(smem + 16384);
    float* red = (float*)(smem + 32768);
    int x = blockIdx.x, y = blockIdx.y;
    if (y < 16) {
        int lb = x + 42*y;                 // 672 blocks
        int nb = (lb & 7) * 84 + (lb >> 3);
        int sx = nb % 42, sy = nb / 42;
        gemm_core<128,128,64,1,false,true,false>(As, Bs, red, sx*128,
            2*HD + sy*128,
            jfb, Cc, Cc, jfb, Cc, 0, jfb, Cc, 0, wqkvT, Cc, QKVb, QKVN, nullptr);
    } else if (y < 32) {
        int lb = x + 42*(y - 16);
        int nb = (lb & 7) * 84 + (lb >> 3);
        int sx = nb / 16, sy = nb % 16;
        gemm_core<128,128,64,3,false,false,true>(As, Bs, red, sx*128, sy*128,
            (const unsigned short*)jfh, Cc, Cc, (const unsigned short*)jfl, Cc, Cc,
            (const unsigned short*)jfd, Cc, Cc, (const unsigned short*)GT, 768,
            Tm, HD, nullptr);
    } else {
        int q = (y - 32) * 42 + x;
        float (*hr)[256] = (float(*)[256])smem;
        float* wl = (float*)(smem + 8192);
        int t = threadIdx.x;
        int j0 = q * 8;
        #pragma unroll
        for (int i = 0; i < 6; ++i)
            *(float4*)&wl[t*4 + i*1024] = *(const float4*)&Wvp2[t*4 + i*1024];
        {
            int r = t >> 5, c = (t & 31) * 8;
            const float* src = &jf[(size_t)(j0 + r)*Cc + c];
            *(float4*)&hr[r][c]   = *(const float4*)src;
            *(float4*)&hr[r][c+4] = *(const float4*)(src + 4);
        }
        __syncthreads();
        int r = t >> 5, o = t & 31;
        if (o < 24) {
            float a = 0.0f;
            for (int e = 0; e < 256; ++e) a += hr[r][e] * wl[e*24 + o];
            vproj[(size_t)(j0 + r)*24 + o] = a;
        }
    }
}

// ---------------------------------------------------------------------------
// layer-1 QKV gemm with XCD-chunked swizzle (grid 42x48, 2016 blocks).
__global__ __launch_bounds__(256)
void qkv1_kernel(const unsigned short* __restrict__ h1b,
                 const unsigned short* __restrict__ wqkvT1,
                 unsigned short* __restrict__ QKVb) {
    __shared__ __align__(16) unsigned short As[128*64];
    __shared__ __align__(16) unsigned short Bs[128*64];
    __shared__ float red[4];
    int lb = blockIdx.x + 42*blockIdx.y;
    int nb = (lb & 7) * 252 + (lb >> 3);
    int sx = nb % 42, sy = nb / 42;
    gemm_core<128,128,64,1,false,true,false>(
        As, Bs, red, sx*128, sy*128,
        h1b, Cc, Cc, h1b, Cc, 0, h1b, Cc, 0, wqkvT1, Cc, QKVb, QKVN, nullptr);
}

// ---------------------------------------------------------------------------
// fused epilogue gemm (+ optional layer-1 kNN in extra y-blocks)
template<bool OUT_BF16, bool DO_KNN>
__global__ __launch_bounds__(256)
void fused_kernel(const unsigned short* __restrict__ att,
                  const unsigned short* __restrict__ hseg,
                  const unsigned short* __restrict__ h0seg,
                  const unsigned short* __restrict__ fbtL,
                  void* __restrict__ Cv, float* __restrict__ stat,
                  const float* __restrict__ crd, int* __restrict__ nbr1) {
    __shared__ __align__(16) char smem[16400];
    if (DO_KNN && blockIdx.y >= 4) {
        int b = (blockIdx.y - 4) * 84 + blockIdx.x;
        if (b < Bb) knn_body(b, crd, 4, nbr1, (float(*)[3])smem);
        return;
    }
    unsigned short* As = (unsigned short*)smem;
    unsigned short* Bs = (unsigned short*)(smem + 8192);
    float* red = (float*)(smem + 16384);
    gemm_core<64,64,64,3,true,OUT_BF16,false>(
        As, Bs, red, blockIdx.x*64, blockIdx.y*64,
        att, HD, HD, hseg, Cc, Cc, h0seg, Cc, Cc,
        fbtL, KFUSE, Cv, Cc, stat);
}

// ---------------------------------------------------------------------------
// precise layer-0 coords + FUSED layer-0 attention: computes fp32 softmax
// weights in-register, shares them via LDS, then does the V gather/weighted
// sum for this row (identical per-output math & k-order as the old attnw).
__global__ __launch_bounds__(64)
void precise_kernel(const float* __restrict__ T, const float* __restrict__ h0,
                    const int* __restrict__ nbr, const float* __restrict__ vproj,
                    const float* __restrict__ wsum,
                    const unsigned short* __restrict__ QKV,
                    float* __restrict__ crd, unsigned short* __restrict__ att) {
    int i = blockIdx.x;
    int b = i / Jj;
    int l = threadIdx.x;
    __shared__ float Ts[8][260];
    __shared__ float nb[8][260];
    __shared__ float hi[256];
    __shared__ float wsL[64];
    __shared__ int nbs[KNN];
    #pragma unroll
    for (int u = 0; u < 8; ++u) {
        int idx = u*64 + l;
        float4 v = *(const float4*)&T[(size_t)i*HD + idx*4];
        int hh = idx >> 6, dd = (idx & 63) * 4;
        *(float4*)&Ts[hh][dd] = v;
    }
    *(float4*)&hi[l*4] = *(const float4*)&h0[(size_t)i*Cc + l*4];
    if (l < KNN) nbs[l] = nbr[i*KNN + l];
    int kq = l >> 3, s = l & 7;
    int njs = nbr[i*KNN + kq];
    const float* nrow = &h0[(size_t)(b*Jj + njs)*Cc];
    #pragma unroll
    for (int u = 0; u < 8; ++u)
        *(float4*)&nb[kq][(s*8+u)*4] = *(const float4*)&nrow[(s*8+u)*4];
    __syncthreads();

    int k = l >> 3, h = l & 7;
    float sacc = 0;
    #pragma unroll 8
    for (int d = 0; d < 256; d += 4) {
        float4 tv = *(const float4*)&Ts[h][d];
        float4 nv = *(const float4*)&nb[k][d];
        sacc += tv.x*nv.x + tv.y*nv.y + tv.z*nv.z + tv.w*nv.w;
    }
    float sc = sacc * 0.0625f;
    sc = (sc >= 0.0f) ? sc : 0.2f * sc;
    float m = sc;
    m = fmaxf(m, __shfl_xor(m, 8));
    m = fmaxf(m, __shfl_xor(m, 16));
    m = fmaxf(m, __shfl_xor(m, 32));
    float e = expf(sc - m);
    float den = e;
    den += __shfl_xor(den, 8); den += __shfl_xor(den, 16); den += __shfl_xor(den, 32);
    float w = e / den;
    wsL[l] = w;                            // wsL[k*8 + h]

    int njk = nbs[k];
    const float* vp = &vproj[(size_t)(b*Jj + njk)*24 + h*3];
    float t0 = w * vp[0], t1 = w * vp[1], t2 = w * vp[2];
    #pragma unroll
    for (int u = 0; u < 4; ++u) {
        int e4 = l*4 + u;
        float hv = hi[e4];
        float4 wv = *(const float4*)&wsum[e4*4];
        t0 += hv * wv.x; t1 += hv * wv.y; t2 += hv * wv.z;
    }
    #pragma unroll
    for (int sft = 1; sft < 64; sft <<= 1) {
        t0 += __shfl_xor(t0, sft); t1 += __shfl_xor(t1, sft); t2 += __shfl_xor(t2, sft);
    }
    if (l == 0) {
        crd[i*4+0] = fmaxf(t0, 0.0f);
        crd[i*4+1] = fmaxf(t1, 0.0f);
        crd[i*4+2] = fmaxf(t2, 0.0f);
        crd[i*4+3] = 0.0f;
    }
    __syncthreads();

    // ---- fused layer-0 attention: lane l -> head h2 = l>>3, d chunk sub*32
    int h2 = l >> 3, sub = l & 7;
    float o[32] = {};
    #pragma unroll
    for (int kk = 0; kk < KNN; ++kk) {
        float wk_ = wsL[kk*8 + h2];
        const unsigned short* vrow =
            &QKV[(size_t)(b*Jj + nbs[kk])*QKVN + 2*HD + h2*256 + sub*32];
        #pragma unroll
        for (int j = 0; j < 4; ++j) {
            u16x8 v = *(const u16x8*)(vrow + j*8);
            #pragma unroll
            for (int u = 0; u < 8; ++u) o[j*8+u] += wk_ * bf2f(v[u]);
        }
    }
    unsigned short* arow = &att[(size_t)i*HD + h2*256 + sub*32];
    #pragma unroll
    for (int j = 0; j < 4; ++j) {
        u16x8 ou;
        #pragma unroll
        for (int u = 0; u < 8; ++u) ou[u] = f2bf(o[j*8+u]);
        *(u16x8*)(arow + j*8) = ou;
    }
}

// ---------------------------------------------------------------------------
// layer-1 attention (score-based): one wave per (row, head-pair), XCD-chunked.
__global__ __launch_bounds__(64)
void attn_kernel(const unsigned short* __restrict__ QKV,
                 const int* __restrict__ nbr, unsigned short* __restrict__ att) {
    int lb = blockIdx.x;
    int gid = (lb & 7) * (Mrows*4/8) + (lb >> 3);
    int hp = gid & 3, row = gid >> 2, b = row / Jj;
    int lane = threadIdx.x;
    int h = hp*2 + (lane >> 5);
    int d0 = (lane & 31) * 8;

    u16x8 qu = *(const u16x8*)&QKV[(size_t)row*QKVN + h*Dd + d0];
    float qf[8];
    #pragma unroll
    for (int i = 0; i < 8; ++i) qf[i] = bf2f(qu[i]);
    const int* np_ = nbr + row * KNN;

    float sc[KNN]; int nb[KNN];
    #pragma unroll
    for (int k = 0; k < KNN; ++k) {
        int n = np_[k]; nb[k] = n;
        u16x8 ku = *(const u16x8*)&QKV[(size_t)(b*Jj + n)*QKVN + HD + h*Dd + d0];
        float p = 0;
        #pragma unroll
        for (int i = 0; i < 8; ++i) p += qf[i] * bf2f(ku[i]);
        #pragma unroll
        for (int s = 1; s < 32; s <<= 1) p += __shfl_xor(p, s);
        sc[k] = p;
    }
    float mx = -INFINITY;
    #pragma unroll
    for (int k = 0; k < KNN; ++k) {
        float s = sc[k] * 0.0625f;
        s = (s >= 0.0f) ? s : 0.2f * s;
        sc[k] = s; mx = fmaxf(mx, s);
    }
    float den = 0.0f;
    #pragma unroll
    for (int k = 0; k < KNN; ++k) { sc[k] = expf(sc[k] - mx); den += sc[k]; }
    float inv = 1.0f / den;
    float o[8] = {};
    #pragma unroll
    for (int k = 0; k < KNN; ++k) {
        u16x8 vu = *(const u16x8*)&QKV[(size_t)(b*Jj + nb[k])*QKVN + 2*HD + h*Dd + d0];
        float w = sc[k] * inv;
        #pragma unroll
        for (int i = 0; i < 8; ++i) o[i] += w * bf2f(vu[i]);
    }
    u16x8 ou;
    #pragma unroll
    for (int i = 0; i < 8; ++i) ou[i] = f2bf(o[i]);
    *(u16x8*)&att[(size_t)row*HD + h*Dd + d0] = ou;
}

// ---------------------------------------------------------------------------
__global__ __launch_bounds__(64)
void final_kernel(const float* __restrict__ h, const float* __restrict__ fcw,
                  const float* __restrict__ fcb, const float* __restrict__ stats,
                  float* __restrict__ out) {
    int row = blockIdx.x, lane = threadIdx.x;
    const float4 hv = *(const float4*)(h + (size_t)row*Cc + lane*4);
    float a0=0, a1=0, a2=0;
    const float hx[4] = {hv.x, hv.y, hv.z, hv.w};
    #pragma unroll
    for (int i = 0; i < 4; ++i) {
        int c = lane*4 + i;
        a0 += hx[i]*fcw[c*3+0]; a1 += hx[i]*fcw[c*3+1]; a2 += hx[i]*fcw[c*3+2];
    }
    #pragma unroll
    for (int s = 32; s > 0; s >>= 1) {
        a0 += __shfl_xor(a0, s); a1 += __shfl_xor(a1, s); a2 += __shfl_xor(a2, s);
    }
    if (lane == 0) {
        out[row*3+0] = a0 + fcb[0];
        out[row*3+1] = a1 + fcb[1];
        out[row*3+2] = a2 + fcb[2];
        if (row == 0)
            out[(size_t)Mrows*3] =
                (stats[0] + stats[1]) * (0.5f / ((float)Mrows * (float)Cc));
    }
}

// ---------------------------------------------------------------------------
extern "C" void kernel_launch(void* const* d_in, const int* in_sizes, int n_in,
                              void* d_out, int out_size, void* d_ws, size_t ws_size,
                              hipStream_t stream) {
    (void)in_sizes; (void)n_in; (void)out_size; (void)ws_size;
    const float* jf     = (const float*)d_in[0];
    const float* wq     = (const float*)d_in[1];
    const float* wk     = (const float*)d_in[2];
    const float* wv     = (const float*)d_in[3];
    const float* wp     = (const float*)d_in[4];
    const float* wsw    = (const float*)d_in[5];
    const float* wskip0 = (const float*)d_in[6];
    const float* fcw    = (const float*)d_in[7];
    const float* fcb    = (const float*)d_in[8];
    float* out = (float*)d_out;

    char* wsb = (char*)d_ws;
    unsigned short* QKVb  = (unsigned short*)(wsb + OFF_QKV);
    float*          Tm    = (float*)(wsb + OFF_T);
    unsigned short* attb  = (unsigned short*)(wsb + OFF_ATT);
    _Float16*       GT    = (_Float16*)(wsb + OFF_GT);
    unsigned short* jfb   = (unsigned short*)(wsb + OFF_JFB);
    _Float16*       jfh   = (_Float16*)(wsb + OFF_JFH);
    _Float16*       jfl   = (_Float16*)(wsb + OFF_JFL);
    _Float16*       jfd   = (_Float16*)(wsb + OFF_JFD);
    unsigned short* h1b   = (unsigned short*)(wsb + OFF_H1B);
    float*          h2f   = (float*)(wsb + OFF_H2F);
    unsigned short* wqkvT = (unsigned short*)(wsb + OFF_WQKVT);
    unsigned short* fbt   = (unsigned short*)(wsb + OFF_FBT);
    float*          Wvp   = (float*)(wsb + OFF_WVP);
    float*          vproj = (float*)(wsb + OFF_VPROJ);
    float*          wsum  = (float*)(wsb + OFF_WSUM);
    float*          crd   = (float*)(wsb + OFF_CRD);
    int*            nbr0  = (int*)(wsb + OFF_NBR0);
    int*            nbr1  = (int*)(wsb + OFF_NBR1);
    float*          stats = (float*)(wsb + OFF_STAT);

    // 1. all input-only prep in one launch (long poles dispatched first)
    mega_prep_kernel<<<6217, 256, 0, stream>>>(jf, wq, wk, wv, wp, wsw, wskip0,
                                               wqkvT, fbt, stats, wsum,
                                               jfb, jfh, jfl, jfd, GT, Wvp, nbr0);
    // 2. layer-0 V gemm + fp16-split T-gemm + vproj in one launch
    combo_kernel<<<dim3(42, 48), 256, 0, stream>>>(jfb, wqkvT, QKVb,
                                                   jfh, jfl, jfd, GT, Tm,
                                                   jf, Wvp, vproj);
    // 3. precise layer-0 coords + fused layer-0 attention (consumes Tm, V)
    precise_kernel<<<Mrows, 64, 0, stream>>>(Tm, jf, nbr0, vproj, wsum,
                                             QKVb, crd, attb);
    // 4. layer-0 fused output gemm + layer-1 kNN
    fused_kernel<true, true><<<dim3(84, 8), 256, 0, stream>>>(
        attb, jfb, jfb, fbt, h1b, &stats[0], crd, nbr1);
    // 5. layer-1 QKV gemm (XCD-chunked)
    qkv1_kernel<<<dim3(42, 48), 256, 0, stream>>>(h1b, wqkvT + (size_t)QKVN*Cc, QKVb);
    // 6. layer-1 attention (XCD-chunked)
    attn_kernel<<<Mrows*4, 64, 0, stream>>>(QKVb, nbr1, attb);
    // 7. layer-1 fused output gemm
    fused_kernel<false, false><<<dim3(84, 4), 256, 0, stream>>>(
        attb, h1b, jfb, fbt + (size_t)Cc*KFUSE, h2f, &stats[1], nullptr, nullptr);
    // 8. final
    final_kernel<<<Mrows, 64, 0, stream>>>(h2f, fcw, fcb, stats, out);
}

// Round 17
// 194.608 us; speedup vs baseline: 1.3634x; 1.0381x over previous
//
#include <hip/hip_runtime.h>
#include <hip/hip_bf16.h>
#include <math.h>
#include <type_traits>

namespace {
constexpr int Bb = 256, Jj = 21, Cc = 256, Hh = 8, Dd = 256;
constexpr int Mrows = Bb * Jj;      // 5376
constexpr int HD    = Hh * Dd;      // 2048
constexpr int QKVN  = 3 * HD;       // 6144
constexpr int KNN   = 8;
constexpr int KFUSE = HD + Cc + Cc; // 2560

// ---- workspace byte offsets ----
constexpr size_t OFF_QKV   = 0;                                   // bf16 5376x6144
constexpr size_t OFF_T     = OFF_QKV   + (size_t)Mrows*QKVN*2;    // f32  5376x2048
constexpr size_t OFF_ATT   = OFF_T     + (size_t)Mrows*HD*4;      // bf16 5376x2048
constexpr size_t OFF_GT    = OFF_ATT   + (size_t)Mrows*HD*2;      // f16  2048x768
constexpr size_t OFF_JFB   = OFF_GT    + (size_t)HD*768*2;        // bf16 5376x256
constexpr size_t OFF_JFH   = OFF_JFB   + (size_t)Mrows*Cc*2;      // f16  5376x256
constexpr size_t OFF_JFL   = OFF_JFH   + (size_t)Mrows*Cc*2;      // f16  5376x256
constexpr size_t OFF_JFD   = OFF_JFL   + (size_t)Mrows*Cc*2;      // f16  5376x256
constexpr size_t OFF_H1B   = OFF_JFD   + (size_t)Mrows*Cc*2;      // bf16 5376x256
constexpr size_t OFF_H2F   = OFF_H1B   + (size_t)Mrows*Cc*2;      // f32  5376x256
constexpr size_t OFF_WQKVT = OFF_H2F   + (size_t)Mrows*Cc*4;      // bf16 2x6144x256
constexpr size_t OFF_FBT   = OFF_WQKVT + (size_t)2*QKVN*Cc*2;     // bf16 2x256x2560
constexpr size_t OFF_WVP   = OFF_FBT   + (size_t)2*Cc*KFUSE*2;    // f32  256x24
constexpr size_t OFF_VPROJ = OFF_WVP   + (size_t)Cc*24*4;         // f32  5376x24
constexpr size_t OFF_WSUM  = OFF_VPROJ + (size_t)Mrows*24*4;      // f32  256x4
constexpr size_t OFF_CRD   = OFF_WSUM  + (size_t)Cc*4*4;          // f32  5376x4
constexpr size_t OFF_NBR0  = OFF_CRD   + (size_t)Mrows*4*4;       // int  5376x8
constexpr size_t OFF_NBR1  = OFF_NBR0  + (size_t)Mrows*KNN*4;
constexpr size_t OFF_STAT  = OFF_NBR1  + (size_t)Mrows*KNN*4;     // 2 f32
} // namespace

typedef short short8 __attribute__((ext_vector_type(8)));
typedef _Float16 half8 __attribute__((ext_vector_type(8)));
typedef _Float16 half4v __attribute__((ext_vector_type(4)));
typedef unsigned short u16x8 __attribute__((ext_vector_type(8)));
typedef float f32x4 __attribute__((ext_vector_type(4)));

__device__ __forceinline__ unsigned short f2bf(float x) {
    unsigned int u = __float_as_uint(x);
    u = u + 0x7fffu + ((u >> 16) & 1u);            // round-to-nearest-even
    return (unsigned short)(u >> 16);
}
__device__ __forceinline__ float bf2f(unsigned short b) {
    return __uint_as_float(((unsigned int)b) << 16);
}

// ---------------------------------------------------------------------------
// kNN body: exact stable-argsort ranks 1..8 by (d2, index).
__device__ __forceinline__ void knn_body(int b, const float* __restrict__ src,
                                         int ld, int* __restrict__ nbr,
                                         float (*cs)[3]) {
    int t = threadIdx.x;
    if (t < Jj) {
        const float* p = src + (size_t)(b * Jj + t) * ld;
        cs[t][0] = p[0]; cs[t][1] = p[1]; cs[t][2] = p[2];
    }
    __syncthreads();
    if (t < Jj) {
        float x = cs[t][0], y = cs[t][1], z = cs[t][2];
        float d2[Jj];
        #pragma unroll
        for (int jj = 0; jj < Jj; ++jj) {
            float dx = x - cs[jj][0], dy = y - cs[jj][1], dz = z - cs[jj][2];
            d2[jj] = dx*dx + dy*dy + dz*dz;
        }
        unsigned int used = 0u;
        int out_base = (b * Jj + t) * KNN;
        #pragma unroll
        for (int r = 0; r <= KNN; ++r) {
            int best = -1; float bd = INFINITY;
            #pragma unroll
            for (int jj = 0; jj < Jj; ++jj)
                if (!((used >> jj) & 1u) && d2[jj] < bd) { bd = d2[jj]; best = jj; }
            used |= (1u << best);
            if (r > 0) nbr[out_base + r - 1] = best;
        }
    }
}

// ---------------------------------------------------------------------------
// MEGA-PREP: one launch for all input-only work. Long poles dispatched FIRST:
// [0,256) g_gemm 32x64; [256,264) wvp; [264,520) knn0; 520 wsum/stats;
// [521,1865) cvt_split; [1865,6217) weight transposes.
__global__ __launch_bounds__(256)
void mega_prep_kernel(const float* __restrict__ jf,
                      const float* __restrict__ wq, const float* __restrict__ wk,
                      const float* __restrict__ wv, const float* __restrict__ wp,
                      const float* __restrict__ wsw, const float* __restrict__ wsk,
                      unsigned short* __restrict__ wqkvT,
                      unsigned short* __restrict__ fbt, float* __restrict__ stats,
                      float* __restrict__ wsum,
                      unsigned short* __restrict__ jfb, _Float16* __restrict__ jfh,
                      _Float16* __restrict__ jfl, _Float16* __restrict__ jfd,
                      _Float16* __restrict__ GT, float* __restrict__ Wvp2,
                      int* __restrict__ nbr0) {
    __shared__ __align__(16) char sm[17408];
    int bid = blockIdx.x;
    int tidx = threadIdx.x;

    if (bid < 256) {                       // ---- g_gemm 32x64 -> GT ----
        int h = bid >> 5, rem = bid & 31;
        int m0 = (rem >> 2) * 32, n0 = (rem & 3) * 64;
        float (*As)[36] = (float(*)[36])sm;              // 4608 B
        float (*Ws)[68] = (float(*)[68])(sm + 4608);     // 8704 B
        int ty = tidx >> 4, tx = tidx & 15;
        float acc[2][4] = {};
        for (int kb = 0; kb < 256; kb += 32) {
            {
                int row = tidx >> 3, col = (tidx & 7) * 4;
                float4 v = *(const float4*)&wq[(size_t)(m0 + row)*HD + h*256 + kb + col];
                As[col+0][row] = v.x; As[col+1][row] = v.y;
                As[col+2][row] = v.z; As[col+3][row] = v.w;
                int row2 = tidx >> 2, col2 = (tidx & 3) * 8;
                float4 u0 = *(const float4*)&wk[(size_t)(n0 + row2)*HD + h*256 + kb + col2];
                float4 u1 = *(const float4*)&wk[(size_t)(n0 + row2)*HD + h*256 + kb + col2 + 4];
                Ws[col2+0][row2] = u0.x; Ws[col2+1][row2] = u0.y;
                Ws[col2+2][row2] = u0.z; Ws[col2+3][row2] = u0.w;
                Ws[col2+4][row2] = u1.x; Ws[col2+5][row2] = u1.y;
                Ws[col2+6][row2] = u1.z; Ws[col2+7][row2] = u1.w;
            }
            __syncthreads();
            #pragma unroll
            for (int kk = 0; kk < 32; ++kk) {
                float a0 = As[kk][ty*2], a1 = As[kk][ty*2 + 1];
                float4 bv = *(const float4*)&Ws[kk][tx*4];
                float b4[4] = {bv.x, bv.y, bv.z, bv.w};
                #pragma unroll
                for (int j = 0; j < 4; ++j) {
                    acc[0][j] += a0 * b4[j];
                    acc[1][j] += a1 * b4[j];
                }
            }
            __syncthreads();
        }
        #pragma unroll
        for (int j = 0; j < 4; ++j) {
            int n = h*256 + n0 + tx*4 + j;
            float g0 = acc[0][j], g1 = acc[1][j];
            _Float16 h0_ = (_Float16)g0, h1_ = (_Float16)g1;
            _Float16* base = &GT[(size_t)n*768 + m0 + ty*2];
            base[0]   = h0_;                          base[1]   = h1_;
            base[256] = (_Float16)(g0 * 0.0625f);     base[257] = (_Float16)(g1 * 0.0625f);
            base[512] = (_Float16)((g0 - (float)h0_) * 128.0f);
            base[513] = (_Float16)((g1 - (float)h1_) * 128.0f);
        }
    } else if (bid < 264) {                // ---- wvp ----
        int h = bid - 256;
        float (*wpc)[3] = (float(*)[3])sm;
        int t = tidx;
        const float* p = &wp[(size_t)(h*256 + t) * Cc];
        wpc[t][0] = p[0]; wpc[t][1] = p[1]; wpc[t][2] = p[2];
        __syncthreads();
        const float* vr = &wv[(size_t)t*HD + h*256];
        float a0=0, a1=0, a2=0;
        for (int d = 0; d < 256; ++d) {
            float v = vr[d];
            a0 += v*wpc[d][0]; a1 += v*wpc[d][1]; a2 += v*wpc[d][2];
        }
        float* o = &Wvp2[(size_t)t*24 + h*3];
        o[0]=a0; o[1]=a1; o[2]=a2;
    } else if (bid < 520) {                // ---- knn layer 0 ----
        knn_body(bid - 264, jf, Cc, nbr0, (float(*)[3])sm);
    } else if (bid == 520) {               // ---- wsum + stats zero ----
        int e = tidx;
        float4 o;
        o.x = wsw[(size_t)e*Dd + 0] + wsk[(size_t)e*Dd + 0];
        o.y = wsw[(size_t)e*Dd + 1] + wsk[(size_t)e*Dd + 1];
        o.z = wsw[(size_t)e*Dd + 2] + wsk[(size_t)e*Dd + 2];
        o.w = 0.0f;
        *(float4*)&wsum[e*4] = o;
        if (e < 2) stats[e] = 0.0f;
    } else if (bid < 1865) {               // ---- cvt_split ----
        int i = (bid - 521) * 256 + tidx;
        float4 v = ((const float4*)jf)[i];
        float x[4] = {v.x, v.y, v.z, v.w};
        ushort4 ob; half4v oh, ol, od;
        #pragma unroll
        for (int u = 0; u < 4; ++u) {
            ((unsigned short*)&ob)[u] = f2bf(x[u]);
            _Float16 h = (_Float16)x[u];
            oh[u] = h;
            ol[u] = (_Float16)((x[u] - (float)h) * 16.0f);
            od[u] = (_Float16)(x[u] * 0.0078125f);   // /128
        }
        ((ushort4*)jfb)[i] = ob;
        ((half4v*)jfh)[i] = oh;
        ((half4v*)jfl)[i] = ol;
        ((half4v*)jfd)[i] = od;
    } else {                               // ---- weight transposes ----
        int tt = bid - 1865;
        const float* src; unsigned short* dst;
        int ldin, ldout, tilesX, tile;
        constexpr size_t CH = (size_t)Cc * HD;
        if (tt < 3072) {
            int op = tt >> 9; tile = tt & 511; tilesX = 64;
            ldin = HD; ldout = Cc;
            const float* s3[3] = {wq, wk, wv};
            src = s3[op % 3] + (size_t)(op / 3) * CH;
            dst = wqkvT + (size_t)(op % 3) * HD * Cc + (size_t)(op / 3) * QKVN * Cc;
        } else if (tt < 4096) {
            int op = (tt - 3072) >> 9; tile = (tt - 3072) & 511; tilesX = 8;
            ldin = Cc; ldout = KFUSE;
            src = wp + (size_t)op * HD * Cc;
            dst = fbt + (size_t)op * Cc * KFUSE;
        } else {
            int q = tt - 4096; int op = q >> 6; tile = q & 63; tilesX = 8;
            ldin = Cc; ldout = KFUSE;
            const float* s4[4] = {wsw, wsw + (size_t)Cc * Cc, wsk, wsk};
            src = s4[op];
            dst = fbt + (size_t)(op & 1) * Cc * KFUSE + HD + (size_t)(op >> 1) * Cc;
        }
        int bx = tile % tilesX, by = tile / tilesX;
        int n0 = bx * 32, k0 = by * 32;
        float (*t)[33] = (float(*)[33])sm;
        int r = tidx >> 3, c4 = (tidx & 7) * 4;
        float4 v = *(const float4*)&src[(size_t)(k0 + r) * ldin + n0 + c4];
        t[r][c4+0] = v.x; t[r][c4+1] = v.y; t[r][c4+2] = v.z; t[r][c4+3] = v.w;
        __syncthreads();
        ushort4 o;
        o.x = f2bf(t[c4+0][r]); o.y = f2bf(t[c4+1][r]);
        o.z = f2bf(t[c4+2][r]); o.w = f2bf(t[c4+3][r]);
        *(ushort4*)&dst[(size_t)(n0 + r) * ldout + k0 + c4] = o;
    }
}

// ---------------------------------------------------------------------------
// 16-bit MFMA GEMM core, XOR-swizzled LDS.
template<int BM, int BN, int BK, int NSEG, bool RELU_STATS, bool OUT_BF16, bool F16>
__device__ __forceinline__
void gemm_core(unsigned short* As, unsigned short* Bs, float* red,
               int bm, int bn,
               const unsigned short* __restrict__ A0, int lda0, int klen0,
               const unsigned short* __restrict__ A1, int lda1, int klen1,
               const unsigned short* __restrict__ A2, int lda2, int klen2,
               const unsigned short* __restrict__ Bt, int ldb,
               void* __restrict__ Cv, int ldc, float* __restrict__ stat) {
    constexpr int WM = BM/2, WN = BN/2;
    constexpr int MW = WM/16, NW = WN/16, KW = BK/32;
    constexpr int CHUNKA = BM*BK/8;
    constexpr int CHUNKB = BN*BK/8;
    constexpr int KB8 = BK/8;
    constexpr int SWZ = KB8 - 1;
    using frag = std::conditional_t<F16, half8, short8>;

    int tid = threadIdx.x;
    int wid = tid >> 6, lane = tid & 63;
    int wr = wid >> 1, wc = wid & 1;

    f32x4 acc[MW][NW];
    #pragma unroll
    for (int m = 0; m < MW; ++m)
        #pragma unroll
        for (int n = 0; n < NW; ++n)
            acc[m][n] = (f32x4){0.f, 0.f, 0.f, 0.f};

    const unsigned short* Aseg[3] = {A0, A1, A2};
    const int ldas[3] = {lda0, lda1, lda2};
    const int klens[3] = {klen0, klen1, klen2};

    int kglob = 0;
    for (int seg = 0; seg < NSEG; ++seg) {
        const unsigned short* A = Aseg[seg];
        const int lda = ldas[seg];
        const int klen = klens[seg];
        for (int k0 = 0; k0 < klen; k0 += BK) {
            #pragma unroll
            for (int it = 0; it < CHUNKA/256; ++it) {
                int c = tid + it*256;
                int row = c / KB8;
                int kp = (c % KB8) ^ (row & SWZ);
                __builtin_amdgcn_global_load_lds(
                    (const __attribute__((address_space(1))) unsigned int*)
                        (A + (size_t)(bm + row)*lda + k0 + kp*8),
                    (__attribute__((address_space(3))) unsigned int*)(As + c*8),
                    16, 0, 0);
            }
            #pragma unroll
            for (int it = 0; it < CHUNKB/256; ++it) {
                int c = tid + it*256;
                int row = c / KB8;
                int kp = (c % KB8) ^ (row & SWZ);
                __builtin_amdgcn_global_load_lds(
                    (const __attribute__((address_space(1))) unsigned int*)
                        (Bt + (size_t)(bn + row)*ldb + kglob + k0 + kp*8),
                    (__attribute__((address_space(3))) unsigned int*)(Bs + c*8),
                    16, 0, 0);
            }
            __syncthreads();
            #pragma unroll
            for (int kp = 0; kp < KW; ++kp) {
                frag af[MW], bf[NW];
                int cbase = kp*4 + (lane >> 4);
                #pragma unroll
                for (int m = 0; m < MW; ++m) {
                    int r = wr*WM + m*16 + (lane & 15);
                    af[m] = *(const frag*)&As[r*BK + ((cbase ^ (r & SWZ))*8)];
                }
                #pragma unroll
                for (int n = 0; n < NW; ++n) {
                    int r = wc*WN + n*16 + (lane & 15);
                    bf[n] = *(const frag*)&Bs[r*BK + ((cbase ^ (r & SWZ))*8)];
                }
                #pragma unroll
                for (int m = 0; m < MW; ++m)
                    #pragma unroll
                    for (int n = 0; n < NW; ++n) {
                        if constexpr (F16)
                            acc[m][n] = __builtin_amdgcn_mfma_f32_16x16x32_f16(
                                af[m], bf[n], acc[m][n], 0, 0, 0);
                        else
                            acc[m][n] = __builtin_amdgcn_mfma_f32_16x16x32_bf16(
                                af[m], bf[n], acc[m][n], 0, 0, 0);
                    }
            }
            __syncthreads();
        }
        kglob += klen;
    }

    int cr = (lane >> 4)*4, cc = lane & 15;
    float bsum = 0.0f;
    #pragma unroll
    for (int m = 0; m < MW; ++m)
        #pragma unroll
        for (int n = 0; n < NW; ++n)
            #pragma unroll
            for (int j = 0; j < 4; ++j) {
                float v = acc[m][n][j];
                if (RELU_STATS) { v = fmaxf(v, 0.0f); bsum += v; }
                size_t row = bm + wr*WM + m*16 + cr + j;
                size_t col = bn + wc*WN + n*16 + cc;
                if (OUT_BF16) ((unsigned short*)Cv)[row*ldc + col] = f2bf(v);
                else          ((float*)Cv)[row*ldc + col] = v;
            }
    if (RELU_STATS) {
        #pragma unroll
        for (int sft = 1; sft < 64; sft <<= 1) bsum += __shfl_xor(bsum, sft);
        if (lane == 0) red[wid] = bsum;
        __syncthreads();
        if (tid == 0) atomicAdd(stat, red[0] + red[1] + red[2] + red[3]);
    }
}

// ---------------------------------------------------------------------------
// COMBO: y<16 -> layer-0 V gemm (writes V columns of QKVb, XCD-chunked);
// y in [16,32) -> fp16-split T-gemm (XCD-chunked); y in [32,48) -> vproj.
__global__ __launch_bounds__(256)
void combo_kernel(const unsigned short* __restrict__ jfb,
                  const unsigned short* __restrict__ wqkvT,
                  unsigned short* __restrict__ QKVb,
                  const _Float16* __restrict__ jfh, const _Float16* __restrict__ jfl,
                  const _Float16* __restrict__ jfd, const _Float16* __restrict__ GT,
                  float* __restrict__ Tm,
                  const float* __restrict__ jf, const float* __restrict__ Wvp2,
                  float* __restrict__ vproj) {
    __shared__ __align__(16) char smem[32784];
    unsigned short* As = (unsigned short*)smem;
    unsigned short* Bs = (unsigned short*)(smem + 16384);
    float* red = (float*)(smem + 32768);
    int x = blockIdx.x, y = blockIdx.y;
    if (y < 16) {
        int lb = x + 42*y;                 // 672 blocks
        int nb = (lb & 7) * 84 + (lb >> 3);
        int sx = nb % 42, sy = nb / 42;
        gemm_core<128,128,64,1,false,true,false>(As, Bs, red, sx*128,
            2*HD + sy*128,
            jfb, Cc, Cc, jfb, Cc, 0, jfb, Cc, 0, wqkvT, Cc, QKVb, QKVN, nullptr);
    } else if (y < 32) {
        int lb = x + 42*(y - 16);
        int nb = (lb & 7) * 84 + (lb >> 3);
        int sx = nb / 16, sy = nb % 16;
        gemm_core<128,128,64,3,false,false,true>(As, Bs, red, sx*128, sy*128,
            (const unsigned short*)jfh, Cc, Cc, (const unsigned short*)jfl, Cc, Cc,
            (const unsigned short*)jfd, Cc, Cc, (const unsigned short*)GT, 768,
            Tm, HD, nullptr);
    } else {
        int q = (y - 32) * 42 + x;
        float (*hr)[256] = (float(*)[256])smem;
        float* wl = (float*)(smem + 8192);
        int t = threadIdx.x;
        int j0 = q * 8;
        #pragma unroll
        for (int i = 0; i < 6; ++i)
            *(float4*)&wl[t*4 + i*1024] = *(const float4*)&Wvp2[t*4 + i*1024];
        {
            int r = t >> 5, c = (t & 31) * 8;
            const float* src = &jf[(size_t)(j0 + r)*Cc + c];
            *(float4*)&hr[r][c]   = *(const float4*)src;
            *(float4*)&hr[r][c+4] = *(const float4*)(src + 4);
        }
        __syncthreads();
        int r = t >> 5, o = t & 31;
        if (o < 24) {
            float a = 0.0f;
            for (int e = 0; e < 256; ++e) a += hr[r][e] * wl[e*24 + o];
            vproj[(size_t)(j0 + r)*24 + o] = a;
        }
    }
}

// ---------------------------------------------------------------------------
// layer-1 QKV gemm with XCD-chunked swizzle (grid 42x48, 2016 blocks).
__global__ __launch_bounds__(256)
void qkv1_kernel(const unsigned short* __restrict__ h1b,
                 const unsigned short* __restrict__ wqkvT1,
                 unsigned short* __restrict__ QKVb) {
    __shared__ __align__(16) unsigned short As[128*64];
    __shared__ __align__(16) unsigned short Bs[128*64];
    __shared__ float red[4];
    int lb = blockIdx.x + 42*blockIdx.y;
    int nb = (lb & 7) * 252 + (lb >> 3);
    int sx = nb % 42, sy = nb / 42;
    gemm_core<128,128,64,1,false,true,false>(
        As, Bs, red, sx*128, sy*128,
        h1b, Cc, Cc, h1b, Cc, 0, h1b, Cc, 0, wqkvT1, Cc, QKVb, QKVN, nullptr);
}

// ---------------------------------------------------------------------------
// fused epilogue gemm (+ optional layer-1 kNN in extra y-blocks)
template<bool OUT_BF16, bool DO_KNN>
__global__ __launch_bounds__(256)
void fused_kernel(const unsigned short* __restrict__ att,
                  const unsigned short* __restrict__ hseg,
                  const unsigned short* __restrict__ h0seg,
                  const unsigned short* __restrict__ fbtL,
                  void* __restrict__ Cv, float* __restrict__ stat,
                  const float* __restrict__ crd, int* __restrict__ nbr1) {
    __shared__ __align__(16) char smem[16400];
    if (DO_KNN && blockIdx.y >= 4) {
        int b = (blockIdx.y - 4) * 84 + blockIdx.x;
        if (b < Bb) knn_body(b, crd, 4, nbr1, (float(*)[3])smem);
        return;
    }
    unsigned short* As = (unsigned short*)smem;
    unsigned short* Bs = (unsigned short*)(smem + 8192);
    float* red = (float*)(smem + 16384);
    gemm_core<64,64,64,3,true,OUT_BF16,false>(
        As, Bs, red, blockIdx.x*64, blockIdx.y*64,
        att, HD, HD, hseg, Cc, Cc, h0seg, Cc, Cc,
        fbtL, KFUSE, Cv, Cc, stat);
}

// ---------------------------------------------------------------------------
// precise layer-0 coords + FUSED layer-0 attention; XCD-chunked grid so each
// XCD owns 32 whole batches (V/h0 gather set ~3.4MB < 4MB L2/XCD).
__global__ __launch_bounds__(64)
void precise_kernel(const float* __restrict__ T, const float* __restrict__ h0,
                    const int* __restrict__ nbr, const float* __restrict__ vproj,
                    const float* __restrict__ wsum,
                    const unsigned short* __restrict__ QKV,
                    float* __restrict__ crd, unsigned short* __restrict__ att) {
    int lb = blockIdx.x;
    int i = (lb & 7) * (Mrows/8) + (lb >> 3);   // bijective: 5376 % 8 == 0
    int b = i / Jj;
    int l = threadIdx.x;
    __shared__ float Ts[8][260];
    __shared__ float nb[8][260];
    __shared__ float hi[256];
    __shared__ float wsL[64];
    __shared__ int nbs[KNN];
    #pragma unroll
    for (int u = 0; u < 8; ++u) {
        int idx = u*64 + l;
        float4 v = *(const float4*)&T[(size_t)i*HD + idx*4];
        int hh = idx >> 6, dd = (idx & 63) * 4;
        *(float4*)&Ts[hh][dd] = v;
    }
    *(float4*)&hi[l*4] = *(const float4*)&h0[(size_t)i*Cc + l*4];
    if (l < KNN) nbs[l] = nbr[i*KNN + l];
    int kq = l >> 3, s = l & 7;
    int njs = nbr[i*KNN + kq];
    const float* nrow = &h0[(size_t)(b*Jj + njs)*Cc];
    #pragma unroll
    for (int u = 0; u < 8; ++u)
        *(float4*)&nb[kq][(s*8+u)*4] = *(const float4*)&nrow[(s*8+u)*4];
    __syncthreads();

    int k = l >> 3, h = l & 7;
    float sacc = 0;
    #pragma unroll 8
    for (int d = 0; d < 256; d += 4) {
        float4 tv = *(const float4*)&Ts[h][d];
        float4 nv = *(const float4*)&nb[k][d];
        sacc += tv.x*nv.x + tv.y*nv.y + tv.z*nv.z + tv.w*nv.w;
    }
    float sc = sacc * 0.0625f;
    sc = (sc >= 0.0f) ? sc : 0.2f * sc;
    float m = sc;
    m = fmaxf(m, __shfl_xor(m, 8));
    m = fmaxf(m, __shfl_xor(m, 16));
    m = fmaxf(m, __shfl_xor(m, 32));
    float e = expf(sc - m);
    float den = e;
    den += __shfl_xor(den, 8); den += __shfl_xor(den, 16); den += __shfl_xor(den, 32);
    float w = e / den;
    wsL[l] = w;                            // wsL[k*8 + h]

    int njk = nbs[k];
    const float* vp = &vproj[(size_t)(b*Jj + njk)*24 + h*3];
    float t0 = w * vp[0], t1 = w * vp[1], t2 = w * vp[2];
    #pragma unroll
    for (int u = 0; u < 4; ++u) {
        int e4 = l*4 + u;
        float hv = hi[e4];
        float4 wv = *(const float4*)&wsum[e4*4];
        t0 += hv * wv.x; t1 += hv * wv.y; t2 += hv * wv.z;
    }
    #pragma unroll
    for (int sft = 1; sft < 64; sft <<= 1) {
        t0 += __shfl_xor(t0, sft); t1 += __shfl_xor(t1, sft); t2 += __shfl_xor(t2, sft);
    }
    if (l == 0) {
        crd[i*4+0] = fmaxf(t0, 0.0f);
        crd[i*4+1] = fmaxf(t1, 0.0f);
        crd[i*4+2] = fmaxf(t2, 0.0f);
        crd[i*4+3] = 0.0f;
    }
    __syncthreads();

    // ---- fused layer-0 attention: lane l -> head h2 = l>>3, d chunk sub*32
    int h2 = l >> 3, sub = l & 7;
    float o[32] = {};
    #pragma unroll
    for (int kk = 0; kk < KNN; ++kk) {
        float wk_ = wsL[kk*8 + h2];
        const unsigned short* vrow =
            &QKV[(size_t)(b*Jj + nbs[kk])*QKVN + 2*HD + h2*256 + sub*32];
        #pragma unroll
        for (int j = 0; j < 4; ++j) {
            u16x8 v = *(const u16x8*)(vrow + j*8);
            #pragma unroll
            for (int u = 0; u < 8; ++u) o[j*8+u] += wk_ * bf2f(v[u]);
        }
    }
    unsigned short* arow = &att[(size_t)i*HD + h2*256 + sub*32];
    #pragma unroll
    for (int j = 0; j < 4; ++j) {
        u16x8 ou;
        #pragma unroll
        for (int u = 0; u < 8; ++u) ou[u] = f2bf(o[j*8+u]);
        *(u16x8*)(arow + j*8) = ou;
    }
}

// ---------------------------------------------------------------------------
// layer-1 attention (score-based): one wave per (row, head-pair), XCD-chunked.
__global__ __launch_bounds__(64)
void attn_kernel(const unsigned short* __restrict__ QKV,
                 const int* __restrict__ nbr, unsigned short* __restrict__ att) {
    int lb = blockIdx.x;
    int gid = (lb & 7) * (Mrows*4/8) + (lb >> 3);
    int hp = gid & 3, row = gid >> 2, b = row / Jj;
    int lane = threadIdx.x;
    int h = hp*2 + (lane >> 5);
    int d0 = (lane & 31) * 8;

    u16x8 qu = *(const u16x8*)&QKV[(size_t)row*QKVN + h*Dd + d0];
    float qf[8];
    #pragma unroll
    for (int i = 0; i < 8; ++i) qf[i] = bf2f(qu[i]);
    const int* np_ = nbr + row * KNN;

    float sc[KNN]; int nb[KNN];
    #pragma unroll
    for (int k = 0; k < KNN; ++k) {
        int n = np_[k]; nb[k] = n;
        u16x8 ku = *(const u16x8*)&QKV[(size_t)(b*Jj + n)*QKVN + HD + h*Dd + d0];
        float p = 0;
        #pragma unroll
        for (int i = 0; i < 8; ++i) p += qf[i] * bf2f(ku[i]);
        #pragma unroll
        for (int s = 1; s < 32; s <<= 1) p += __shfl_xor(p, s);
        sc[k] = p;
    }
    float mx = -INFINITY;
    #pragma unroll
    for (int k = 0; k < KNN; ++k) {
        float s = sc[k] * 0.0625f;
        s = (s >= 0.0f) ? s : 0.2f * s;
        sc[k] = s; mx = fmaxf(mx, s);
    }
    float den = 0.0f;
    #pragma unroll
    for (int k = 0; k < KNN; ++k) { sc[k] = expf(sc[k] - mx); den += sc[k]; }
    float inv = 1.0f / den;
    float o[8] = {};
    #pragma unroll
    for (int k = 0; k < KNN; ++k) {
        u16x8 vu = *(const u16x8*)&QKV[(size_t)(b*Jj + nb[k])*QKVN + 2*HD + h*Dd + d0];
        float w = sc[k] * inv;
        #pragma unroll
        for (int i = 0; i < 8; ++i) o[i] += w * bf2f(vu[i]);
    }
    u16x8 ou;
    #pragma unroll
    for (int i = 0; i < 8; ++i) ou[i] = f2bf(o[i]);
    *(u16x8*)&att[(size_t)row*HD + h*Dd + d0] = ou;
}

// ---------------------------------------------------------------------------
__global__ __launch_bounds__(64)
void final_kernel(const float* __restrict__ h, const float* __restrict__ fcw,
                  const float* __restrict__ fcb, const float* __restrict__ stats,
                  float* __restrict__ out) {
    int row = blockIdx.x, lane = threadIdx.x;
    const float4 hv = *(const float4*)(h + (size_t)row*Cc + lane*4);
    float a0=0, a1=0, a2=0;
    const float hx[4] = {hv.x, hv.y, hv.z, hv.w};
    #pragma unroll
    for (int i = 0; i < 4; ++i) {
        int c = lane*4 + i;
        a0 += hx[i]*fcw[c*3+0]; a1 += hx[i]*fcw[c*3+1]; a2 += hx[i]*fcw[c*3+2];
    }
    #pragma unroll
    for (int s = 32; s > 0; s >>= 1) {
        a0 += __shfl_xor(a0, s); a1 += __shfl_xor(a1, s); a2 += __shfl_xor(a2, s);
    }
    if (lane == 0) {
        out[row*3+0] = a0 + fcb[0];
        out[row*3+1] = a1 + fcb[1];
        out[row*3+2] = a2 + fcb[2];
        if (row == 0)
            out[(size_t)Mrows*3] =
                (stats[0] + stats[1]) * (0.5f / ((float)Mrows * (float)Cc));
    }
}

// ---------------------------------------------------------------------------
extern "C" void kernel_launch(void* const* d_in, const int* in_sizes, int n_in,
                              void* d_out, int out_size, void* d_ws, size_t ws_size,
                              hipStream_t stream) {
    (void)in_sizes; (void)n_in; (void)out_size; (void)ws_size;
    const float* jf     = (const float*)d_in[0];
    const float* wq     = (const float*)d_in[1];
    const float* wk     = (const float*)d_in[2];
    const float* wv     = (const float*)d_in[3];
    const float* wp     = (const float*)d_in[4];
    const float* wsw    = (const float*)d_in[5];
    const float* wskip0 = (const float*)d_in[6];
    const float* fcw    = (const float*)d_in[7];
    const float* fcb    = (const float*)d_in[8];
    float* out = (float*)d_out;

    char* wsb = (char*)d_ws;
    unsigned short* QKVb  = (unsigned short*)(wsb + OFF_QKV);
    float*          Tm    = (float*)(wsb + OFF_T);
    unsigned short* attb  = (unsigned short*)(wsb + OFF_ATT);
    _Float16*       GT    = (_Float16*)(wsb + OFF_GT);
    unsigned short* jfb   = (unsigned short*)(wsb + OFF_JFB);
    _Float16*       jfh   = (_Float16*)(wsb + OFF_JFH);
    _Float16*       jfl   = (_Float16*)(wsb + OFF_JFL);
    _Float16*       jfd   = (_Float16*)(wsb + OFF_JFD);
    unsigned short* h1b   = (unsigned short*)(wsb + OFF_H1B);
    float*          h2f   = (float*)(wsb + OFF_H2F);
    unsigned short* wqkvT = (unsigned short*)(wsb + OFF_WQKVT);
    unsigned short* fbt   = (unsigned short*)(wsb + OFF_FBT);
    float*          Wvp   = (float*)(wsb + OFF_WVP);
    float*          vproj = (float*)(wsb + OFF_VPROJ);
    float*          wsum  = (float*)(wsb + OFF_WSUM);
    float*          crd   = (float*)(wsb + OFF_CRD);
    int*            nbr0  = (int*)(wsb + OFF_NBR0);
    int*            nbr1  = (int*)(wsb + OFF_NBR1);
    float*          stats = (float*)(wsb + OFF_STAT);

    // 1. all input-only prep in one launch (long poles dispatched first)
    mega_prep_kernel<<<6217, 256, 0, stream>>>(jf, wq, wk, wv, wp, wsw, wskip0,
                                               wqkvT, fbt, stats, wsum,
                                               jfb, jfh, jfl, jfd, GT, Wvp, nbr0);
    // 2. layer-0 V gemm + fp16-split T-gemm + vproj in one launch
    combo_kernel<<<dim3(42, 48), 256, 0, stream>>>(jfb, wqkvT, QKVb,
                                                   jfh, jfl, jfd, GT, Tm,
                                                   jf, Wvp, vproj);
    // 3. precise layer-0 coords + fused layer-0 attention (XCD-chunked)
    precise_kernel<<<Mrows, 64, 0, stream>>>(Tm, jf, nbr0, vproj, wsum,
                                             QKVb, crd, attb);
    // 4. layer-0 fused output gemm + layer-1 kNN
    fused_kernel<true, true><<<dim3(84, 8), 256, 0, stream>>>(
        attb, jfb, jfb, fbt, h1b, &stats[0], crd, nbr1);
    // 5. layer-1 QKV gemm (XCD-chunked)
    qkv1_kernel<<<dim3(42, 48), 256, 0, stream>>>(h1b, wqkvT + (size_t)QKVN*Cc, QKVb);
    // 6. layer-1 attention (XCD-chunked)
    attn_kernel<<<Mrows*4, 64, 0, stream>>>(QKVb, nbr1, attb);
    // 7. layer-1 fused output gemm
    fused_kernel<false, false><<<dim3(84, 4), 256, 0, stream>>>(
        attb, h1b, jfb, fbt + (size_t)Cc*KFUSE, h2f, &stats[1], nullptr, nullptr);
    // 8. final
    final_kernel<<<Mrows, 64, 0, stream>>>(h2f, fcw, fcb, stats, out);
}

// Round 18
// 191.526 us; speedup vs baseline: 1.3854x; 1.0161x over previous
//
#include <hip/hip_runtime.h>
#include <hip/hip_bf16.h>
#include <math.h>
#include <type_traits>

namespace {
constexpr int Bb = 256, Jj = 21, Cc = 256, Hh = 8, Dd = 256;
constexpr int Mrows = Bb * Jj;      // 5376
constexpr int HD    = Hh * Dd;      // 2048
constexpr int QKVN  = 3 * HD;       // 6144
constexpr int KNN   = 8;
constexpr int KFUSE = HD + Cc + Cc; // 2560

// ---- workspace byte offsets ----
constexpr size_t OFF_QKV   = 0;                                   // bf16 5376x6144
constexpr size_t OFF_T     = OFF_QKV   + (size_t)Mrows*QKVN*2;    // f32  5376x2048
constexpr size_t OFF_ATT   = OFF_T     + (size_t)Mrows*HD*4;      // bf16 5376x2048
constexpr size_t OFF_GT    = OFF_ATT   + (size_t)Mrows*HD*2;      // f16  2048x768
constexpr size_t OFF_G1T   = OFF_GT    + (size_t)HD*768*2;        // bf16 2048x256
constexpr size_t OFF_JFB   = OFF_G1T   + (size_t)HD*Cc*2;         // bf16 5376x256
constexpr size_t OFF_JFH   = OFF_JFB   + (size_t)Mrows*Cc*2;      // f16  5376x256
constexpr size_t OFF_JFL   = OFF_JFH   + (size_t)Mrows*Cc*2;      // f16  5376x256
constexpr size_t OFF_JFD   = OFF_JFL   + (size_t)Mrows*Cc*2;      // f16  5376x256
constexpr size_t OFF_H1B   = OFF_JFD   + (size_t)Mrows*Cc*2;      // bf16 5376x256
constexpr size_t OFF_H2F   = OFF_H1B   + (size_t)Mrows*Cc*2;      // f32  5376x256
constexpr size_t OFF_WQKVT = OFF_H2F   + (size_t)Mrows*Cc*4;      // bf16 2x6144x256
constexpr size_t OFF_FBT   = OFF_WQKVT + (size_t)2*QKVN*Cc*2;     // bf16 2x256x2560
constexpr size_t OFF_WVP   = OFF_FBT   + (size_t)2*Cc*KFUSE*2;    // f32  256x24
constexpr size_t OFF_VPROJ = OFF_WVP   + (size_t)Cc*24*4;         // f32  5376x24
constexpr size_t OFF_WSUM  = OFF_VPROJ + (size_t)Mrows*24*4;      // f32  256x4
constexpr size_t OFF_CRD   = OFF_WSUM  + (size_t)Cc*4*4;          // f32  5376x4
constexpr size_t OFF_NBR0  = OFF_CRD   + (size_t)Mrows*4*4;       // int  5376x8
constexpr size_t OFF_NBR1  = OFF_NBR0  + (size_t)Mrows*KNN*4;
constexpr size_t OFF_STAT  = OFF_NBR1  + (size_t)Mrows*KNN*4;     // 2 f32
} // namespace

typedef short short8 __attribute__((ext_vector_type(8)));
typedef _Float16 half8 __attribute__((ext_vector_type(8)));
typedef _Float16 half4v __attribute__((ext_vector_type(4)));
typedef unsigned short u16x8 __attribute__((ext_vector_type(8)));
typedef float f32x4 __attribute__((ext_vector_type(4)));

__device__ __forceinline__ unsigned short f2bf(float x) {
    unsigned int u = __float_as_uint(x);
    u = u + 0x7fffu + ((u >> 16) & 1u);            // round-to-nearest-even
    return (unsigned short)(u >> 16);
}
__device__ __forceinline__ float bf2f(unsigned short b) {
    return __uint_as_float(((unsigned int)b) << 16);
}

// ---------------------------------------------------------------------------
// kNN body: exact stable-argsort ranks 1..8 by (d2, index).
__device__ __forceinline__ void knn_body(int b, const float* __restrict__ src,
                                         int ld, int* __restrict__ nbr,
                                         float (*cs)[3]) {
    int t = threadIdx.x;
    if (t < Jj) {
        const float* p = src + (size_t)(b * Jj + t) * ld;
        cs[t][0] = p[0]; cs[t][1] = p[1]; cs[t][2] = p[2];
    }
    __syncthreads();
    if (t < Jj) {
        float x = cs[t][0], y = cs[t][1], z = cs[t][2];
        float d2[Jj];
        #pragma unroll
        for (int jj = 0; jj < Jj; ++jj) {
            float dx = x - cs[jj][0], dy = y - cs[jj][1], dz = z - cs[jj][2];
            d2[jj] = dx*dx + dy*dy + dz*dz;
        }
        unsigned int used = 0u;
        int out_base = (b * Jj + t) * KNN;
        #pragma unroll
        for (int r = 0; r <= KNN; ++r) {
            int best = -1; float bd = INFINITY;
            #pragma unroll
            for (int jj = 0; jj < Jj; ++jj)
                if (!((used >> jj) & 1u) && d2[jj] < bd) { bd = d2[jj]; best = jj; }
            used |= (1u << best);
            if (r > 0) nbr[out_base + r - 1] = best;
        }
    }
}

// ---------------------------------------------------------------------------
// g-gemm body: 32x64 tile of G_h = wq_h @ wk_h^T (fp32 accum).
// acc[2][4] per thread; caller handles epilogue.
__device__ __forceinline__ void g_gemm_body(const float* __restrict__ wq,
                                            const float* __restrict__ wk,
                                            int h, int m0, int n0, char* sm,
                                            float acc[2][4]) {
    float (*As)[36] = (float(*)[36])sm;              // 4608 B
    float (*Ws)[68] = (float(*)[68])(sm + 4608);     // 8704 B
    int tidx = threadIdx.x;
    int ty = tidx >> 4, tx = tidx & 15;
    for (int kb = 0; kb < 256; kb += 32) {
        {
            int row = tidx >> 3, col = (tidx & 7) * 4;
            float4 v = *(const float4*)&wq[(size_t)(m0 + row)*HD + h*256 + kb + col];
            As[col+0][row] = v.x; As[col+1][row] = v.y;
            As[col+2][row] = v.z; As[col+3][row] = v.w;
            int row2 = tidx >> 2, col2 = (tidx & 3) * 8;
            float4 u0 = *(const float4*)&wk[(size_t)(n0 + row2)*HD + h*256 + kb + col2];
            float4 u1 = *(const float4*)&wk[(size_t)(n0 + row2)*HD + h*256 + kb + col2 + 4];
            Ws[col2+0][row2] = u0.x; Ws[col2+1][row2] = u0.y;
            Ws[col2+2][row2] = u0.z; Ws[col2+3][row2] = u0.w;
            Ws[col2+4][row2] = u1.x; Ws[col2+5][row2] = u1.y;
            Ws[col2+6][row2] = u1.z; Ws[col2+7][row2] = u1.w;
        }
        __syncthreads();
        #pragma unroll
        for (int kk = 0; kk < 32; ++kk) {
            float a0 = As[kk][ty*2], a1 = As[kk][ty*2 + 1];
            float4 bv = *(const float4*)&Ws[kk][tx*4];
            float b4[4] = {bv.x, bv.y, bv.z, bv.w};
            #pragma unroll
            for (int j = 0; j < 4; ++j) {
                acc[0][j] += a0 * b4[j];
                acc[1][j] += a1 * b4[j];
            }
        }
        __syncthreads();
    }
}

// ---------------------------------------------------------------------------
// MEGA-PREP: one launch for all input-only work. Long poles dispatched FIRST:
// [0,256) g_gemm L0 (fp16-split GT); [256,512) g_gemm L1 (bf16 G1T);
// [512,520) wvp; [520,776) knn0; 776 wsum/stats; [777,2121) cvt_split;
// [2121,5449) weight transposes (q0,k0,v0,v1, wp x2, ws/wskip).
__global__ __launch_bounds__(256)
void mega_prep_kernel(const float* __restrict__ jf,
                      const float* __restrict__ wq, const float* __restrict__ wk,
                      const float* __restrict__ wv, const float* __restrict__ wp,
                      const float* __restrict__ wsw, const float* __restrict__ wsk,
                      unsigned short* __restrict__ wqkvT,
                      unsigned short* __restrict__ fbt, float* __restrict__ stats,
                      float* __restrict__ wsum,
                      unsigned short* __restrict__ jfb, _Float16* __restrict__ jfh,
                      _Float16* __restrict__ jfl, _Float16* __restrict__ jfd,
                      _Float16* __restrict__ GT, unsigned short* __restrict__ G1T,
                      float* __restrict__ Wvp2, int* __restrict__ nbr0) {
    __shared__ __align__(16) char sm[17408];
    int bid = blockIdx.x;
    int tidx = threadIdx.x;
    constexpr size_t CH = (size_t)Cc * HD;

    if (bid < 256) {                       // ---- g_gemm L0 -> GT fp16-split --
        int h = bid >> 5, rem = bid & 31;
        int m0 = (rem >> 2) * 32, n0 = (rem & 3) * 64;
        int ty = tidx >> 4, tx = tidx & 15;
        float acc[2][4] = {};
        g_gemm_body(wq, wk, h, m0, n0, sm, acc);
        #pragma unroll
        for (int j = 0; j < 4; ++j) {
            int n = h*256 + n0 + tx*4 + j;
            float g0 = acc[0][j], g1 = acc[1][j];
            _Float16 h0_ = (_Float16)g0, h1_ = (_Float16)g1;
            _Float16* base = &GT[(size_t)n*768 + m0 + ty*2];
            base[0]   = h0_;                          base[1]   = h1_;
            base[256] = (_Float16)(g0 * 0.0625f);     base[257] = (_Float16)(g1 * 0.0625f);
            base[512] = (_Float16)((g0 - (float)h0_) * 128.0f);
            base[513] = (_Float16)((g1 - (float)h1_) * 128.0f);
        }
    } else if (bid < 512) {                // ---- g_gemm L1 -> G1T bf16 ------
        int q = bid - 256;
        int h = q >> 5, rem = q & 31;
        int m0 = (rem >> 2) * 32, n0 = (rem & 3) * 64;
        int ty = tidx >> 4, tx = tidx & 15;
        float acc[2][4] = {};
        g_gemm_body(wq + CH, wk + CH, h, m0, n0, sm, acc);
        #pragma unroll
        for (int j = 0; j < 4; ++j) {
            int n = h*256 + n0 + tx*4 + j;
            unsigned short* base = &G1T[(size_t)n*256 + m0 + ty*2];
            base[0] = f2bf(acc[0][j]);
            base[1] = f2bf(acc[1][j]);
        }
    } else if (bid < 520) {                // ---- wvp ----
        int h = bid - 512;
        float (*wpc)[3] = (float(*)[3])sm;
        int t = tidx;
        const float* p = &wp[(size_t)(h*256 + t) * Cc];
        wpc[t][0] = p[0]; wpc[t][1] = p[1]; wpc[t][2] = p[2];
        __syncthreads();
        const float* vr = &wv[(size_t)t*HD + h*256];
        float a0=0, a1=0, a2=0;
        for (int d = 0; d < 256; ++d) {
            float v = vr[d];
            a0 += v*wpc[d][0]; a1 += v*wpc[d][1]; a2 += v*wpc[d][2];
        }
        float* o = &Wvp2[(size_t)t*24 + h*3];
        o[0]=a0; o[1]=a1; o[2]=a2;
    } else if (bid < 776) {                // ---- knn layer 0 ----
        knn_body(bid - 520, jf, Cc, nbr0, (float(*)[3])sm);
    } else if (bid == 776) {               // ---- wsum + stats zero ----
        int e = tidx;
        float4 o;
        o.x = wsw[(size_t)e*Dd + 0] + wsk[(size_t)e*Dd + 0];
        o.y = wsw[(size_t)e*Dd + 1] + wsk[(size_t)e*Dd + 1];
        o.z = wsw[(size_t)e*Dd + 2] + wsk[(size_t)e*Dd + 2];
        o.w = 0.0f;
        *(float4*)&wsum[e*4] = o;
        if (e < 2) stats[e] = 0.0f;
    } else if (bid < 2121) {               // ---- cvt_split ----
        int i = (bid - 777) * 256 + tidx;
        float4 v = ((const float4*)jf)[i];
        float x[4] = {v.x, v.y, v.z, v.w};
        ushort4 ob; half4v oh, ol, od;
        #pragma unroll
        for (int u = 0; u < 4; ++u) {
            ((unsigned short*)&ob)[u] = f2bf(x[u]);
            _Float16 h = (_Float16)x[u];
            oh[u] = h;
            ol[u] = (_Float16)((x[u] - (float)h) * 16.0f);
            od[u] = (_Float16)(x[u] * 0.0078125f);   // /128
        }
        ((ushort4*)jfb)[i] = ob;
        ((half4v*)jfh)[i] = oh;
        ((half4v*)jfl)[i] = ol;
        ((half4v*)jfd)[i] = od;
    } else {                               // ---- weight transposes ----
        int tt = bid - 2121;
        const float* src; unsigned short* dst;
        int ldin, ldout, tilesX, tile;
        if (tt < 2048) {                   // q0,k0,v0,v1 (op 0,1,2,5)
            int opIdx = tt >> 9; tile = tt & 511; tilesX = 64;
            int op = (opIdx < 3) ? opIdx : 5;
            ldin = HD; ldout = Cc;
            const float* s3[3] = {wq, wk, wv};
            src = s3[op % 3] + (size_t)(op / 3) * CH;
            dst = wqkvT + (size_t)(op % 3) * HD * Cc + (size_t)(op / 3) * QKVN * Cc;
        } else if (tt < 3072) {            // wp x2
            int op = (tt - 2048) >> 9; tile = (tt - 2048) & 511; tilesX = 8;
            ldin = Cc; ldout = KFUSE;
            src = wp + (size_t)op * HD * Cc;
            dst = fbt + (size_t)op * Cc * KFUSE;
        } else {                           // ws l0/l1, wskip x2
            int q = tt - 3072; int op = q >> 6; tile = q & 63; tilesX = 8;
            ldin = Cc; ldout = KFUSE;
            const float* s4[4] = {wsw, wsw + (size_t)Cc * Cc, wsk, wsk};
            src = s4[op];
            dst = fbt + (size_t)(op & 1) * Cc * KFUSE + HD + (size_t)(op >> 1) * Cc;
        }
        int bx = tile % tilesX, by = tile / tilesX;
        int n0 = bx * 32, k0 = by * 32;
        float (*t)[33] = (float(*)[33])sm;
        int r = tidx >> 3, c4 = (tidx & 7) * 4;
        float4 v = *(const float4*)&src[(size_t)(k0 + r) * ldin + n0 + c4];
        t[r][c4+0] = v.x; t[r][c4+1] = v.y; t[r][c4+2] = v.z; t[r][c4+3] = v.w;
        __syncthreads();
        ushort4 o;
        o.x = f2bf(t[c4+0][r]); o.y = f2bf(t[c4+1][r]);
        o.z = f2bf(t[c4+2][r]); o.w = f2bf(t[c4+3][r]);
        *(ushort4*)&dst[(size_t)(n0 + r) * ldout + k0 + c4] = o;
    }
}

// ---------------------------------------------------------------------------
// 16-bit MFMA GEMM core, XOR-swizzled LDS.
template<int BM, int BN, int BK, int NSEG, bool RELU_STATS, bool OUT_BF16, bool F16>
__device__ __forceinline__
void gemm_core(unsigned short* As, unsigned short* Bs, float* red,
               int bm, int bn,
               const unsigned short* __restrict__ A0, int lda0, int klen0,
               const unsigned short* __restrict__ A1, int lda1, int klen1,
               const unsigned short* __restrict__ A2, int lda2, int klen2,
               const unsigned short* __restrict__ Bt, int ldb,
               void* __restrict__ Cv, int ldc, float* __restrict__ stat) {
    constexpr int WM = BM/2, WN = BN/2;
    constexpr int MW = WM/16, NW = WN/16, KW = BK/32;
    constexpr int CHUNKA = BM*BK/8;
    constexpr int CHUNKB = BN*BK/8;
    constexpr int KB8 = BK/8;
    constexpr int SWZ = KB8 - 1;
    using frag = std::conditional_t<F16, half8, short8>;

    int tid = threadIdx.x;
    int wid = tid >> 6, lane = tid & 63;
    int wr = wid >> 1, wc = wid & 1;

    f32x4 acc[MW][NW];
    #pragma unroll
    for (int m = 0; m < MW; ++m)
        #pragma unroll
        for (int n = 0; n < NW; ++n)
            acc[m][n] = (f32x4){0.f, 0.f, 0.f, 0.f};

    const unsigned short* Aseg[3] = {A0, A1, A2};
    const int ldas[3] = {lda0, lda1, lda2};
    const int klens[3] = {klen0, klen1, klen2};

    int kglob = 0;
    for (int seg = 0; seg < NSEG; ++seg) {
        const unsigned short* A = Aseg[seg];
        const int lda = ldas[seg];
        const int klen = klens[seg];
        for (int k0 = 0; k0 < klen; k0 += BK) {
            #pragma unroll
            for (int it = 0; it < CHUNKA/256; ++it) {
                int c = tid + it*256;
                int row = c / KB8;
                int kp = (c % KB8) ^ (row & SWZ);
                __builtin_amdgcn_global_load_lds(
                    (const __attribute__((address_space(1))) unsigned int*)
                        (A + (size_t)(bm + row)*lda + k0 + kp*8),
                    (__attribute__((address_space(3))) unsigned int*)(As + c*8),
                    16, 0, 0);
            }
            #pragma unroll
            for (int it = 0; it < CHUNKB/256; ++it) {
                int c = tid + it*256;
                int row = c / KB8;
                int kp = (c % KB8) ^ (row & SWZ);
                __builtin_amdgcn_global_load_lds(
                    (const __attribute__((address_space(1))) unsigned int*)
                        (Bt + (size_t)(bn + row)*ldb + kglob + k0 + kp*8),
                    (__attribute__((address_space(3))) unsigned int*)(Bs + c*8),
                    16, 0, 0);
            }
            __syncthreads();
            #pragma unroll
            for (int kp = 0; kp < KW; ++kp) {
                frag af[MW], bf[NW];
                int cbase = kp*4 + (lane >> 4);
                #pragma unroll
                for (int m = 0; m < MW; ++m) {
                    int r = wr*WM + m*16 + (lane & 15);
                    af[m] = *(const frag*)&As[r*BK + ((cbase ^ (r & SWZ))*8)];
                }
                #pragma unroll
                for (int n = 0; n < NW; ++n) {
                    int r = wc*WN + n*16 + (lane & 15);
                    bf[n] = *(const frag*)&Bs[r*BK + ((cbase ^ (r & SWZ))*8)];
                }
                #pragma unroll
                for (int m = 0; m < MW; ++m)
                    #pragma unroll
                    for (int n = 0; n < NW; ++n) {
                        if constexpr (F16)
                            acc[m][n] = __builtin_amdgcn_mfma_f32_16x16x32_f16(
                                af[m], bf[n], acc[m][n], 0, 0, 0);
                        else
                            acc[m][n] = __builtin_amdgcn_mfma_f32_16x16x32_bf16(
                                af[m], bf[n], acc[m][n], 0, 0, 0);
                    }
            }
            __syncthreads();
        }
        kglob += klen;
    }

    int cr = (lane >> 4)*4, cc = lane & 15;
    float bsum = 0.0f;
    #pragma unroll
    for (int m = 0; m < MW; ++m)
        #pragma unroll
        for (int n = 0; n < NW; ++n)
            #pragma unroll
            for (int j = 0; j < 4; ++j) {
                float v = acc[m][n][j];
                if (RELU_STATS) { v = fmaxf(v, 0.0f); bsum += v; }
                size_t row = bm + wr*WM + m*16 + cr + j;
                size_t col = bn + wc*WN + n*16 + cc;
                if (OUT_BF16) ((unsigned short*)Cv)[row*ldc + col] = f2bf(v);
                else          ((float*)Cv)[row*ldc + col] = v;
            }
    if (RELU_STATS) {
        #pragma unroll
        for (int sft = 1; sft < 64; sft <<= 1) bsum += __shfl_xor(bsum, sft);
        if (lane == 0) red[wid] = bsum;
        __syncthreads();
        if (tid == 0) atomicAdd(stat, red[0] + red[1] + red[2] + red[3]);
    }
}

// ---------------------------------------------------------------------------
// COMBO (layer 0): y<16 -> V gemm (V cols of QKVb); y in [16,32) -> fp16-split
// T-gemm; y in [32,48) -> vproj. All XCD-chunked where GEMM.
__global__ __launch_bounds__(256)
void combo_kernel(const unsigned short* __restrict__ jfb,
                  const unsigned short* __restrict__ wqkvT,
                  unsigned short* __restrict__ QKVb,
                  const _Float16* __restrict__ jfh, const _Float16* __restrict__ jfl,
                  const _Float16* __restrict__ jfd, const _Float16* __restrict__ GT,
                  float* __restrict__ Tm,
                  const float* __restrict__ jf, const float* __restrict__ Wvp2,
                  float* __restrict__ vproj) {
    __shared__ __align__(16) char smem[32784];
    unsigned short* As = (unsigned short*)smem;
    unsigned short* Bs = (unsigned short*)(smem + 16384);
    float* red = (float*)(smem + 32768);
    int x = blockIdx.x, y = blockIdx.y;
    if (y < 16) {
        int lb = x + 42*y;                 // 672 blocks
        int nb = (lb & 7) * 84 + (lb >> 3);
        int sx = nb % 42, sy = nb / 42;
        gemm_core<128,128,64,1,false,true,false>(As, Bs, red, sx*128,
            2*HD + sy*128,
            jfb, Cc, Cc, jfb, Cc, 0, jfb, Cc, 0, wqkvT, Cc, QKVb, QKVN, nullptr);
    } else if (y < 32) {
        int lb = x + 42*(y - 16);
        int nb = (lb & 7) * 84 + (lb >> 3);
        int sx = nb / 16, sy = nb % 16;
        gemm_core<128,128,64,3,false,false,true>(As, Bs, red, sx*128, sy*128,
            (const unsigned short*)jfh, Cc, Cc, (const unsigned short*)jfl, Cc, Cc,
            (const unsigned short*)jfd, Cc, Cc, (const unsigned short*)GT, 768,
            Tm, HD, nullptr);
    } else {
        int q = (y - 32) * 42 + x;
        float (*hr)[256] = (float(*)[256])smem;
        float* wl = (float*)(smem + 8192);
        int t = threadIdx.x;
        int j0 = q * 8;
        #pragma unroll
        for (int i = 0; i < 6; ++i)
            *(float4*)&wl[t*4 + i*1024] = *(const float4*)&Wvp2[t*4 + i*1024];
        {
            int r = t >> 5, c = (t & 31) * 8;
            const float* src = &jf[(size_t)(j0 + r)*Cc + c];
            *(float4*)&hr[r][c]   = *(const float4*)src;
            *(float4*)&hr[r][c+4] = *(const float4*)(src + 4);
        }
        __syncthreads();
        int r = t >> 5, o = t & 31;
        if (o < 24) {
            float a = 0.0f;
            for (int e = 0; e < 256; ++e) a += hr[r][e] * wl[e*24 + o];
            vproj[(size_t)(j0 + r)*24 + o] = a;
        }
    }
}

// ---------------------------------------------------------------------------
// COMBO1 (layer 1): y<16 -> V1 gemm (V cols of QKVb); y in [16,32) ->
// T1 = h1b @ G1 (bf16, written into the Q columns of QKVb). XCD-chunked.
__global__ __launch_bounds__(256)
void combo1_kernel(const unsigned short* __restrict__ h1b,
                   const unsigned short* __restrict__ wqkvT1,
                   const unsigned short* __restrict__ G1T,
                   unsigned short* __restrict__ QKVb) {
    __shared__ __align__(16) unsigned short As[128*64];
    __shared__ __align__(16) unsigned short Bs[128*64];
    __shared__ float red[4];
    int x = blockIdx.x, y = blockIdx.y;
    if (y < 16) {
        int lb = x + 42*y;
        int nb = (lb & 7) * 84 + (lb >> 3);
        int sx = nb % 42, sy = nb / 42;
        gemm_core<128,128,64,1,false,true,false>(As, Bs, red, sx*128,
            2*HD + sy*128,
            h1b, Cc, Cc, h1b, Cc, 0, h1b, Cc, 0, wqkvT1, Cc, QKVb, QKVN, nullptr);
    } else {
        int lb = x + 42*(y - 16);
        int nb = (lb & 7) * 84 + (lb >> 3);
        int sx = nb % 42, sy = nb / 42;
        gemm_core<128,128,64,1,false,true,false>(As, Bs, red, sx*128, sy*128,
            h1b, Cc, Cc, h1b, Cc, 0, h1b, Cc, 0, G1T, Cc, QKVb, QKVN, nullptr);
    }
}

// ---------------------------------------------------------------------------
// fused epilogue gemm (+ optional layer-1 kNN in extra y-blocks)
template<bool OUT_BF16, bool DO_KNN>
__global__ __launch_bounds__(256)
void fused_kernel(const unsigned short* __restrict__ att,
                  const unsigned short* __restrict__ hseg,
                  const unsigned short* __restrict__ h0seg,
                  const unsigned short* __restrict__ fbtL,
                  void* __restrict__ Cv, float* __restrict__ stat,
                  const float* __restrict__ crd, int* __restrict__ nbr1) {
    __shared__ __align__(16) char smem[16400];
    if (DO_KNN && blockIdx.y >= 4) {
        int b = (blockIdx.y - 4) * 84 + blockIdx.x;
        if (b < Bb) knn_body(b, crd, 4, nbr1, (float(*)[3])smem);
        return;
    }
    unsigned short* As = (unsigned short*)smem;
    unsigned short* Bs = (unsigned short*)(smem + 8192);
    float* red = (float*)(smem + 16384);
    gemm_core<64,64,64,3,true,OUT_BF16,false>(
        As, Bs, red, blockIdx.x*64, blockIdx.y*64,
        att, HD, HD, hseg, Cc, Cc, h0seg, Cc, Cc,
        fbtL, KFUSE, Cv, Cc, stat);
}

// ---------------------------------------------------------------------------
// precise layer-0 coords + FUSED layer-0 attention; XCD-chunked grid.
__global__ __launch_bounds__(64)
void precise_kernel(const float* __restrict__ T, const float* __restrict__ h0,
                    const int* __restrict__ nbr, const float* __restrict__ vproj,
                    const float* __restrict__ wsum,
                    const unsigned short* __restrict__ QKV,
                    float* __restrict__ crd, unsigned short* __restrict__ att) {
    int lb = blockIdx.x;
    int i = (lb & 7) * (Mrows/8) + (lb >> 3);   // bijective: 5376 % 8 == 0
    int b = i / Jj;
    int l = threadIdx.x;
    __shared__ float Ts[8][260];
    __shared__ float nb[8][260];
    __shared__ float hi[256];
    __shared__ float wsL[64];
    __shared__ int nbs[KNN];
    #pragma unroll
    for (int u = 0; u < 8; ++u) {
        int idx = u*64 + l;
        float4 v = *(const float4*)&T[(size_t)i*HD + idx*4];
        int hh = idx >> 6, dd = (idx & 63) * 4;
        *(float4*)&Ts[hh][dd] = v;
    }
    *(float4*)&hi[l*4] = *(const float4*)&h0[(size_t)i*Cc + l*4];
    if (l < KNN) nbs[l] = nbr[i*KNN + l];
    int kq = l >> 3, s = l & 7;
    int njs = nbr[i*KNN + kq];
    const float* nrow = &h0[(size_t)(b*Jj + njs)*Cc];
    #pragma unroll
    for (int u = 0; u < 8; ++u)
        *(float4*)&nb[kq][(s*8+u)*4] = *(const float4*)&nrow[(s*8+u)*4];
    __syncthreads();

    int k = l >> 3, h = l & 7;
    float sacc = 0;
    #pragma unroll 8
    for (int d = 0; d < 256; d += 4) {
        float4 tv = *(const float4*)&Ts[h][d];
        float4 nv = *(const float4*)&nb[k][d];
        sacc += tv.x*nv.x + tv.y*nv.y + tv.z*nv.z + tv.w*nv.w;
    }
    float sc = sacc * 0.0625f;
    sc = (sc >= 0.0f) ? sc : 0.2f * sc;
    float m = sc;
    m = fmaxf(m, __shfl_xor(m, 8));
    m = fmaxf(m, __shfl_xor(m, 16));
    m = fmaxf(m, __shfl_xor(m, 32));
    float e = expf(sc - m);
    float den = e;
    den += __shfl_xor(den, 8); den += __shfl_xor(den, 16); den += __shfl_xor(den, 32);
    float w = e / den;
    wsL[l] = w;                            // wsL[k*8 + h]

    int njk = nbs[k];
    const float* vp = &vproj[(size_t)(b*Jj + njk)*24 + h*3];
    float t0 = w * vp[0], t1 = w * vp[1], t2 = w * vp[2];
    #pragma unroll
    for (int u = 0; u < 4; ++u) {
        int e4 = l*4 + u;
        float hv = hi[e4];
        float4 wv = *(const float4*)&wsum[e4*4];
        t0 += hv * wv.x; t1 += hv * wv.y; t2 += hv * wv.z;
    }
    #pragma unroll
    for (int sft = 1; sft < 64; sft <<= 1) {
        t0 += __shfl_xor(t0, sft); t1 += __shfl_xor(t1, sft); t2 += __shfl_xor(t2, sft);
    }
    if (l == 0) {
        crd[i*4+0] = fmaxf(t0, 0.0f);
        crd[i*4+1] = fmaxf(t1, 0.0f);
        crd[i*4+2] = fmaxf(t2, 0.0f);
        crd[i*4+3] = 0.0f;
    }
    __syncthreads();

    // ---- fused layer-0 attention: lane l -> head h2 = l>>3, d chunk sub*32
    int h2 = l >> 3, sub = l & 7;
    float o[32] = {};
    #pragma unroll
    for (int kk = 0; kk < KNN; ++kk) {
        float wk_ = wsL[kk*8 + h2];
        const unsigned short* vrow =
            &QKV[(size_t)(b*Jj + nbs[kk])*QKVN + 2*HD + h2*256 + sub*32];
        #pragma unroll
        for (int j = 0; j < 4; ++j) {
            u16x8 v = *(const u16x8*)(vrow + j*8);
            #pragma unroll
            for (int u = 0; u < 8; ++u) o[j*8+u] += wk_ * bf2f(v[u]);
        }
    }
    unsigned short* arow = &att[(size_t)i*HD + h2*256 + sub*32];
    #pragma unroll
    for (int j = 0; j < 4; ++j) {
        u16x8 ou;
        #pragma unroll
        for (int u = 0; u < 8; ++u) ou[u] = f2bf(o[j*8+u]);
        *(u16x8*)(arow + j*8) = ou;
    }
}

// ---------------------------------------------------------------------------
// layer-1 attention via T1: score_h = T1[row][h*256+:] . h1b[nbr][:] / 16.
// One wave per (row, head-pair), XCD-chunked. V gather unchanged.
__global__ __launch_bounds__(64)
void attn1_kernel(const unsigned short* __restrict__ QKV,
                  const unsigned short* __restrict__ h1b,
                  const int* __restrict__ nbr, unsigned short* __restrict__ att) {
    int lb = blockIdx.x;
    int gid = (lb & 7) * (Mrows*4/8) + (lb >> 3);
    int hp = gid & 3, row = gid >> 2, b = row / Jj;
    int lane = threadIdx.x;
    int h = hp*2 + (lane >> 5);
    int d0 = (lane & 31) * 8;

    // T1 slice for this row/head (stored in Q columns of QKV)
    u16x8 tu = *(const u16x8*)&QKV[(size_t)row*QKVN + h*Dd + d0];
    float tf[8];
    #pragma unroll
    for (int i = 0; i < 8; ++i) tf[i] = bf2f(tu[i]);
    const int* np_ = nbr + row * KNN;

    float sc[KNN]; int nb[KNN];
    #pragma unroll
    for (int k = 0; k < KNN; ++k) {
        int n = np_[k]; nb[k] = n;
        u16x8 hu = *(const u16x8*)&h1b[(size_t)(b*Jj + n)*Cc + d0];
        float p = 0;
        #pragma unroll
        for (int i = 0; i < 8; ++i) p += tf[i] * bf2f(hu[i]);
        #pragma unroll
        for (int s = 1; s < 32; s <<= 1) p += __shfl_xor(p, s);
        sc[k] = p;
    }
    float mx = -INFINITY;
    #pragma unroll
    for (int k = 0; k < KNN; ++k) {
        float s = sc[k] * 0.0625f;
        s = (s >= 0.0f) ? s : 0.2f * s;
        sc[k] = s; mx = fmaxf(mx, s);
    }
    float den = 0.0f;
    #pragma unroll
    for (int k = 0; k < KNN; ++k) { sc[k] = expf(sc[k] - mx); den += sc[k]; }
    float inv = 1.0f / den;
    float o[8] = {};
    #pragma unroll
    for (int k = 0; k < KNN; ++k) {
        u16x8 vu = *(const u16x8*)&QKV[(size_t)(b*Jj + nb[k])*QKVN + 2*HD + h*Dd + d0];
        float w = sc[k] * inv;
        #pragma unroll
        for (int i = 0; i < 8; ++i) o[i] += w * bf2f(vu[i]);
    }
    u16x8 ou;
    #pragma unroll
    for (int i = 0; i < 8; ++i) ou[i] = f2bf(o[i]);
    *(u16x8*)&att[(size_t)row*HD + h*Dd + d0] = ou;
}

// ---------------------------------------------------------------------------
__global__ __launch_bounds__(64)
void final_kernel(const float* __restrict__ h, const float* __restrict__ fcw,
                  const float* __restrict__ fcb, const float* __restrict__ stats,
                  float* __restrict__ out) {
    int row = blockIdx.x, lane = threadIdx.x;
    const float4 hv = *(const float4*)(h + (size_t)row*Cc + lane*4);
    float a0=0, a1=0, a2=0;
    const float hx[4] = {hv.x, hv.y, hv.z, hv.w};
    #pragma unroll
    for (int i = 0; i < 4; ++i) {
        int c = lane*4 + i;
        a0 += hx[i]*fcw[c*3+0]; a1 += hx[i]*fcw[c*3+1]; a2 += hx[i]*fcw[c*3+2];
    }
    #pragma unroll
    for (int s = 32; s > 0; s >>= 1) {
        a0 += __shfl_xor(a0, s); a1 += __shfl_xor(a1, s); a2 += __shfl_xor(a2, s);
    }
    if (lane == 0) {
        out[row*3+0] = a0 + fcb[0];
        out[row*3+1] = a1 + fcb[1];
        out[row*3+2] = a2 + fcb[2];
        if (row == 0)
            out[(size_t)Mrows*3] =
                (stats[0] + stats[1]) * (0.5f / ((float)Mrows * (float)Cc));
    }
}

// ---------------------------------------------------------------------------
extern "C" void kernel_launch(void* const* d_in, const int* in_sizes, int n_in,
                              void* d_out, int out_size, void* d_ws, size_t ws_size,
                              hipStream_t stream) {
    (void)in_sizes; (void)n_in; (void)out_size; (void)ws_size;
    const float* jf     = (const float*)d_in[0];
    const float* wq     = (const float*)d_in[1];
    const float* wk     = (const float*)d_in[2];
    const float* wv     = (const float*)d_in[3];
    const float* wp     = (const float*)d_in[4];
    const float* wsw    = (const float*)d_in[5];
    const float* wskip0 = (const float*)d_in[6];
    const float* fcw    = (const float*)d_in[7];
    const float* fcb    = (const float*)d_in[8];
    float* out = (float*)d_out;

    char* wsb = (char*)d_ws;
    unsigned short* QKVb  = (unsigned short*)(wsb + OFF_QKV);
    float*          Tm    = (float*)(wsb + OFF_T);
    unsigned short* attb  = (unsigned short*)(wsb + OFF_ATT);
    _Float16*       GT    = (_Float16*)(wsb + OFF_GT);
    unsigned short* G1T   = (unsigned short*)(wsb + OFF_G1T);
    unsigned short* jfb   = (unsigned short*)(wsb + OFF_JFB);
    _Float16*       jfh   = (_Float16*)(wsb + OFF_JFH);
    _Float16*       jfl   = (_Float16*)(wsb + OFF_JFL);
    _Float16*       jfd   = (_Float16*)(wsb + OFF_JFD);
    unsigned short* h1b   = (unsigned short*)(wsb + OFF_H1B);
    float*          h2f   = (float*)(wsb + OFF_H2F);
    unsigned short* wqkvT = (unsigned short*)(wsb + OFF_WQKVT);
    unsigned short* fbt   = (unsigned short*)(wsb + OFF_FBT);
    float*          Wvp   = (float*)(wsb + OFF_WVP);
    float*          vproj = (float*)(wsb + OFF_VPROJ);
    float*          wsum  = (float*)(wsb + OFF_WSUM);
    float*          crd   = (float*)(wsb + OFF_CRD);
    int*            nbr0  = (int*)(wsb + OFF_NBR0);
    int*            nbr1  = (int*)(wsb + OFF_NBR1);
    float*          stats = (float*)(wsb + OFF_STAT);

    // 1. all input-only prep in one launch (long poles dispatched first)
    mega_prep_kernel<<<5449, 256, 0, stream>>>(jf, wq, wk, wv, wp, wsw, wskip0,
                                               wqkvT, fbt, stats, wsum,
                                               jfb, jfh, jfl, jfd, GT, G1T,
                                               Wvp, nbr0);
    // 2. layer-0 V gemm + fp16-split T-gemm + vproj in one launch
    combo_kernel<<<dim3(42, 48), 256, 0, stream>>>(jfb, wqkvT, QKVb,
                                                   jfh, jfl, jfd, GT, Tm,
                                                   jf, Wvp, vproj);
    // 3. precise layer-0 coords + fused layer-0 attention (XCD-chunked)
    precise_kernel<<<Mrows, 64, 0, stream>>>(Tm, jf, nbr0, vproj, wsum,
                                             QKVb, crd, attb);
    // 4. layer-0 fused output gemm + layer-1 kNN
    fused_kernel<true, true><<<dim3(84, 8), 256, 0, stream>>>(
        attb, jfb, jfb, fbt, h1b, &stats[0], crd, nbr1);
    // 5. layer-1 V gemm + T1 gemm (XCD-chunked)
    combo1_kernel<<<dim3(42, 32), 256, 0, stream>>>(
        h1b, wqkvT + (size_t)QKVN*Cc, G1T, QKVb);
    // 6. layer-1 attention via T1 (XCD-chunked)
    attn1_kernel<<<Mrows*4, 64, 0, stream>>>(QKVb, h1b, nbr1, attb);
    // 7. layer-1 fused output gemm
    fused_kernel<false, false><<<dim3(84, 4), 256, 0, stream>>>(
        attb, h1b, jfb, fbt + (size_t)Cc*KFUSE, h2f, &stats[1], nullptr, nullptr);
    // 8. final
    final_kernel<<<Mrows, 64, 0, stream>>>(h2f, fcw, fcb, stats, out);
}

// Round 19
// 189.213 us; speedup vs baseline: 1.4023x; 1.0122x over previous
//
#include <hip/hip_runtime.h>
#include <hip/hip_bf16.h>
#include <math.h>
#include <type_traits>

namespace {
constexpr int Bb = 256, Jj = 21, Cc = 256, Hh = 8, Dd = 256;
constexpr int Mrows = Bb * Jj;      // 5376
constexpr int HD    = Hh * Dd;      // 2048
constexpr int QKVN  = 3 * HD;       // 6144
constexpr int KNN   = 8;
constexpr int KF0   = HD + Cc;      // 2304 (layer-0 fused K: wp | ws0+wskip0)
constexpr int KF1   = HD + 2*Cc;    // 2560 (layer-1 fused K: wp1 | ws1 | wskip0)

// ---- workspace byte offsets ----
constexpr size_t OFF_QKV   = 0;                                   // bf16 5376x6144
constexpr size_t OFF_T     = OFF_QKV   + (size_t)Mrows*QKVN*2;    // f32  5376x2048
constexpr size_t OFF_ATT   = OFF_T     + (size_t)Mrows*HD*4;      // bf16 5376x2048
constexpr size_t OFF_GT    = OFF_ATT   + (size_t)Mrows*HD*2;      // f16  2048x768
constexpr size_t OFF_G1T   = OFF_GT    + (size_t)HD*768*2;        // bf16 2048x256
constexpr size_t OFF_JFB   = OFF_G1T   + (size_t)HD*Cc*2;         // bf16 5376x256
constexpr size_t OFF_JFH   = OFF_JFB   + (size_t)Mrows*Cc*2;      // f16  5376x256
constexpr size_t OFF_JFL   = OFF_JFH   + (size_t)Mrows*Cc*2;      // f16  5376x256
constexpr size_t OFF_JFD   = OFF_JFL   + (size_t)Mrows*Cc*2;      // f16  5376x256
constexpr size_t OFF_H1B   = OFF_JFD   + (size_t)Mrows*Cc*2;      // bf16 5376x256
constexpr size_t OFF_H2F   = OFF_H1B   + (size_t)Mrows*Cc*2;      // f32  5376x256
constexpr size_t OFF_WQKVT = OFF_H2F   + (size_t)Mrows*Cc*4;      // bf16 2x6144x256
constexpr size_t OFF_FBT0  = OFF_WQKVT + (size_t)2*QKVN*Cc*2;     // bf16 256x2304
constexpr size_t OFF_FBT1  = OFF_FBT0  + (size_t)Cc*KF0*2;        // bf16 256x2560
constexpr size_t OFF_WVP   = OFF_FBT1  + (size_t)Cc*KF1*2;        // f32  256x24
constexpr size_t OFF_VPROJ = OFF_WVP   + (size_t)Cc*24*4;         // f32  5376x24
constexpr size_t OFF_WSUM  = OFF_VPROJ + (size_t)Mrows*24*4;      // f32  256x4
constexpr size_t OFF_CRD   = OFF_WSUM  + (size_t)Cc*4*4;          // f32  5376x4
constexpr size_t OFF_NBR0  = OFF_CRD   + (size_t)Mrows*4*4;       // int  5376x8
constexpr size_t OFF_NBR1  = OFF_NBR0  + (size_t)Mrows*KNN*4;
constexpr size_t OFF_STAT  = OFF_NBR1  + (size_t)Mrows*KNN*4;     // 2 f32
} // namespace

typedef short short8 __attribute__((ext_vector_type(8)));
typedef _Float16 half8 __attribute__((ext_vector_type(8)));
typedef _Float16 half4v __attribute__((ext_vector_type(4)));
typedef unsigned short u16x8 __attribute__((ext_vector_type(8)));
typedef float f32x4 __attribute__((ext_vector_type(4)));

__device__ __forceinline__ unsigned short f2bf(float x) {
    unsigned int u = __float_as_uint(x);
    u = u + 0x7fffu + ((u >> 16) & 1u);            // round-to-nearest-even
    return (unsigned short)(u >> 16);
}
__device__ __forceinline__ float bf2f(unsigned short b) {
    return __uint_as_float(((unsigned int)b) << 16);
}

// ---------------------------------------------------------------------------
// kNN body: exact stable-argsort ranks 1..8 by (d2, index).
__device__ __forceinline__ void knn_body(int b, const float* __restrict__ src,
                                         int ld, int* __restrict__ nbr,
                                         float (*cs)[3]) {
    int t = threadIdx.x;
    if (t < Jj) {
        const float* p = src + (size_t)(b * Jj + t) * ld;
        cs[t][0] = p[0]; cs[t][1] = p[1]; cs[t][2] = p[2];
    }
    __syncthreads();
    if (t < Jj) {
        float x = cs[t][0], y = cs[t][1], z = cs[t][2];
        float d2[Jj];
        #pragma unroll
        for (int jj = 0; jj < Jj; ++jj) {
            float dx = x - cs[jj][0], dy = y - cs[jj][1], dz = z - cs[jj][2];
            d2[jj] = dx*dx + dy*dy + dz*dz;
        }
        unsigned int used = 0u;
        int out_base = (b * Jj + t) * KNN;
        #pragma unroll
        for (int r = 0; r <= KNN; ++r) {
            int best = -1; float bd = INFINITY;
            #pragma unroll
            for (int jj = 0; jj < Jj; ++jj)
                if (!((used >> jj) & 1u) && d2[jj] < bd) { bd = d2[jj]; best = jj; }
            used |= (1u << best);
            if (r > 0) nbr[out_base + r - 1] = best;
        }
    }
}

// ---------------------------------------------------------------------------
// g-gemm body: 32x64 tile of G_h = wq_h @ wk_h^T (fp32 accum).
__device__ __forceinline__ void g_gemm_body(const float* __restrict__ wq,
                                            const float* __restrict__ wk,
                                            int h, int m0, int n0, char* sm,
                                            float acc[2][4]) {
    float (*As)[36] = (float(*)[36])sm;              // 4608 B
    float (*Ws)[68] = (float(*)[68])(sm + 4608);     // 8704 B
    int tidx = threadIdx.x;
    int ty = tidx >> 4, tx = tidx & 15;
    for (int kb = 0; kb < 256; kb += 32) {
        {
            int row = tidx >> 3, col = (tidx & 7) * 4;
            float4 v = *(const float4*)&wq[(size_t)(m0 + row)*HD + h*256 + kb + col];
            As[col+0][row] = v.x; As[col+1][row] = v.y;
            As[col+2][row] = v.z; As[col+3][row] = v.w;
            int row2 = tidx >> 2, col2 = (tidx & 3) * 8;
            float4 u0 = *(const float4*)&wk[(size_t)(n0 + row2)*HD + h*256 + kb + col2];
            float4 u1 = *(const float4*)&wk[(size_t)(n0 + row2)*HD + h*256 + kb + col2 + 4];
            Ws[col2+0][row2] = u0.x; Ws[col2+1][row2] = u0.y;
            Ws[col2+2][row2] = u0.z; Ws[col2+3][row2] = u0.w;
            Ws[col2+4][row2] = u1.x; Ws[col2+5][row2] = u1.y;
            Ws[col2+6][row2] = u1.z; Ws[col2+7][row2] = u1.w;
        }
        __syncthreads();
        #pragma unroll
        for (int kk = 0; kk < 32; ++kk) {
            float a0 = As[kk][ty*2], a1 = As[kk][ty*2 + 1];
            float4 bv = *(const float4*)&Ws[kk][tx*4];
            float b4[4] = {bv.x, bv.y, bv.z, bv.w};
            #pragma unroll
            for (int j = 0; j < 4; ++j) {
                acc[0][j] += a0 * b4[j];
                acc[1][j] += a1 * b4[j];
            }
        }
        __syncthreads();
    }
}

// ---------------------------------------------------------------------------
// MEGA-PREP: one launch for all input-only work. Long poles dispatched FIRST:
// [0,256) g_gemm L0; [256,512) g_gemm L1; [512,520) wvp; [520,776) knn0;
// 776 wsum/stats; [777,2121) cvt_split; [2121,5385) weight transposes.
__global__ __launch_bounds__(256)
void mega_prep_kernel(const float* __restrict__ jf,
                      const float* __restrict__ wq, const float* __restrict__ wk,
                      const float* __restrict__ wv, const float* __restrict__ wp,
                      const float* __restrict__ wsw, const float* __restrict__ wsk,
                      unsigned short* __restrict__ wqkvT,
                      unsigned short* __restrict__ fbt0,
                      unsigned short* __restrict__ fbt1,
                      float* __restrict__ stats, float* __restrict__ wsum,
                      unsigned short* __restrict__ jfb, _Float16* __restrict__ jfh,
                      _Float16* __restrict__ jfl, _Float16* __restrict__ jfd,
                      _Float16* __restrict__ GT, unsigned short* __restrict__ G1T,
                      float* __restrict__ Wvp2, int* __restrict__ nbr0) {
    __shared__ __align__(16) char sm[17408];
    int bid = blockIdx.x;
    int tidx = threadIdx.x;
    constexpr size_t CH = (size_t)Cc * HD;

    if (bid < 256) {                       // ---- g_gemm L0 -> GT fp16-split --
        int h = bid >> 5, rem = bid & 31;
        int m0 = (rem >> 2) * 32, n0 = (rem & 3) * 64;
        int ty = tidx >> 4, tx = tidx & 15;
        float acc[2][4] = {};
        g_gemm_body(wq, wk, h, m0, n0, sm, acc);
        #pragma unroll
        for (int j = 0; j < 4; ++j) {
            int n = h*256 + n0 + tx*4 + j;
            float g0 = acc[0][j], g1 = acc[1][j];
            _Float16 h0_ = (_Float16)g0, h1_ = (_Float16)g1;
            _Float16* base = &GT[(size_t)n*768 + m0 + ty*2];
            base[0]   = h0_;                          base[1]   = h1_;
            base[256] = (_Float16)(g0 * 0.0625f);     base[257] = (_Float16)(g1 * 0.0625f);
            base[512] = (_Float16)((g0 - (float)h0_) * 128.0f);
            base[513] = (_Float16)((g1 - (float)h1_) * 128.0f);
        }
    } else if (bid < 512) {                // ---- g_gemm L1 -> G1T bf16 ------
        int q = bid - 256;
        int h = q >> 5, rem = q & 31;
        int m0 = (rem >> 2) * 32, n0 = (rem & 3) * 64;
        int ty = tidx >> 4, tx = tidx & 15;
        float acc[2][4] = {};
        g_gemm_body(wq + CH, wk + CH, h, m0, n0, sm, acc);
        #pragma unroll
        for (int j = 0; j < 4; ++j) {
            int n = h*256 + n0 + tx*4 + j;
            unsigned short* base = &G1T[(size_t)n*256 + m0 + ty*2];
            base[0] = f2bf(acc[0][j]);
            base[1] = f2bf(acc[1][j]);
        }
    } else if (bid < 520) {                // ---- wvp ----
        int h = bid - 512;
        float (*wpc)[3] = (float(*)[3])sm;
        int t = tidx;
        const float* p = &wp[(size_t)(h*256 + t) * Cc];
        wpc[t][0] = p[0]; wpc[t][1] = p[1]; wpc[t][2] = p[2];
        __syncthreads();
        const float* vr = &wv[(size_t)t*HD + h*256];
        float a0=0, a1=0, a2=0;
        for (int d = 0; d < 256; ++d) {
            float v = vr[d];
            a0 += v*wpc[d][0]; a1 += v*wpc[d][1]; a2 += v*wpc[d][2];
        }
        float* o = &Wvp2[(size_t)t*24 + h*3];
        o[0]=a0; o[1]=a1; o[2]=a2;
    } else if (bid < 776) {                // ---- knn layer 0 ----
        knn_body(bid - 520, jf, Cc, nbr0, (float(*)[3])sm);
    } else if (bid == 776) {               // ---- wsum + stats zero ----
        int e = tidx;
        float4 o;
        o.x = wsw[(size_t)e*Dd + 0] + wsk[(size_t)e*Dd + 0];
        o.y = wsw[(size_t)e*Dd + 1] + wsk[(size_t)e*Dd + 1];
        o.z = wsw[(size_t)e*Dd + 2] + wsk[(size_t)e*Dd + 2];
        o.w = 0.0f;
        *(float4*)&wsum[e*4] = o;
        if (e < 2) stats[e] = 0.0f;
    } else if (bid < 2121) {               // ---- cvt_split ----
        int i = (bid - 777) * 256 + tidx;
        float4 v = ((const float4*)jf)[i];
        float x[4] = {v.x, v.y, v.z, v.w};
        ushort4 ob; half4v oh, ol, od;
        #pragma unroll
        for (int u = 0; u < 4; ++u) {
            ((unsigned short*)&ob)[u] = f2bf(x[u]);
            _Float16 h = (_Float16)x[u];
            oh[u] = h;
            ol[u] = (_Float16)((x[u] - (float)h) * 16.0f);
            od[u] = (_Float16)(x[u] * 0.0078125f);   // /128
        }
        ((ushort4*)jfb)[i] = ob;
        ((half4v*)jfh)[i] = oh;
        ((half4v*)jfl)[i] = ol;
        ((half4v*)jfd)[i] = od;
    } else {                               // ---- weight transposes ----
        int tt = bid - 2121;               // 0..3263
        const float* src = nullptr; const float* src2 = nullptr;
        unsigned short* dst;
        int ldin, ldout, tilesX, tile;
        if (tt < 2048) {                   // q0,k0,v0,v1 (op 0,1,2,5)
            int opIdx = tt >> 9; tile = tt & 511; tilesX = 64;
            int op = (opIdx < 3) ? opIdx : 5;
            ldin = HD; ldout = Cc;
            const float* s3[3] = {wq, wk, wv};
            src = s3[op % 3] + (size_t)(op / 3) * CH;
            dst = wqkvT + (size_t)(op % 3) * HD * Cc + (size_t)(op / 3) * QKVN * Cc;
        } else if (tt < 2560) {            // wp0 -> FBT0
            tile = tt - 2048; tilesX = 8; ldin = Cc; ldout = KF0;
            src = wp; dst = fbt0;
        } else if (tt < 3072) {            // wp1 -> FBT1
            tile = tt - 2560; tilesX = 8; ldin = Cc; ldout = KF1;
            src = wp + CH; dst = fbt1;
        } else if (tt < 3136) {            // wss = ws0+wskip0 -> FBT0+2048
            tile = tt - 3072; tilesX = 8; ldin = Cc; ldout = KF0;
            src = wsw; src2 = wsk; dst = fbt0 + HD;
        } else if (tt < 3200) {            // ws1 -> FBT1+2048
            tile = tt - 3136; tilesX = 8; ldin = Cc; ldout = KF1;
            src = wsw + (size_t)Cc * Cc; dst = fbt1 + HD;
        } else {                           // wskip0 -> FBT1+2304
            tile = tt - 3200; tilesX = 8; ldin = Cc; ldout = KF1;
            src = wsk; dst = fbt1 + HD + Cc;
        }
        int bx = tile % tilesX, by = tile / tilesX;
        int n0 = bx * 32, k0 = by * 32;
        float (*t)[33] = (float(*)[33])sm;
        int r = tidx >> 3, c4 = (tidx & 7) * 4;
        float4 v = *(const float4*)&src[(size_t)(k0 + r) * ldin + n0 + c4];
        if (src2) {
            float4 w = *(const float4*)&src2[(size_t)(k0 + r) * ldin + n0 + c4];
            v.x += w.x; v.y += w.y; v.z += w.z; v.w += w.w;
        }
        t[r][c4+0] = v.x; t[r][c4+1] = v.y; t[r][c4+2] = v.z; t[r][c4+3] = v.w;
        __syncthreads();
        ushort4 o;
        o.x = f2bf(t[c4+0][r]); o.y = f2bf(t[c4+1][r]);
        o.z = f2bf(t[c4+2][r]); o.w = f2bf(t[c4+3][r]);
        *(ushort4*)&dst[(size_t)(n0 + r) * ldout + k0 + c4] = o;
    }
}

// ---------------------------------------------------------------------------
// 16-bit MFMA GEMM core, XOR-swizzled LDS.
template<int BM, int BN, int BK, int NSEG, bool RELU_STATS, bool OUT_BF16, bool F16>
__device__ __forceinline__
void gemm_core(unsigned short* As, unsigned short* Bs, float* red,
               int bm, int bn,
               const unsigned short* __restrict__ A0, int lda0, int klen0,
               const unsigned short* __restrict__ A1, int lda1, int klen1,
               const unsigned short* __restrict__ A2, int lda2, int klen2,
               const unsigned short* __restrict__ Bt, int ldb,
               void* __restrict__ Cv, int ldc, float* __restrict__ stat) {
    constexpr int WM = BM/2, WN = BN/2;
    constexpr int MW = WM/16, NW = WN/16, KW = BK/32;
    constexpr int CHUNKA = BM*BK/8;
    constexpr int CHUNKB = BN*BK/8;
    constexpr int KB8 = BK/8;
    constexpr int SWZ = KB8 - 1;
    using frag = std::conditional_t<F16, half8, short8>;

    int tid = threadIdx.x;
    int wid = tid >> 6, lane = tid & 63;
    int wr = wid >> 1, wc = wid & 1;

    f32x4 acc[MW][NW];
    #pragma unroll
    for (int m = 0; m < MW; ++m)
        #pragma unroll
        for (int n = 0; n < NW; ++n)
            acc[m][n] = (f32x4){0.f, 0.f, 0.f, 0.f};

    const unsigned short* Aseg[3] = {A0, A1, A2};
    const int ldas[3] = {lda0, lda1, lda2};
    const int klens[3] = {klen0, klen1, klen2};

    int kglob = 0;
    for (int seg = 0; seg < NSEG; ++seg) {
        const unsigned short* A = Aseg[seg];
        const int lda = ldas[seg];
        const int klen = klens[seg];
        for (int k0 = 0; k0 < klen; k0 += BK) {
            #pragma unroll
            for (int it = 0; it < CHUNKA/256; ++it) {
                int c = tid + it*256;
                int row = c / KB8;
                int kp = (c % KB8) ^ (row & SWZ);
                __builtin_amdgcn_global_load_lds(
                    (const __attribute__((address_space(1))) unsigned int*)
                        (A + (size_t)(bm + row)*lda + k0 + kp*8),
                    (__attribute__((address_space(3))) unsigned int*)(As + c*8),
                    16, 0, 0);
            }
            #pragma unroll
            for (int it = 0; it < CHUNKB/256; ++it) {
                int c = tid + it*256;
                int row = c / KB8;
                int kp = (c % KB8) ^ (row & SWZ);
                __builtin_amdgcn_global_load_lds(
                    (const __attribute__((address_space(1))) unsigned int*)
                        (Bt + (size_t)(bn + row)*ldb + kglob + k0 + kp*8),
                    (__attribute__((address_space(3))) unsigned int*)(Bs + c*8),
                    16, 0, 0);
            }
            __syncthreads();
            #pragma unroll
            for (int kp = 0; kp < KW; ++kp) {
                frag af[MW], bf[NW];
                int cbase = kp*4 + (lane >> 4);
                #pragma unroll
                for (int m = 0; m < MW; ++m) {
                    int r = wr*WM + m*16 + (lane & 15);
                    af[m] = *(const frag*)&As[r*BK + ((cbase ^ (r & SWZ))*8)];
                }
                #pragma unroll
                for (int n = 0; n < NW; ++n) {
                    int r = wc*WN + n*16 + (lane & 15);
                    bf[n] = *(const frag*)&Bs[r*BK + ((cbase ^ (r & SWZ))*8)];
                }
                #pragma unroll
                for (int m = 0; m < MW; ++m)
                    #pragma unroll
                    for (int n = 0; n < NW; ++n) {
                        if constexpr (F16)
                            acc[m][n] = __builtin_amdgcn_mfma_f32_16x16x32_f16(
                                af[m], bf[n], acc[m][n], 0, 0, 0);
                        else
                            acc[m][n] = __builtin_amdgcn_mfma_f32_16x16x32_bf16(
                                af[m], bf[n], acc[m][n], 0, 0, 0);
                    }
            }
            __syncthreads();
        }
        kglob += klen;
    }

    int cr = (lane >> 4)*4, cc = lane & 15;
    float bsum = 0.0f;
    #pragma unroll
    for (int m = 0; m < MW; ++m)
        #pragma unroll
        for (int n = 0; n < NW; ++n)
            #pragma unroll
            for (int j = 0; j < 4; ++j) {
                float v = acc[m][n][j];
                if (RELU_STATS) { v = fmaxf(v, 0.0f); bsum += v; }
                size_t row = bm + wr*WM + m*16 + cr + j;
                size_t col = bn + wc*WN + n*16 + cc;
                if (OUT_BF16) ((unsigned short*)Cv)[row*ldc + col] = f2bf(v);
                else          ((float*)Cv)[row*ldc + col] = v;
            }
    if (RELU_STATS) {
        #pragma unroll
        for (int sft = 1; sft < 64; sft <<= 1) bsum += __shfl_xor(bsum, sft);
        if (lane == 0) red[wid] = bsum;
        __syncthreads();
        if (tid == 0) atomicAdd(stat, red[0] + red[1] + red[2] + red[3]);
    }
}

// ---------------------------------------------------------------------------
// COMBO (layer 0): y<16 -> V gemm (V cols of QKVb); y in [16,32) -> fp16-split
// T-gemm; y in [32,48) -> vproj. XCD-chunked GEMMs.
__global__ __launch_bounds__(256)
void combo_kernel(const unsigned short* __restrict__ jfb,
                  const unsigned short* __restrict__ wqkvT,
                  unsigned short* __restrict__ QKVb,
                  const _Float16* __restrict__ jfh, const _Float16* __restrict__ jfl,
                  const _Float16* __restrict__ jfd, const _Float16* __restrict__ GT,
                  float* __restrict__ Tm,
                  const float* __restrict__ jf, const float* __restrict__ Wvp2,
                  float* __restrict__ vproj) {
    __shared__ __align__(16) char smem[32784];
    unsigned short* As = (unsigned short*)smem;
    unsigned short* Bs = (unsigned short*)(smem + 16384);
    float* red = (float*)(smem + 32768);
    int x = blockIdx.x, y = blockIdx.y;
    if (y < 16) {
        int lb = x + 42*y;                 // 672 blocks
        int nb = (lb & 7) * 84 + (lb >> 3);
        int sx = nb % 42, sy = nb / 42;
        gemm_core<128,128,64,1,false,true,false>(As, Bs, red, sx*128,
            2*HD + sy*128,
            jfb, Cc, Cc, jfb, Cc, 0, jfb, Cc, 0, wqkvT, Cc, QKVb, QKVN, nullptr);
    } else if (y < 32) {
        int lb = x + 42*(y - 16);
        int nb = (lb & 7) * 84 + (lb >> 3);
        int sx = nb / 16, sy = nb % 16;
        gemm_core<128,128,64,3,false,false,true>(As, Bs, red, sx*128, sy*128,
            (const unsigned short*)jfh, Cc, Cc, (const unsigned short*)jfl, Cc, Cc,
            (const unsigned short*)jfd, Cc, Cc, (const unsigned short*)GT, 768,
            Tm, HD, nullptr);
    } else {
        int q = (y - 32) * 42 + x;
        float (*hr)[256] = (float(*)[256])smem;
        float* wl = (float*)(smem + 8192);
        int t = threadIdx.x;
        int j0 = q * 8;
        #pragma unroll
        for (int i = 0; i < 6; ++i)
            *(float4*)&wl[t*4 + i*1024] = *(const float4*)&Wvp2[t*4 + i*1024];
        {
            int r = t >> 5, c = (t & 31) * 8;
            const float* src = &jf[(size_t)(j0 + r)*Cc + c];
            *(float4*)&hr[r][c]   = *(const float4*)src;
            *(float4*)&hr[r][c+4] = *(const float4*)(src + 4);
        }
        __syncthreads();
        int r = t >> 5, o = t & 31;
        if (o < 24) {
            float a = 0.0f;
            for (int e = 0; e < 256; ++e) a += hr[r][e] * wl[e*24 + o];
            vproj[(size_t)(j0 + r)*24 + o] = a;
        }
    }
}

// ---------------------------------------------------------------------------
// COMBO1 (layer 1): y<16 -> V1 gemm; y in [16,32) -> T1 = h1b @ G1 (Q cols).
__global__ __launch_bounds__(256)
void combo1_kernel(const unsigned short* __restrict__ h1b,
                   const unsigned short* __restrict__ wqkvT1,
                   const unsigned short* __restrict__ G1T,
                   unsigned short* __restrict__ QKVb) {
    __shared__ __align__(16) unsigned short As[128*64];
    __shared__ __align__(16) unsigned short Bs[128*64];
    __shared__ float red[4];
    int x = blockIdx.x, y = blockIdx.y;
    if (y < 16) {
        int lb = x + 42*y;
        int nb = (lb & 7) * 84 + (lb >> 3);
        int sx = nb % 42, sy = nb / 42;
        gemm_core<128,128,64,1,false,true,false>(As, Bs, red, sx*128,
            2*HD + sy*128,
            h1b, Cc, Cc, h1b, Cc, 0, h1b, Cc, 0, wqkvT1, Cc, QKVb, QKVN, nullptr);
    } else {
        int lb = x + 42*(y - 16);
        int nb = (lb & 7) * 84 + (lb >> 3);
        int sx = nb % 42, sy = nb / 42;
        gemm_core<128,128,64,1,false,true,false>(As, Bs, red, sx*128, sy*128,
            h1b, Cc, Cc, h1b, Cc, 0, h1b, Cc, 0, G1T, Cc, QKVb, QKVN, nullptr);
    }
}

// ---------------------------------------------------------------------------
// fused epilogue gemm (NSEG segments, runtime klen/ldb), XCD-chunked gemm
// blocks (+ optional layer-1 kNN in extra y-blocks).
template<int NSEG, bool OUT_BF16, bool DO_KNN>
__global__ __launch_bounds__(256)
void fused_kernel(const unsigned short* __restrict__ att,
                  const unsigned short* __restrict__ hseg, int hk,
                  const unsigned short* __restrict__ h0seg, int h0k,
                  const unsigned short* __restrict__ fbtL, int ldb,
                  void* __restrict__ Cv, float* __restrict__ stat,
                  const float* __restrict__ crd, int* __restrict__ nbr1) {
    __shared__ __align__(16) char smem[16400];
    if (DO_KNN && blockIdx.y >= 4) {
        int b = (blockIdx.y - 4) * 84 + blockIdx.x;
        if (b < Bb) knn_body(b, crd, 4, nbr1, (float(*)[3])smem);
        return;
    }
    unsigned short* As = (unsigned short*)smem;
    unsigned short* Bs = (unsigned short*)(smem + 8192);
    float* red = (float*)(smem + 16384);
    // x-major index so same-A blocks are adjacent; chunk per XCD (336 % 8 == 0)
    int idx = blockIdx.x * 4 + blockIdx.y;
    int nb = (idx & 7) * 42 + (idx >> 3);
    int sx = nb >> 2, sy = nb & 3;
    gemm_core<64,64,64,NSEG,true,OUT_BF16,false>(
        As, Bs, red, sx*64, sy*64,
        att, HD, HD, hseg, Cc, hk, h0seg, Cc, h0k,
        fbtL, ldb, Cv, Cc, stat);
}

// ---------------------------------------------------------------------------
// precise layer-0 coords + FUSED layer-0 attention; XCD-chunked grid.
__global__ __launch_bounds__(64)
void precise_kernel(const float* __restrict__ T, const float* __restrict__ h0,
                    const int* __restrict__ nbr, const float* __restrict__ vproj,
                    const float* __restrict__ wsum,
                    const unsigned short* __restrict__ QKV,
                    float* __restrict__ crd, unsigned short* __restrict__ att) {
    int lb = blockIdx.x;
    int i = (lb & 7) * (Mrows/8) + (lb >> 3);   // bijective: 5376 % 8 == 0
    int b = i / Jj;
    int l = threadIdx.x;
    __shared__ float Ts[8][260];
    __shared__ float nb[8][260];
    __shared__ float wsL[64];
    __shared__ int nbs[KNN];
    #pragma unroll
    for (int u = 0; u < 8; ++u) {
        int idx = u*64 + l;
        float4 v = *(const float4*)&T[(size_t)i*HD + idx*4];
        int hh = idx >> 6, dd = (idx & 63) * 4;
        *(float4*)&Ts[hh][dd] = v;
    }
    float4 hv4 = *(const float4*)&h0[(size_t)i*Cc + l*4];   // lane-local skip slice
    if (l < KNN) nbs[l] = nbr[i*KNN + l];
    int kq = l >> 3, s = l & 7;
    int njs = nbr[i*KNN + kq];
    const float* nrow = &h0[(size_t)(b*Jj + njs)*Cc];
    #pragma unroll
    for (int u = 0; u < 8; ++u)
        *(float4*)&nb[kq][(s*8+u)*4] = *(const float4*)&nrow[(s*8+u)*4];
    __syncthreads();

    int k = l >> 3, h = l & 7;
    float sacc = 0;
    #pragma unroll 8
    for (int d = 0; d < 256; d += 4) {
        float4 tv = *(const float4*)&Ts[h][d];
        float4 nv = *(const float4*)&nb[k][d];
        sacc += tv.x*nv.x + tv.y*nv.y + tv.z*nv.z + tv.w*nv.w;
    }
    float sc = sacc * 0.0625f;
    sc = (sc >= 0.0f) ? sc : 0.2f * sc;
    float m = sc;
    m = fmaxf(m, __shfl_xor(m, 8));
    m = fmaxf(m, __shfl_xor(m, 16));
    m = fmaxf(m, __shfl_xor(m, 32));
    float e = expf(sc - m);
    float den = e;
    den += __shfl_xor(den, 8); den += __shfl_xor(den, 16); den += __shfl_xor(den, 32);
    float w = e / den;
    wsL[l] = w;                            // wsL[k*8 + h]

    int njk = nbs[k];
    const float* vp = &vproj[(size_t)(b*Jj + njk)*24 + h*3];
    float t0 = w * vp[0], t1 = w * vp[1], t2 = w * vp[2];
    const float hx[4] = {hv4.x, hv4.y, hv4.z, hv4.w};
    #pragma unroll
    for (int u = 0; u < 4; ++u) {
        float4 wv = *(const float4*)&wsum[(l*4 + u)*4];
        t0 += hx[u] * wv.x; t1 += hx[u] * wv.y; t2 += hx[u] * wv.z;
    }
    #pragma unroll
    for (int sft = 1; sft < 64; sft <<= 1) {
        t0 += __shfl_xor(t0, sft); t1 += __shfl_xor(t1, sft); t2 += __shfl_xor(t2, sft);
    }
    if (l == 0) {
        crd[i*4+0] = fmaxf(t0, 0.0f);
        crd[i*4+1] = fmaxf(t1, 0.0f);
        crd[i*4+2] = fmaxf(t2, 0.0f);
        crd[i*4+3] = 0.0f;
    }
    __syncthreads();

    // ---- fused layer-0 attention: lane l -> head h2 = l>>3, d chunk sub*32
    int h2 = l >> 3, sub = l & 7;
    float o[32] = {};
    #pragma unroll
    for (int kk = 0; kk < KNN; ++kk) {
        float wk_ = wsL[kk*8 + h2];
        const unsigned short* vrow =
            &QKV[(size_t)(b*Jj + nbs[kk])*QKVN + 2*HD + h2*256 + sub*32];
        #pragma unroll
        for (int j = 0; j < 4; ++j) {
            u16x8 v = *(const u16x8*)(vrow + j*8);
            #pragma unroll
            for (int u = 0; u < 8; ++u) o[j*8+u] += wk_ * bf2f(v[u]);
        }
    }
    unsigned short* arow = &att[(size_t)i*HD + h2*256 + sub*32];
    #pragma unroll
    for (int j = 0; j < 4; ++j) {
        u16x8 ou;
        #pragma unroll
        for (int u = 0; u < 8; ++u) ou[u] = f2bf(o[j*8+u]);
        *(u16x8*)(arow + j*8) = ou;
    }
}

// ---------------------------------------------------------------------------
// layer-1 attention via T1: score_h = T1[row][h*256+:] . h1b[nbr][:] / 16.
__global__ __launch_bounds__(64)
void attn1_kernel(const unsigned short* __restrict__ QKV,
                  const unsigned short* __restrict__ h1b,
                  const int* __restrict__ nbr, unsigned short* __restrict__ att) {
    int lb = blockIdx.x;
    int gid = (lb & 7) * (Mrows*4/8) + (lb >> 3);
    int hp = gid & 3, row = gid >> 2, b = row / Jj;
    int lane = threadIdx.x;
    int h = hp*2 + (lane >> 5);
    int d0 = (lane & 31) * 8;

    u16x8 tu = *(const u16x8*)&QKV[(size_t)row*QKVN + h*Dd + d0];
    float tf[8];
    #pragma unroll
    for (int i = 0; i < 8; ++i) tf[i] = bf2f(tu[i]);
    const int* np_ = nbr + row * KNN;

    float sc[KNN]; int nb[KNN];
    #pragma unroll
    for (int k = 0; k < KNN; ++k) {
        int n = np_[k]; nb[k] = n;
        u16x8 hu = *(const u16x8*)&h1b[(size_t)(b*Jj + n)*Cc + d0];
        float p = 0;
        #pragma unroll
        for (int i = 0; i < 8; ++i) p += tf[i] * bf2f(hu[i]);
        #pragma unroll
        for (int s = 1; s < 32; s <<= 1) p += __shfl_xor(p, s);
        sc[k] = p;
    }
    float mx = -INFINITY;
    #pragma unroll
    for (int k = 0; k < KNN; ++k) {
        float s = sc[k] * 0.0625f;
        s = (s >= 0.0f) ? s : 0.2f * s;
        sc[k] = s; mx = fmaxf(mx, s);
    }
    float den = 0.0f;
    #pragma unroll
    for (int k = 0; k < KNN; ++k) { sc[k] = expf(sc[k] - mx); den += sc[k]; }
    float inv = 1.0f / den;
    float o[8] = {};
    #pragma unroll
    for (int k = 0; k < KNN; ++k) {
        u16x8 vu = *(const u16x8*)&QKV[(size_t)(b*Jj + nb[k])*QKVN + 2*HD + h*Dd + d0];
        float w = sc[k] * inv;
        #pragma unroll
        for (int i = 0; i < 8; ++i) o[i] += w * bf2f(vu[i]);
    }
    u16x8 ou;
    #pragma unroll
    for (int i = 0; i < 8; ++i) ou[i] = f2bf(o[i]);
    *(u16x8*)&att[(size_t)row*HD + h*Dd + d0] = ou;
}

// ---------------------------------------------------------------------------
__global__ __launch_bounds__(64)
void final_kernel(const float* __restrict__ h, const float* __restrict__ fcw,
                  const float* __restrict__ fcb, const float* __restrict__ stats,
                  float* __restrict__ out) {
    int row = blockIdx.x, lane = threadIdx.x;
    const float4 hv = *(const float4*)(h + (size_t)row*Cc + lane*4);
    float a0=0, a1=0, a2=0;
    const float hx[4] = {hv.x, hv.y, hv.z, hv.w};
    #pragma unroll
    for (int i = 0; i < 4; ++i) {
        int c = lane*4 + i;
        a0 += hx[i]*fcw[c*3+0]; a1 += hx[i]*fcw[c*3+1]; a2 += hx[i]*fcw[c*3+2];
    }
    #pragma unroll
    for (int s = 32; s > 0; s >>= 1) {
        a0 += __shfl_xor(a0, s); a1 += __shfl_xor(a1, s); a2 += __shfl_xor(a2, s);
    }
    if (lane == 0) {
        out[row*3+0] = a0 + fcb[0];
        out[row*3+1] = a1 + fcb[1];
        out[row*3+2] = a2 + fcb[2];
        if (row == 0)
            out[(size_t)Mrows*3] =
                (stats[0] + stats[1]) * (0.5f / ((float)Mrows * (float)Cc));
    }
}

// ---------------------------------------------------------------------------
extern "C" void kernel_launch(void* const* d_in, const int* in_sizes, int n_in,
                              void* d_out, int out_size, void* d_ws, size_t ws_size,
                              hipStream_t stream) {
    (void)in_sizes; (void)n_in; (void)out_size; (void)ws_size;
    const float* jf     = (const float*)d_in[0];
    const float* wq     = (const float*)d_in[1];
    const float* wk     = (const float*)d_in[2];
    const float* wv     = (const float*)d_in[3];
    const float* wp     = (const float*)d_in[4];
    const float* wsw    = (const float*)d_in[5];
    const float* wskip0 = (const float*)d_in[6];
    const float* fcw    = (const float*)d_in[7];
    const float* fcb    = (const float*)d_in[8];
    float* out = (float*)d_out;

    char* wsb = (char*)d_ws;
    unsigned short* QKVb  = (unsigned short*)(wsb + OFF_QKV);
    float*          Tm    = (float*)(wsb + OFF_T);
    unsigned short* attb  = (unsigned short*)(wsb + OFF_ATT);
    _Float16*       GT    = (_Float16*)(wsb + OFF_GT);
    unsigned short* G1T   = (unsigned short*)(wsb + OFF_G1T);
    unsigned short* jfb   = (unsigned short*)(wsb + OFF_JFB);
    _Float16*       jfh   = (_Float16*)(wsb + OFF_JFH);
    _Float16*       jfl   = (_Float16*)(wsb + OFF_JFL);
    _Float16*       jfd   = (_Float16*)(wsb + OFF_JFD);
    unsigned short* h1b   = (unsigned short*)(wsb + OFF_H1B);
    float*          h2f   = (float*)(wsb + OFF_H2F);
    unsigned short* wqkvT = (unsigned short*)(wsb + OFF_WQKVT);
    unsigned short* fbt0  = (unsigned short*)(wsb + OFF_FBT0);
    unsigned short* fbt1  = (unsigned short*)(wsb + OFF_FBT1);
    float*          Wvp   = (float*)(wsb + OFF_WVP);
    float*          vproj = (float*)(wsb + OFF_VPROJ);
    float*          wsum  = (float*)(wsb + OFF_WSUM);
    float*          crd   = (float*)(wsb + OFF_CRD);
    int*            nbr0  = (int*)(wsb + OFF_NBR0);
    int*            nbr1  = (int*)(wsb + OFF_NBR1);
    float*          stats = (float*)(wsb + OFF_STAT);

    // 1. all input-only prep in one launch (long poles dispatched first)
    mega_prep_kernel<<<5385, 256, 0, stream>>>(jf, wq, wk, wv, wp, wsw, wskip0,
                                               wqkvT, fbt0, fbt1, stats, wsum,
                                               jfb, jfh, jfl, jfd, GT, G1T,
                                               Wvp, nbr0);
    // 2. layer-0 V gemm + fp16-split T-gemm + vproj
    combo_kernel<<<dim3(42, 48), 256, 0, stream>>>(jfb, wqkvT, QKVb,
                                                   jfh, jfl, jfd, GT, Tm,
                                                   jf, Wvp, vproj);
    // 3. precise layer-0 coords + fused layer-0 attention (XCD-chunked)
    precise_kernel<<<Mrows, 64, 0, stream>>>(Tm, jf, nbr0, vproj, wsum,
                                             QKVb, crd, attb);
    // 4. layer-0 fused output gemm (2 segments: wp | ws0+wskip0) + layer-1 kNN
    fused_kernel<2, true, true><<<dim3(84, 8), 256, 0, stream>>>(
        attb, jfb, Cc, jfb, 0, fbt0, KF0, h1b, &stats[0], crd, nbr1);
    // 5. layer-1 V gemm + T1 gemm (XCD-chunked)
    combo1_kernel<<<dim3(42, 32), 256, 0, stream>>>(
        h1b, wqkvT + (size_t)QKVN*Cc, G1T, QKVb);
    // 6. layer-1 attention via T1 (XCD-chunked)
    attn1_kernel<<<Mrows*4, 64, 0, stream>>>(QKVb, h1b, nbr1, attb);
    // 7. layer-1 fused output gemm (3 segments)
    fused_kernel<3, false, false><<<dim3(84, 4), 256, 0, stream>>>(
        attb, h1b, Cc, jfb, Cc, fbt1, KF1, h2f, &stats[1], nullptr, nullptr);
    // 8. final
    final_kernel<<<Mrows, 64, 0, stream>>>(h2f, fcw, fcb, stats, out);
}